// Round 5
// baseline (356.577 us; speedup 1.0000x reference)
//
#include <hip/hip_runtime.h>

#define NN 20480
#define NPTS 81920   // B(4) * N(20480)
#define MS 36        // MID/ACT row stride (floats)
#define RSH 40       // X row stride in shorts (80 B: c0..33 + 6 pad)
#define PTSH 640     // X shorts per point (16 rows * 40)
#define MIDOFF 2560  // MID region (X = 8*640 shorts = 2560 f)
#define LGROFF 3136  // stage2 lgr scratch (8 floats) [stage1 unused]
#define SHSTR 136    // s2c h row stride in floats (136 ≡ 8 mod 32 banks)
#define LOG2E 1.4426950408889634f

// fp32 weight offsets in wb (floats) — vectorized per-lane layouts:
//   P1M: [k][c] row-direct (lane k reads its row as 8x float4)
//   P2M: [c][k*2+h]   (lane k reads float2 -> outputs k, k+16)
//   M2/SC/M3/M4: [c][k*4+j] (lane k reads float4 -> outputs k+16j)
#define P1MWT 0      // 512
#define P2MWT 512    // 1024
#define M2WT  1536   // 2048
#define SCWT  3584   // 1024
#define M3WT  4608   // 256
#define M4WT  4864   // 8192
#define BFB   13056  // fp16 B-frags: 2 stages x 2048 shorts
#define WTOT  15104  // floats total

typedef _Float16 half8 __attribute__((ext_vector_type(8)));
typedef float f32x4 __attribute__((ext_vector_type(4)));

__device__ __forceinline__ float redsum16(float v){
    v += __shfl_xor(v, 1); v += __shfl_xor(v, 2);
    v += __shfl_xor(v, 4); v += __shfl_xor(v, 8);
    return v;
}
__device__ __forceinline__ float redmax16(float v){
    v = fmaxf(v, __shfl_xor(v, 1)); v = fmaxf(v, __shfl_xor(v, 2));
    v = fmaxf(v, __shfl_xor(v, 4)); v = fmaxf(v, __shfl_xor(v, 8));
    return v;
}
__device__ __forceinline__ void wsync(){
    __builtin_amdgcn_wave_barrier();
    __threadfence_block();
    __builtin_amdgcn_wave_barrier();
}
__device__ __forceinline__ float frcp(float x){ return __builtin_amdgcn_rcpf(x); }

__device__ __forceinline__ unsigned int ph(float lo, float hi){
    union { _Float16 h[2]; unsigned int u; } cv;
    cv.h[0] = (_Float16)lo; cv.h[1] = (_Float16)hi;
    return cv.u;
}
__device__ __forceinline__ float2 unph(unsigned int u){
    union { unsigned int u; _Float16 h[2]; } cv; cv.u = u;
    return make_float2((float)cv.h[0], (float)cv.h[1]);
}
__device__ __forceinline__ float h2f(short s){
    union { short s; _Float16 h; } cv; cv.s = s;
    return (float)cv.h;
}

// Fast atan2 (minimax deg-9; max err ~1.4e-4 rad; atan2(0,0)=0).
__device__ __forceinline__ float fatan2(float y, float x){
    float ax = fabsf(x), ay = fabsf(y);
    float mx = fmaxf(ax, ay), mn = fminf(ax, ay);
    float z = mn * frcp(mx);
    z = (mx == 0.f) ? 0.f : z;
    float z2 = z * z;
    float a = fmaf(0.05265332f, z2, -0.11643287f);
    a = fmaf(a, z2, 0.19354346f);
    a = fmaf(a, z2, -0.33262347f);
    a = fmaf(a, z2, 0.99997726f);
    a = a * z;
    a = (ay > ax) ? (1.5707963268f - a) : a;
    a = (x < 0.f) ? (3.1415926536f - a) : a;
    return (y < 0.f) ? -a : a;
}

// Batch<->XCD affinity swizzle (grid 10240, XCD = blockIdx%8).
__device__ __forceinline__ int swiz(int bid){
    int x = bid & 7, s = bid >> 3;
    return ((x >> 1) * 2560) + ((x & 1) * 1280) + s;
}

__global__ void k_fill4(float4* out, float val, int n4){
    int i = blockIdx.x * blockDim.x + threadIdx.x;
    int stride = gridDim.x * blockDim.x;
    float4 v = make_float4(val, val, val, val);
    for (; i < n4; i += stride) out[i] = v;
}

// Weight prep: vectorized-per-lane fp32 layouts + fp16 MFMA B-frags.
__global__ void k_prep(
    const float* __restrict__ p1fc, const float* __restrict__ p2fc,
    const float* __restrict__ p1mW, const float* __restrict__ p2mW,
    const float* __restrict__ m2W,  const float* __restrict__ scW,
    const float* __restrict__ m3W,  const float* __restrict__ m4W,
    float* __restrict__ wb)
{
    int bid = blockIdx.x;
    if (bid == 0){
        for (int e = threadIdx.x; e < 512; e += 256)
            wb[P1MWT + e] = p1mW[e];
    } else if (bid == 1){
        for (int e = threadIdx.x; e < 1024; e += 256){
            int c = e >> 5, r = e & 31;
            int k = r >> 1, h = r & 1;
            wb[P2MWT + e] = p2mW[(k + 16*h)*32 + c];
        }
    } else if (bid == 2){
        for (int e = threadIdx.x; e < 2048; e += 256){
            int c = e >> 6, r = e & 63;
            int k = r >> 2, j = r & 3;
            wb[M2WT + e] = m2W[(k + 16*j)*32 + c];
        }
    } else if (bid == 3){
        for (int e = threadIdx.x; e < 1024; e += 256){
            int c = e >> 6, r = e & 63;
            int k = r >> 2, j = r & 3;
            wb[SCWT + e] = scW[(k + 16*j)*16 + c];
        }
    } else if (bid == 4){
        for (int e = threadIdx.x; e < 256; e += 256){
            int c = e >> 6, r = e & 63;
            int k = r >> 2, j = r & 3;
            wb[M3WT + e] = m3W[(k + 16*j)*4 + c];
        }
    } else if (bid == 5){
        for (int e = threadIdx.x; e < 8192; e += 256){
            int c = e >> 6, r = e & 63;
            int k = r >> 2, j = r & 3;
            wb[M4WT + e] = m4W[(k + 16*j)*128 + c];
        }
    } else if (bid == 6 || bid == 7){
        // fc B-frags: value = fc[o][c]*LOG2E as fp16 (16x16x32 B layout).
        const float* src = (bid == 6) ? p1fc : p2fc;
        short* dst = (short*)(wb + BFB) + (bid - 6) * 2048;
        for (int e = threadIdx.x; e < 2048; e += 256){
            int j = e & 7, l = (e >> 3) & 63, tq = (e >> 9) & 3;
            int q = tq & 1, t = tq >> 1;
            int kk = ((l >> 4) << 3) + j;
            int c = q*32 + kk;
            int o = (l & 15) + 16*t;
            float v = (c < 34) ? src[o*34 + c] * LOG2E : 0.f;
            union { _Float16 h; short s; } cv; cv.h = (_Float16)v;
            dst[e] = cv.s;
        }
    }
}

__global__ __launch_bounds__(256) void k_feat0(
    const float* __restrict__ featp,
    const float* __restrict__ m1W,
    const float* __restrict__ m1g,
    const float* __restrict__ m1b,
    float* __restrict__ feat0)
{
    int p = blockIdx.x * 256 + threadIdx.x;
    if (p >= NPTS) return;
    int b = p / NN;
    int n = p - b * NN;
    float x[16];
    #pragma unroll
    for (int c = 0; c < 16; c++) x[c] = featp[(b*16 + c)*NN + n];
    float* dst = feat0 + (size_t)p * 16;
    for (int o = 0; o < 16; o++){
        float acc = 0.f;
        #pragma unroll
        for (int c = 0; c < 16; c++) acc = fmaf(m1W[o*16 + c], x[c], acc);
        dst[o] = fmaxf(fmaf(m1g[o], acc, m1b[o]), 0.f);
    }
}

// Pool one o-tile: softmax over k (4 in-lane + 2 butterflies, max-sub) and
// attention-weighted sum of X[c][k].
__device__ __forceinline__ float poolT(f32x4 a, const short* base, int c, int g){
    const short* xc = base + c;
    float x0 = h2f(xc[(g*4 + 0)*RSH]), x1 = h2f(xc[(g*4 + 1)*RSH]);
    float x2 = h2f(xc[(g*4 + 2)*RSH]), x3 = h2f(xc[(g*4 + 3)*RSH]);
    float m = fmaxf(fmaxf(a[0], a[1]), fmaxf(a[2], a[3]));
    m = fmaxf(m, __shfl_xor(m, 16)); m = fmaxf(m, __shfl_xor(m, 32));
    float e0 = exp2f(a[0] - m), e1 = exp2f(a[1] - m);
    float e2 = exp2f(a[2] - m), e3 = exp2f(a[3] - m);
    float s = (e0 + e1) + (e2 + e3);
    float num = fmaf(e3, x3, fmaf(e2, x2, fmaf(e1, x1, e0*x0)));
    s   += __shfl_xor(s, 16);   s   += __shfl_xor(s, 32);
    num += __shfl_xor(num, 16); num += __shfl_xor(num, 32);
    return num * frcp(s);
}

// Phase B via MFMA: per point D[k][o-tile] = X^T · W^T (K=64; c 34..63 zero).
__device__ __forceinline__ void phaseB_mfma(
    const short* xs, const short* bfS, float* smMid, int tid)
{
    const half8* bf = (const half8*)bfS;
    const int l = tid & 63, wv = tid >> 6;
    const int o = l & 15, g = l >> 4;
    half8 B00 = bf[l], B01 = bf[64 + l], B10 = bf[128 + l], B11 = bf[192 + l];
    #pragma unroll 2
    for (int pp = 0; pp < 4; pp++){
        const int pt = wv*4 + pp;
        const short* base = xs + pt*PTSH;
        const short* rowp = base + (l & 15)*RSH;
        half8 A0 = *(const half8*)(rowp + g*8);     // c = g*8+j
        unsigned int d = *(const unsigned int*)(rowp + 32);  // c32,33
        union { unsigned int u[4]; half8 v; } a1u;
        a1u.u[0] = (g == 0) ? d : 0u;
        a1u.u[1] = 0u; a1u.u[2] = 0u; a1u.u[3] = 0u;
        half8 A1 = a1u.v;                           // c = 32+g*8+j
        f32x4 z = {0.f, 0.f, 0.f, 0.f};
        f32x4 a0 = __builtin_amdgcn_mfma_f32_16x16x32_f16(A0, B00, z, 0, 0, 0);
        a0       = __builtin_amdgcn_mfma_f32_16x16x32_f16(A1, B01, a0, 0, 0, 0);
        f32x4 a1 = __builtin_amdgcn_mfma_f32_16x16x32_f16(A0, B10, z, 0, 0, 0);
        a1       = __builtin_amdgcn_mfma_f32_16x16x32_f16(A1, B11, a1, 0, 0, 0);
        float mid0 = poolT(a0, base, 2 + o,      g);
        float mid1 = poolT(a1, base, 2 + o + 16, g);
        if (g == 0){
            smMid[pt*MS + o]      = mid0;
            smMid[pt*MS + o + 16] = mid1;
        }
    }
}

// ---------------- Stage 1 (unchanged structure) ----------------
__global__ __launch_bounds__(128, 2) void k_stage1(
    const float* __restrict__ xyzp,
    const int* __restrict__ nidx,
    const float* __restrict__ feat0,
    const float* __restrict__ lm1W,
    const float* __restrict__ lm1g,
    const float* __restrict__ lm1b,
    const float* __restrict__ wb,
    const float* __restrict__ p1mg,
    const float* __restrict__ p1mb,
    float* __restrict__ feat1)
{
    __shared__ float sm[2848];
    short* xs = (short*)sm;
    const int k  = threadIdx.x & 15;
    const int pt = threadIdx.x >> 4;
    const int p  = (swiz(blockIdx.x) << 3) + pt;
    const int b  = p / NN;

    {
        const int ii = nidx[(p << 4) + k];
        const int q  = b * NN + ii;
        const float4* an = (const float4*)(feat0 + (size_t)q * 16);
        const float4* as = (const float4*)(feat0 + (size_t)p * 16);
        const float sx = xyzp[p*3 + 0];
        const float sy = xyzp[p*3 + 1];
        const float sz = xyzp[p*3 + 2];
        const float nx = xyzp[q*3 + 0];
        const float ny = xyzp[q*3 + 1];
        const float nz = xyzp[q*3 + 2];

        float4 A0 = an[0], A1 = an[1], A2 = an[2], A3 = an[3];
        float sd = 0.f;
        {
            float4 S0 = as[0], S1 = as[1], S2 = as[2], S3 = as[3];
            sd += fabsf(S0.x-A0.x) + fabsf(S0.y-A0.y) + fabsf(S0.z-A0.z) + fabsf(S0.w-A0.w);
            sd += fabsf(S1.x-A1.x) + fabsf(S1.y-A1.y) + fabsf(S1.z-A1.z) + fabsf(S1.w-A1.w);
            sd += fabsf(S2.x-A2.x) + fabsf(S2.y-A2.y) + fabsf(S2.z-A2.z) + fabsf(S2.w-A2.w);
            sd += fabsf(S3.x-A3.x) + fabsf(S3.y-A3.y) + fabsf(S3.z-A3.z) + fabsf(S3.w-A3.w);
        }
        float fdis2 = 2.f * __expf(-sd * 0.0625f);

        float rx = sx - nx, ry = sy - ny, rz = sz - nz;
        float r2 = rx*rx + ry*ry;
        float rdis = sqrtf(r2 + rz*rz);
        float ralpha = fatan2(ry, rx);
        float rbeta  = fatan2(rz, sqrtf(r2));
        float gdis = __expf(-rdis);

        float mx = redsum16(nx) * 0.0625f;
        float my = redsum16(ny) * 0.0625f;
        float mz = redsum16(nz) * 0.0625f;
        float dx = sx - mx, dy = sy - my, dz = sz - mz;
        float dalpha = fatan2(dy, dx);
        float dbeta  = fatan2(dz, sqrtf(dx*dx + dy*dy));

        float rep[9] = { ralpha - dalpha, rbeta - dbeta, rdis, sx, sy, sz, nx, ny, nz };
        float lrep[16];
        #pragma unroll
        for (int o = 0; o < 16; o++){
            float acc = 0.f;
            #pragma unroll
            for (int c = 0; c < 9; c++) acc = fmaf(lm1W[o*9 + c], rep[c], acc);
            lrep[o] = fmaxf(fmaf(lm1g[o], acc, lm1b[o]), 0.f);
        }

        uint4* rp = (uint4*)(xs + pt*PTSH + k*RSH);
        uint4 U;
        U.x = ph(gdis, fdis2); U.y = ph(A0.x, A0.y);
        U.z = ph(A0.z, A0.w);  U.w = ph(A1.x, A1.y);
        rp[0] = U;
        U.x = ph(A1.z, A1.w);  U.y = ph(A2.x, A2.y);
        U.z = ph(A2.z, A2.w);  U.w = ph(A3.x, A3.y);
        rp[1] = U;
        U.x = ph(A3.z, A3.w);      U.y = ph(lrep[0], lrep[1]);
        U.z = ph(lrep[2], lrep[3]); U.w = ph(lrep[4], lrep[5]);
        rp[2] = U;
        U.x = ph(lrep[6], lrep[7]);   U.y = ph(lrep[8], lrep[9]);
        U.z = ph(lrep[10], lrep[11]); U.w = ph(lrep[12], lrep[13]);
        rp[3] = U;
        U.x = ph(lrep[14], lrep[15]); U.y = 0u; U.z = 0u; U.w = 0u;
        rp[4] = U;
    }
    wsync();

    phaseB_mfma(xs, (const short*)(wb + BFB), sm + MIDOFF, threadIdx.x);
    wsync();

    {
        float mid[32];
        const float4* mp = (const float4*)(sm + MIDOFF + pt*MS);
        #pragma unroll
        for (int i = 0; i < 8; i++){
            float4 t = mp[i];
            mid[4*i]=t.x; mid[4*i+1]=t.y; mid[4*i+2]=t.z; mid[4*i+3]=t.w;
        }
        const float4* wp = (const float4*)(wb + P1MWT) + (k << 3);
        float acc = 0.f;
        #pragma unroll
        for (int i = 0; i < 8; i++){
            float4 wv = wp[i];
            acc = fmaf(wv.x, mid[4*i],   acc);
            acc = fmaf(wv.y, mid[4*i+1], acc);
            acc = fmaf(wv.z, mid[4*i+2], acc);
            acc = fmaf(wv.w, mid[4*i+3], acc);
        }
        feat1[(size_t)(p << 4) + k] = fmaxf(fmaf(p1mg[k], acc, p1mb[k]), 0.f);
    }
}

// ---------------- Stage 2AB: gather+geometry+MFMA-pool ----------------
// Writes MID (32 fp16, packed 2-per-dword) into out rows 0..15 of each
// point's output column; lgr (fp32) into row 16.  These rows are dead
// space until k_s2c overwrites them with the real output.
__global__ __launch_bounds__(128, 2) void k_s2ab(
    const float* __restrict__ xyzp,
    const int* __restrict__ nidx,
    const float* __restrict__ feat1,
    const float* __restrict__ lm1W,
    const float* __restrict__ lm1g,
    const float* __restrict__ lm1b,
    const float* __restrict__ lm2W,
    const float* __restrict__ lm2g,
    const float* __restrict__ lm2b,
    const float* __restrict__ wb,
    float* __restrict__ outp)
{
    __shared__ float sm[2848];
    short* xs = (short*)sm;
    const int k    = threadIdx.x & 15;
    const int pt   = threadIdx.x >> 4;
    const int pblk = swiz(blockIdx.x);
    const int p    = (pblk << 3) + pt;
    const int b    = p / NN;
    const int n    = p - b * NN;
    float lgrv;

    // ---- Phase A ----
    {
        const int ii = nidx[(p << 4) + k];
        const int q  = b * NN + ii;
        const float4* an = (const float4*)(feat1 + (size_t)q * 16);
        const float4* as = (const float4*)(feat1 + (size_t)p * 16);
        const float sx = xyzp[p*3 + 0];
        const float sy = xyzp[p*3 + 1];
        const float sz = xyzp[p*3 + 2];
        const float nx = xyzp[q*3 + 0];
        const float ny = xyzp[q*3 + 1];
        const float nz = xyzp[q*3 + 2];

        float4 A0 = an[0], A1 = an[1], A2 = an[2], A3 = an[3];
        float sd = 0.f;
        {
            float4 S0 = as[0], S1 = as[1], S2 = as[2], S3 = as[3];
            sd += fabsf(S0.x-A0.x) + fabsf(S0.y-A0.y) + fabsf(S0.z-A0.z) + fabsf(S0.w-A0.w);
            sd += fabsf(S1.x-A1.x) + fabsf(S1.y-A1.y) + fabsf(S1.z-A1.z) + fabsf(S1.w-A1.w);
            sd += fabsf(S2.x-A2.x) + fabsf(S2.y-A2.y) + fabsf(S2.z-A2.z) + fabsf(S2.w-A2.w);
            sd += fabsf(S3.x-A3.x) + fabsf(S3.y-A3.y) + fabsf(S3.z-A3.z) + fabsf(S3.w-A3.w);
        }
        float fdis2 = 2.f * __expf(-sd * 0.0625f);

        float rx = sx - nx, ry = sy - ny, rz = sz - nz;
        float r2 = rx*rx + ry*ry;
        float rdis = sqrtf(r2 + rz*rz);
        float ralpha = fatan2(ry, rx);
        float rbeta  = fatan2(rz, sqrtf(r2));
        float gdis = __expf(-rdis);

        float mx = redsum16(nx) * 0.0625f;
        float my = redsum16(ny) * 0.0625f;
        float mz = redsum16(nz) * 0.0625f;
        float dx = sx - mx, dy = sy - my, dz = sz - mz;
        float dalpha = fatan2(dy, dx);
        float dbeta  = fatan2(dz, sqrtf(dx*dx + dy*dy));

        float mxd = redmax16(rdis);
        float nr  = sqrtf(sx*sx + sy*sy + sz*sz);
        lgrv = (mxd*mxd*mxd) * frcp(nr*nr*nr);

        float rep[9] = { ralpha - dalpha, rbeta - dbeta, rdis, sx, sy, sz, nx, ny, nz };
        float lrep[16];
        #pragma unroll
        for (int o = 0; o < 16; o++){
            float acc = 0.f;
            #pragma unroll
            for (int c = 0; c < 9; c++) acc = fmaf(lm1W[o*9 + c], rep[c], acc);
            lrep[o] = fmaxf(fmaf(lm1g[o], acc, lm1b[o]), 0.f);
        }
        float lrep2[16];
        #pragma unroll
        for (int o = 0; o < 16; o++){
            float acc = 0.f;
            #pragma unroll
            for (int c = 0; c < 16; c++) acc = fmaf(lm2W[o*16 + c], lrep[c], acc);
            lrep2[o] = fmaxf(fmaf(lm2g[o], acc, lm2b[o]), 0.f);
        }

        uint4* rp = (uint4*)(xs + pt*PTSH + k*RSH);
        uint4 U;
        U.x = ph(gdis, fdis2); U.y = ph(A0.x, A0.y);
        U.z = ph(A0.z, A0.w);  U.w = ph(A1.x, A1.y);
        rp[0] = U;
        U.x = ph(A1.z, A1.w);  U.y = ph(A2.x, A2.y);
        U.z = ph(A2.z, A2.w);  U.w = ph(A3.x, A3.y);
        rp[1] = U;
        U.x = ph(A3.z, A3.w);        U.y = ph(lrep2[0], lrep2[1]);
        U.z = ph(lrep2[2], lrep2[3]); U.w = ph(lrep2[4], lrep2[5]);
        rp[2] = U;
        U.x = ph(lrep2[6], lrep2[7]);   U.y = ph(lrep2[8], lrep2[9]);
        U.z = ph(lrep2[10], lrep2[11]); U.w = ph(lrep2[12], lrep2[13]);
        rp[3] = U;
        U.x = ph(lrep2[14], lrep2[15]); U.y = 0u; U.z = 0u; U.w = 0u;
        rp[4] = U;
    }
    wsync();

    phaseB_mfma(xs, (const short*)(wb + BFB) + 2048, sm + MIDOFF, threadIdx.x);
    wsync();

    // ---- Pack MID -> out rows 0..15 (fp16 x2), lgr -> row 16 ----
    {
        float m0 = sm[MIDOFF + pt*MS + 2*k];
        float m1 = sm[MIDOFF + pt*MS + 2*k + 1];
        unsigned int u = ph(m0, m1);
        ((unsigned int*)outp)[(size_t)(b*64 + k)*NN + n] = u;
        if (k == 0) outp[(size_t)(b*64 + 16)*NN + n] = lgrv;
    }
}

// ---------------- Stage 2C: weight matvecs ----------------
// Reads MID/lgr from out rows 0..16, writes the full output column.
// LDS: MID 0..288, ACT 288..576, per-wave sH/out region at 576 + w*832
//   (sH rows at (pt&3)*SHSTR, out staging at +544).
__global__ __launch_bounds__(128, 4) void k_s2c(
    const float* __restrict__ featp,
    const float* __restrict__ xyzp,
    const float* __restrict__ wb,
    const float* __restrict__ p2mg,
    const float* __restrict__ p2mb,
    const float* __restrict__ m2g,
    const float* __restrict__ m2b,
    const float* __restrict__ scg,
    const float* __restrict__ scb,
    const float* __restrict__ m3g,
    const float* __restrict__ m3b,
    const float* __restrict__ m4g,
    const float* __restrict__ m4b,
    float* __restrict__ outp)
{
    __shared__ float sm[2240];
    const int k    = threadIdx.x & 15;
    const int pt   = threadIdx.x >> 4;
    const int pblk = swiz(blockIdx.x);
    const int p    = (pblk << 3) + pt;
    const int b    = p / NN;
    const int n    = p - b * NN;

    // ---- Load MID + lgr ----
    float lgr;
    {
        unsigned int u = ((const unsigned int*)outp)[(size_t)(b*64 + k)*NN + n];
        lgr = outp[(size_t)(b*64 + 16)*NN + n];
        float2 f = unph(u);
        sm[pt*MS + 2*k]     = f.x;
        sm[pt*MS + 2*k + 1] = f.y;
    }
    wsync();

    // ---- C1: p2m (relu); MID -> ACT ----
    {
        const float2* wp = (const float2*)(wb + P2MWT);
        const float* midp = sm + pt*MS;
        float actA = 0.f, actB = 0.f;
        #pragma unroll 2
        for (int c = 0; c < 32; c++){
            float2 wv = wp[c*16 + k];
            float m = midp[c];
            actA = fmaf(wv.x, m, actA);
            actB = fmaf(wv.y, m, actB);
        }
        sm[288 + pt*MS + k]      = fmaxf(fmaf(p2mg[k],    actA, p2mb[k]),    0.f);
        sm[288 + pt*MS + k + 16] = fmaxf(fmaf(p2mg[k+16], actB, p2mb[k+16]), 0.f);
    }
    wsync();

    // ---- C2: m2 + sc + m3 -> sH ----
    {
        const float4* w2 = (const float4*)(wb + M2WT);
        const float* actp = sm + 288 + pt*MS;
        float hA[4] = {0.f, 0.f, 0.f, 0.f};
        #pragma unroll 2
        for (int c = 0; c < 32; c++){
            float4 wv = w2[c*16 + k];
            float a = actp[c];
            hA[0] = fmaf(wv.x, a, hA[0]);
            hA[1] = fmaf(wv.y, a, hA[1]);
            hA[2] = fmaf(wv.z, a, hA[2]);
            hA[3] = fmaf(wv.w, a, hA[3]);
        }
        const float4* ws = (const float4*)(wb + SCWT);
        float sA4[4] = {0.f, 0.f, 0.f, 0.f};
        #pragma unroll 2
        for (int c = 0; c < 16; c++){
            float xc = featp[(b*16 + c)*NN + n];
            float4 wv = ws[c*16 + k];
            sA4[0] = fmaf(wv.x, xc, sA4[0]);
            sA4[1] = fmaf(wv.y, xc, sA4[1]);
            sA4[2] = fmaf(wv.z, xc, sA4[2]);
            sA4[3] = fmaf(wv.w, xc, sA4[3]);
        }
        const float sx = xyzp[p*3 + 0];
        const float sy = xyzp[p*3 + 1];
        const float sz = xyzp[p*3 + 2];
        const float v3[4] = { sx, sy, sz, lgr };
        const float4* w3 = (const float4*)(wb + M3WT);
        float m3a[4] = {0.f, 0.f, 0.f, 0.f};
        #pragma unroll
        for (int c = 0; c < 4; c++){
            float4 wv = w3[c*16 + k];
            float vc = v3[c];
            m3a[0] = fmaf(wv.x, vc, m3a[0]);
            m3a[1] = fmaf(wv.y, vc, m3a[1]);
            m3a[2] = fmaf(wv.z, vc, m3a[2]);
            m3a[3] = fmaf(wv.w, vc, m3a[3]);
        }
        float* sH = sm + 576 + (threadIdx.x >> 6)*832 + (pt & 3)*SHSTR;
        #pragma unroll
        for (int j = 0; j < 4; j++){
            int oo = k + 16*j;
            float scv = fmaf(scg[oo], sA4[j], scb[oo]);
            float m2v = fmaf(m2g[oo], hA[j],  m2b[oo]);
            sH[oo]      = m2v + scv;
            sH[64 + oo] = fmaf(m3g[oo], m3a[j], m3b[oo]);
        }
    }
    wsync();

    // ---- C3: m4 (relu) ----
    float o4[4] = {0.f, 0.f, 0.f, 0.f};
    {
        const float* hRow = sm + 576 + (threadIdx.x >> 6)*832 + (pt & 3)*SHSTR;
        const float4* w4 = (const float4*)(wb + M4WT);
        #pragma unroll 2
        for (int cb = 0; cb < 32; cb++){
            const float4 hv = *(const float4*)(hRow + cb*4);
            float4 wa = w4[(cb*4 + 0)*16 + k];
            float4 wbv= w4[(cb*4 + 1)*16 + k];
            float4 wc = w4[(cb*4 + 2)*16 + k];
            float4 wd = w4[(cb*4 + 3)*16 + k];
            o4[0] = fmaf(wa.x, hv.x, o4[0]); o4[1] = fmaf(wa.y, hv.x, o4[1]);
            o4[2] = fmaf(wa.z, hv.x, o4[2]); o4[3] = fmaf(wa.w, hv.x, o4[3]);
            o4[0] = fmaf(wbv.x, hv.y, o4[0]); o4[1] = fmaf(wbv.y, hv.y, o4[1]);
            o4[2] = fmaf(wbv.z, hv.y, o4[2]); o4[3] = fmaf(wbv.w, hv.y, o4[3]);
            o4[0] = fmaf(wc.x, hv.z, o4[0]); o4[1] = fmaf(wc.y, hv.z, o4[1]);
            o4[2] = fmaf(wc.z, hv.z, o4[2]); o4[3] = fmaf(wc.w, hv.z, o4[3]);
            o4[0] = fmaf(wd.x, hv.w, o4[0]); o4[1] = fmaf(wd.y, hv.w, o4[1]);
            o4[2] = fmaf(wd.z, hv.w, o4[2]); o4[3] = fmaf(wd.w, hv.w, o4[3]);
        }
    }
    wsync();
    {
        const int w   = threadIdx.x >> 6;
        const int l   = threadIdx.x & 63;
        float* sOutW  = sm + 576 + w*832 + 544;
        const int pt3 = pt & 3;
        #pragma unroll
        for (int j = 0; j < 4; j++)
            sOutW[4*(k + 16*j) + pt3] = fmaxf(fmaf(m4g[k+16*j], o4[j], m4b[k+16*j]), 0.f);
        wsync();
        const int pbase = pblk << 3;
        const int b0 = pbase / NN;
        const int n0 = pbase - b0 * NN + 4*w;
        float4 u = *(const float4*)(sOutW + 4*l);
        *(float4*)(outp + (size_t)(b0*64 + l)*NN + n0) = u;
    }
}

extern "C" void kernel_launch(void* const* d_in, const int* in_sizes, int n_in,
                              void* d_out, int out_size, void* d_ws, size_t ws_size,
                              hipStream_t stream) {
    float* outp = (float*)d_out;

    float fillv = 1.0f;
    bool ok = true;
    if (n_in != 32) { fillv = 5.0f; ok = false; }
    else if (in_sizes[0] != 1310720 || in_sizes[1] != 245760 ||
             in_sizes[31] != 1310720) { fillv = 7.0f; ok = false; }
    else if (out_size != 5242880) { fillv = 9.0f; ok = false; }
    else if (ws_size < ((size_t)NPTS * 16 + WTOT) * sizeof(float)) { fillv = 11.0f; ok = false; }

    k_fill4<<<1024, 256, 0, stream>>>((float4*)outp, fillv, out_size/4);
    if (!ok) return;

    const float* featp = (const float*)d_in[0];
    const float* xyzp  = (const float*)d_in[1];
    const int*   nidx  = (const int*)d_in[31];

    float* feat0 = (float*)d_out;                      // scratch in d_out
    float* feat1 = (float*)d_ws;
    float* wb    = (float*)d_ws + (size_t)NPTS * 16;

    #define W(i) ((const float*)d_in[2 + (i)])
    k_prep<<<8, 256, 0, stream>>>(W(9), W(13), W(10), W(14), W(17), W(20),
                                  W(23), W(26), wb);
    k_feat0<<<NPTS/256, 256, 0, stream>>>(featp, W(0), W(1), W(2), feat0);
    k_stage1<<<NPTS/8, 128, 0, stream>>>(xyzp, nidx, feat0,
        W(3), W(4), W(5), wb, W(11), W(12), feat1);
    k_s2ab<<<NPTS/8, 128, 0, stream>>>(xyzp, nidx, feat1,
        W(3), W(4), W(5),          // lm1
        W(6), W(7), W(8),          // lm2
        wb, outp);
    k_s2c<<<NPTS/8, 128, 0, stream>>>(featp, xyzp, wb,
        W(15), W(16),              // p2m g/b
        W(18), W(19),              // m2 g/b
        W(21), W(22),              // sc g/b
        W(24), W(25),              // m3 g/b
        W(27), W(28),              // m4 g/b
        outp);
    #undef W
}

// Round 6
// 265.893 us; speedup vs baseline: 1.3411x; 1.3411x over previous
//
#include <hip/hip_runtime.h>

#define NN 20480
#define NPTS 81920   // B(4) * N(20480)
#define MS 36        // MID row stride in s2ab/stage1 (floats)
#define RSH 40       // X row stride in shorts (80 B: c0..33 + 6 pad)
#define PTSH 640     // X shorts per point (16 rows * 40)
#define MIDOFF 2560  // MID region (X = 8*640 shorts = 2560 f)
#define LOG2E 1.4426950408889634f

// k_s2c LDS layout (floats) — strides audited for 16B align + <=2-way banks
#define MIDO 0       // 64 pts x 36
#define ACTO 2304    // 64 pts x 36
#define HO   4608    // 64 pts x 132 (staging reuses wave slice, stride 20)
#define LGRO 13056   // 64
#define SMTOT 13120  // 52.5 KB

// fp32 weight offsets in wb (floats) — vectorized per-lane layouts:
//   P1M: [k][c] row-direct; P2M: [c][k*2+h]; M2/SC/M3/M4: [c][k*4+j]
#define P1MWT 0      // 512
#define P2MWT 512    // 1024
#define M2WT  1536   // 2048
#define SCWT  3584   // 1024
#define M3WT  4608   // 256
#define M4WT  4864   // 8192
#define BFB   13056  // fp16 B-frags: 2 stages x 2048 shorts
#define WTOT  15104  // floats total

typedef _Float16 half8 __attribute__((ext_vector_type(8)));
typedef float f32x4 __attribute__((ext_vector_type(4)));

__device__ __forceinline__ float redsum16(float v){
    v += __shfl_xor(v, 1); v += __shfl_xor(v, 2);
    v += __shfl_xor(v, 4); v += __shfl_xor(v, 8);
    return v;
}
__device__ __forceinline__ float redmax16(float v){
    v = fmaxf(v, __shfl_xor(v, 1)); v = fmaxf(v, __shfl_xor(v, 2));
    v = fmaxf(v, __shfl_xor(v, 4)); v = fmaxf(v, __shfl_xor(v, 8));
    return v;
}
__device__ __forceinline__ void wsync(){
    __builtin_amdgcn_wave_barrier();
    __threadfence_block();
    __builtin_amdgcn_wave_barrier();
}
__device__ __forceinline__ float frcp(float x){ return __builtin_amdgcn_rcpf(x); }

__device__ __forceinline__ unsigned int ph(float lo, float hi){
    union { _Float16 h[2]; unsigned int u; } cv;
    cv.h[0] = (_Float16)lo; cv.h[1] = (_Float16)hi;
    return cv.u;
}
__device__ __forceinline__ float2 unph(unsigned int u){
    union { unsigned int u; _Float16 h[2]; } cv; cv.u = u;
    return make_float2((float)cv.h[0], (float)cv.h[1]);
}
__device__ __forceinline__ float h2f(short s){
    union { short s; _Float16 h; } cv; cv.s = s;
    return (float)cv.h;
}

// Fast atan2 (minimax deg-9; max err ~1.4e-4 rad; atan2(0,0)=0).
__device__ __forceinline__ float fatan2(float y, float x){
    float ax = fabsf(x), ay = fabsf(y);
    float mx = fmaxf(ax, ay), mn = fminf(ax, ay);
    float z = mn * frcp(mx);
    z = (mx == 0.f) ? 0.f : z;
    float z2 = z * z;
    float a = fmaf(0.05265332f, z2, -0.11643287f);
    a = fmaf(a, z2, 0.19354346f);
    a = fmaf(a, z2, -0.33262347f);
    a = fmaf(a, z2, 0.99997726f);
    a = a * z;
    a = (ay > ax) ? (1.5707963268f - a) : a;
    a = (x < 0.f) ? (3.1415926536f - a) : a;
    return (y < 0.f) ? -a : a;
}

// Batch<->XCD affinity swizzles.
__device__ __forceinline__ int swiz(int bid){      // grid 10240
    int x = bid & 7, s = bid >> 3;
    return ((x >> 1) * 2560) + ((x & 1) * 1280) + s;
}
__device__ __forceinline__ int swizC(int bid){     // grid 1280
    int x = bid & 7, s = bid >> 3;
    return x * 160 + s;
}

__global__ void k_fill4(float4* out, float val, int n4){
    int i = blockIdx.x * blockDim.x + threadIdx.x;
    int stride = gridDim.x * blockDim.x;
    float4 v = make_float4(val, val, val, val);
    for (; i < n4; i += stride) out[i] = v;
}

// Weight prep: vectorized-per-lane fp32 layouts + fp16 MFMA B-frags.
__global__ void k_prep(
    const float* __restrict__ p1fc, const float* __restrict__ p2fc,
    const float* __restrict__ p1mW, const float* __restrict__ p2mW,
    const float* __restrict__ m2W,  const float* __restrict__ scW,
    const float* __restrict__ m3W,  const float* __restrict__ m4W,
    float* __restrict__ wb)
{
    int bid = blockIdx.x;
    if (bid == 0){
        for (int e = threadIdx.x; e < 512; e += 256)
            wb[P1MWT + e] = p1mW[e];
    } else if (bid == 1){
        for (int e = threadIdx.x; e < 1024; e += 256){
            int c = e >> 5, r = e & 31;
            int k = r >> 1, h = r & 1;
            wb[P2MWT + e] = p2mW[(k + 16*h)*32 + c];
        }
    } else if (bid == 2){
        for (int e = threadIdx.x; e < 2048; e += 256){
            int c = e >> 6, r = e & 63;
            int k = r >> 2, j = r & 3;
            wb[M2WT + e] = m2W[(k + 16*j)*32 + c];
        }
    } else if (bid == 3){
        for (int e = threadIdx.x; e < 1024; e += 256){
            int c = e >> 6, r = e & 63;
            int k = r >> 2, j = r & 3;
            wb[SCWT + e] = scW[(k + 16*j)*16 + c];
        }
    } else if (bid == 4){
        for (int e = threadIdx.x; e < 256; e += 256){
            int c = e >> 6, r = e & 63;
            int k = r >> 2, j = r & 3;
            wb[M3WT + e] = m3W[(k + 16*j)*4 + c];
        }
    } else if (bid == 5){
        for (int e = threadIdx.x; e < 8192; e += 256){
            int c = e >> 6, r = e & 63;
            int k = r >> 2, j = r & 3;
            wb[M4WT + e] = m4W[(k + 16*j)*128 + c];
        }
    } else if (bid == 6 || bid == 7){
        // fc B-frags: value = fc[o][c]*LOG2E as fp16 (16x16x32 B layout).
        const float* src = (bid == 6) ? p1fc : p2fc;
        short* dst = (short*)(wb + BFB) + (bid - 6) * 2048;
        for (int e = threadIdx.x; e < 2048; e += 256){
            int j = e & 7, l = (e >> 3) & 63, tq = (e >> 9) & 3;
            int q = tq & 1, t = tq >> 1;
            int kk = ((l >> 4) << 3) + j;
            int c = q*32 + kk;
            int o = (l & 15) + 16*t;
            float v = (c < 34) ? src[o*34 + c] * LOG2E : 0.f;
            union { _Float16 h; short s; } cv; cv.h = (_Float16)v;
            dst[e] = cv.s;
        }
    }
}

__global__ __launch_bounds__(256) void k_feat0(
    const float* __restrict__ featp,
    const float* __restrict__ m1W,
    const float* __restrict__ m1g,
    const float* __restrict__ m1b,
    float* __restrict__ feat0)
{
    int p = blockIdx.x * 256 + threadIdx.x;
    if (p >= NPTS) return;
    int b = p / NN;
    int n = p - b * NN;
    float x[16];
    #pragma unroll
    for (int c = 0; c < 16; c++) x[c] = featp[(b*16 + c)*NN + n];
    float* dst = feat0 + (size_t)p * 16;
    for (int o = 0; o < 16; o++){
        float acc = 0.f;
        #pragma unroll
        for (int c = 0; c < 16; c++) acc = fmaf(m1W[o*16 + c], x[c], acc);
        dst[o] = fmaxf(fmaf(m1g[o], acc, m1b[o]), 0.f);
    }
}

// Pool one o-tile: softmax over k (4 in-lane + 2 butterflies, max-sub) and
// attention-weighted sum of X[c][k].
__device__ __forceinline__ float poolT(f32x4 a, const short* base, int c, int g){
    const short* xc = base + c;
    float x0 = h2f(xc[(g*4 + 0)*RSH]), x1 = h2f(xc[(g*4 + 1)*RSH]);
    float x2 = h2f(xc[(g*4 + 2)*RSH]), x3 = h2f(xc[(g*4 + 3)*RSH]);
    float m = fmaxf(fmaxf(a[0], a[1]), fmaxf(a[2], a[3]));
    m = fmaxf(m, __shfl_xor(m, 16)); m = fmaxf(m, __shfl_xor(m, 32));
    float e0 = exp2f(a[0] - m), e1 = exp2f(a[1] - m);
    float e2 = exp2f(a[2] - m), e3 = exp2f(a[3] - m);
    float s = (e0 + e1) + (e2 + e3);
    float num = fmaf(e3, x3, fmaf(e2, x2, fmaf(e1, x1, e0*x0)));
    s   += __shfl_xor(s, 16);   s   += __shfl_xor(s, 32);
    num += __shfl_xor(num, 16); num += __shfl_xor(num, 32);
    return num * frcp(s);
}

// Phase B via MFMA: per point D[k][o-tile] = X^T · W^T (K=64; c 34..63 zero).
__device__ __forceinline__ void phaseB_mfma(
    const short* xs, const short* bfS, float* smMid, int tid)
{
    const half8* bf = (const half8*)bfS;
    const int l = tid & 63, wv = tid >> 6;
    const int o = l & 15, g = l >> 4;
    half8 B00 = bf[l], B01 = bf[64 + l], B10 = bf[128 + l], B11 = bf[192 + l];
    #pragma unroll 2
    for (int pp = 0; pp < 4; pp++){
        const int pt = wv*4 + pp;
        const short* base = xs + pt*PTSH;
        const short* rowp = base + (l & 15)*RSH;
        half8 A0 = *(const half8*)(rowp + g*8);     // c = g*8+j
        unsigned int d = *(const unsigned int*)(rowp + 32);  // c32,33
        union { unsigned int u[4]; half8 v; } a1u;
        a1u.u[0] = (g == 0) ? d : 0u;
        a1u.u[1] = 0u; a1u.u[2] = 0u; a1u.u[3] = 0u;
        half8 A1 = a1u.v;                           // c = 32+g*8+j
        f32x4 z = {0.f, 0.f, 0.f, 0.f};
        f32x4 a0 = __builtin_amdgcn_mfma_f32_16x16x32_f16(A0, B00, z, 0, 0, 0);
        a0       = __builtin_amdgcn_mfma_f32_16x16x32_f16(A1, B01, a0, 0, 0, 0);
        f32x4 a1 = __builtin_amdgcn_mfma_f32_16x16x32_f16(A0, B10, z, 0, 0, 0);
        a1       = __builtin_amdgcn_mfma_f32_16x16x32_f16(A1, B11, a1, 0, 0, 0);
        float mid0 = poolT(a0, base, 2 + o,      g);
        float mid1 = poolT(a1, base, 2 + o + 16, g);
        if (g == 0){
            smMid[pt*MS + o]      = mid0;
            smMid[pt*MS + o + 16] = mid1;
        }
    }
}

// ---------------- Stage 1 ----------------
__global__ __launch_bounds__(128, 2) void k_stage1(
    const float* __restrict__ xyzp,
    const int* __restrict__ nidx,
    const float* __restrict__ feat0,
    const float* __restrict__ lm1W,
    const float* __restrict__ lm1g,
    const float* __restrict__ lm1b,
    const float* __restrict__ wb,
    const float* __restrict__ p1mg,
    const float* __restrict__ p1mb,
    float* __restrict__ feat1)
{
    __shared__ float sm[2848];
    short* xs = (short*)sm;
    const int k  = threadIdx.x & 15;
    const int pt = threadIdx.x >> 4;
    const int p  = (swiz(blockIdx.x) << 3) + pt;
    const int b  = p / NN;

    {
        const int ii = nidx[(p << 4) + k];
        const int q  = b * NN + ii;
        const float4* an = (const float4*)(feat0 + (size_t)q * 16);
        const float4* as = (const float4*)(feat0 + (size_t)p * 16);
        const float sx = xyzp[p*3 + 0];
        const float sy = xyzp[p*3 + 1];
        const float sz = xyzp[p*3 + 2];
        const float nx = xyzp[q*3 + 0];
        const float ny = xyzp[q*3 + 1];
        const float nz = xyzp[q*3 + 2];

        float4 A0 = an[0], A1 = an[1], A2 = an[2], A3 = an[3];
        float sd = 0.f;
        {
            float4 S0 = as[0], S1 = as[1], S2 = as[2], S3 = as[3];
            sd += fabsf(S0.x-A0.x) + fabsf(S0.y-A0.y) + fabsf(S0.z-A0.z) + fabsf(S0.w-A0.w);
            sd += fabsf(S1.x-A1.x) + fabsf(S1.y-A1.y) + fabsf(S1.z-A1.z) + fabsf(S1.w-A1.w);
            sd += fabsf(S2.x-A2.x) + fabsf(S2.y-A2.y) + fabsf(S2.z-A2.z) + fabsf(S2.w-A2.w);
            sd += fabsf(S3.x-A3.x) + fabsf(S3.y-A3.y) + fabsf(S3.z-A3.z) + fabsf(S3.w-A3.w);
        }
        float fdis2 = 2.f * __expf(-sd * 0.0625f);

        float rx = sx - nx, ry = sy - ny, rz = sz - nz;
        float r2 = rx*rx + ry*ry;
        float rdis = sqrtf(r2 + rz*rz);
        float ralpha = fatan2(ry, rx);
        float rbeta  = fatan2(rz, sqrtf(r2));
        float gdis = __expf(-rdis);

        float mx = redsum16(nx) * 0.0625f;
        float my = redsum16(ny) * 0.0625f;
        float mz = redsum16(nz) * 0.0625f;
        float dx = sx - mx, dy = sy - my, dz = sz - mz;
        float dalpha = fatan2(dy, dx);
        float dbeta  = fatan2(dz, sqrtf(dx*dx + dy*dy));

        float rep[9] = { ralpha - dalpha, rbeta - dbeta, rdis, sx, sy, sz, nx, ny, nz };
        float lrep[16];
        #pragma unroll
        for (int o = 0; o < 16; o++){
            float acc = 0.f;
            #pragma unroll
            for (int c = 0; c < 9; c++) acc = fmaf(lm1W[o*9 + c], rep[c], acc);
            lrep[o] = fmaxf(fmaf(lm1g[o], acc, lm1b[o]), 0.f);
        }

        uint4* rp = (uint4*)(xs + pt*PTSH + k*RSH);
        uint4 U;
        U.x = ph(gdis, fdis2); U.y = ph(A0.x, A0.y);
        U.z = ph(A0.z, A0.w);  U.w = ph(A1.x, A1.y);
        rp[0] = U;
        U.x = ph(A1.z, A1.w);  U.y = ph(A2.x, A2.y);
        U.z = ph(A2.z, A2.w);  U.w = ph(A3.x, A3.y);
        rp[1] = U;
        U.x = ph(A3.z, A3.w);      U.y = ph(lrep[0], lrep[1]);
        U.z = ph(lrep[2], lrep[3]); U.w = ph(lrep[4], lrep[5]);
        rp[2] = U;
        U.x = ph(lrep[6], lrep[7]);   U.y = ph(lrep[8], lrep[9]);
        U.z = ph(lrep[10], lrep[11]); U.w = ph(lrep[12], lrep[13]);
        rp[3] = U;
        U.x = ph(lrep[14], lrep[15]); U.y = 0u; U.z = 0u; U.w = 0u;
        rp[4] = U;
    }
    wsync();

    phaseB_mfma(xs, (const short*)(wb + BFB), sm + MIDOFF, threadIdx.x);
    wsync();

    {
        float mid[32];
        const float4* mp = (const float4*)(sm + MIDOFF + pt*MS);
        #pragma unroll
        for (int i = 0; i < 8; i++){
            float4 t = mp[i];
            mid[4*i]=t.x; mid[4*i+1]=t.y; mid[4*i+2]=t.z; mid[4*i+3]=t.w;
        }
        const float4* wp = (const float4*)(wb + P1MWT) + (k << 3);
        float acc = 0.f;
        #pragma unroll
        for (int i = 0; i < 8; i++){
            float4 wv = wp[i];
            acc = fmaf(wv.x, mid[4*i],   acc);
            acc = fmaf(wv.y, mid[4*i+1], acc);
            acc = fmaf(wv.z, mid[4*i+2], acc);
            acc = fmaf(wv.w, mid[4*i+3], acc);
        }
        feat1[(size_t)(p << 4) + k] = fmaxf(fmaf(p1mg[k], acc, p1mb[k]), 0.f);
    }
}

// ---------------- Stage 2AB: gather+geometry+MFMA-pool ----------------
// Writes MID (32 fp16, packed 2-per-dword) into out rows 0..15 of each
// point's output column; lgr (fp32) into row 16.
__global__ __launch_bounds__(128, 2) void k_s2ab(
    const float* __restrict__ xyzp,
    const int* __restrict__ nidx,
    const float* __restrict__ feat1,
    const float* __restrict__ lm1W,
    const float* __restrict__ lm1g,
    const float* __restrict__ lm1b,
    const float* __restrict__ lm2W,
    const float* __restrict__ lm2g,
    const float* __restrict__ lm2b,
    const float* __restrict__ wb,
    float* __restrict__ outp)
{
    __shared__ float sm[2848];
    short* xs = (short*)sm;
    const int k    = threadIdx.x & 15;
    const int pt   = threadIdx.x >> 4;
    const int pblk = swiz(blockIdx.x);
    const int p    = (pblk << 3) + pt;
    const int b    = p / NN;
    const int n    = p - b * NN;
    float lgrv;

    {
        const int ii = nidx[(p << 4) + k];
        const int q  = b * NN + ii;
        const float4* an = (const float4*)(feat1 + (size_t)q * 16);
        const float4* as = (const float4*)(feat1 + (size_t)p * 16);
        const float sx = xyzp[p*3 + 0];
        const float sy = xyzp[p*3 + 1];
        const float sz = xyzp[p*3 + 2];
        const float nx = xyzp[q*3 + 0];
        const float ny = xyzp[q*3 + 1];
        const float nz = xyzp[q*3 + 2];

        float4 A0 = an[0], A1 = an[1], A2 = an[2], A3 = an[3];
        float sd = 0.f;
        {
            float4 S0 = as[0], S1 = as[1], S2 = as[2], S3 = as[3];
            sd += fabsf(S0.x-A0.x) + fabsf(S0.y-A0.y) + fabsf(S0.z-A0.z) + fabsf(S0.w-A0.w);
            sd += fabsf(S1.x-A1.x) + fabsf(S1.y-A1.y) + fabsf(S1.z-A1.z) + fabsf(S1.w-A1.w);
            sd += fabsf(S2.x-A2.x) + fabsf(S2.y-A2.y) + fabsf(S2.z-A2.z) + fabsf(S2.w-A2.w);
            sd += fabsf(S3.x-A3.x) + fabsf(S3.y-A3.y) + fabsf(S3.z-A3.z) + fabsf(S3.w-A3.w);
        }
        float fdis2 = 2.f * __expf(-sd * 0.0625f);

        float rx = sx - nx, ry = sy - ny, rz = sz - nz;
        float r2 = rx*rx + ry*ry;
        float rdis = sqrtf(r2 + rz*rz);
        float ralpha = fatan2(ry, rx);
        float rbeta  = fatan2(rz, sqrtf(r2));
        float gdis = __expf(-rdis);

        float mx = redsum16(nx) * 0.0625f;
        float my = redsum16(ny) * 0.0625f;
        float mz = redsum16(nz) * 0.0625f;
        float dx = sx - mx, dy = sy - my, dz = sz - mz;
        float dalpha = fatan2(dy, dx);
        float dbeta  = fatan2(dz, sqrtf(dx*dx + dy*dy));

        float mxd = redmax16(rdis);
        float nr  = sqrtf(sx*sx + sy*sy + sz*sz);
        lgrv = (mxd*mxd*mxd) * frcp(nr*nr*nr);

        float rep[9] = { ralpha - dalpha, rbeta - dbeta, rdis, sx, sy, sz, nx, ny, nz };
        float lrep[16];
        #pragma unroll
        for (int o = 0; o < 16; o++){
            float acc = 0.f;
            #pragma unroll
            for (int c = 0; c < 9; c++) acc = fmaf(lm1W[o*9 + c], rep[c], acc);
            lrep[o] = fmaxf(fmaf(lm1g[o], acc, lm1b[o]), 0.f);
        }
        float lrep2[16];
        #pragma unroll
        for (int o = 0; o < 16; o++){
            float acc = 0.f;
            #pragma unroll
            for (int c = 0; c < 16; c++) acc = fmaf(lm2W[o*16 + c], lrep[c], acc);
            lrep2[o] = fmaxf(fmaf(lm2g[o], acc, lm2b[o]), 0.f);
        }

        uint4* rp = (uint4*)(xs + pt*PTSH + k*RSH);
        uint4 U;
        U.x = ph(gdis, fdis2); U.y = ph(A0.x, A0.y);
        U.z = ph(A0.z, A0.w);  U.w = ph(A1.x, A1.y);
        rp[0] = U;
        U.x = ph(A1.z, A1.w);  U.y = ph(A2.x, A2.y);
        U.z = ph(A2.z, A2.w);  U.w = ph(A3.x, A3.y);
        rp[1] = U;
        U.x = ph(A3.z, A3.w);        U.y = ph(lrep2[0], lrep2[1]);
        U.z = ph(lrep2[2], lrep2[3]); U.w = ph(lrep2[4], lrep2[5]);
        rp[2] = U;
        U.x = ph(lrep2[6], lrep2[7]);   U.y = ph(lrep2[8], lrep2[9]);
        U.z = ph(lrep2[10], lrep2[11]); U.w = ph(lrep2[12], lrep2[13]);
        rp[3] = U;
        U.x = ph(lrep2[14], lrep2[15]); U.y = 0u; U.z = 0u; U.w = 0u;
        rp[4] = U;
    }
    wsync();

    phaseB_mfma(xs, (const short*)(wb + BFB) + 2048, sm + MIDOFF, threadIdx.x);
    wsync();

    {
        float m0 = sm[MIDOFF + pt*MS + 2*k];
        float m1 = sm[MIDOFF + pt*MS + 2*k + 1];
        unsigned int u = ph(m0, m1);
        ((unsigned int*)outp)[(size_t)(b*64 + k)*NN + n] = u;
        if (k == 0) outp[(size_t)(b*64 + 16)*NN + n] = lgrv;
    }
}

// ---------------- Stage 2C: weight matvecs, 64 pts/block ----------------
// 256 threads = 4 waves; wave w owns pts w*16..w*16+15 (wave-level sync only).
// Thread (k = tid&15, g = (tid>>4)&3) owns outputs {k+16j} x points
// {w*16+g*4+i} — each weight register reused across 4 points (L1 traffic /4).
__global__ __launch_bounds__(256, 2) void k_s2c(
    const float* __restrict__ featp,
    const float* __restrict__ xyzp,
    const float* __restrict__ wb,
    const float* __restrict__ p2mg,
    const float* __restrict__ p2mb,
    const float* __restrict__ m2g,
    const float* __restrict__ m2b,
    const float* __restrict__ scg,
    const float* __restrict__ scb,
    const float* __restrict__ m3g,
    const float* __restrict__ m3b,
    const float* __restrict__ m4g,
    const float* __restrict__ m4b,
    float* __restrict__ outp)
{
    __shared__ float sm[SMTOT];
    const int tid = threadIdx.x;
    const int k   = tid & 15;
    const int g   = (tid >> 4) & 3;
    const int w   = tid >> 6;
    const int pblk = swizC(blockIdx.x);
    const int p0  = pblk << 6;           // 64 pts/block; 320 blocks/batch exact
    const int b   = p0 / NN;
    const int n0  = p0 - b * NN;
    const int ptw = w*16 + g*4;          // thread's first block-local point
    const int nT  = n0 + ptw;            // its column

    // ---- Load MID (rows 0..15 of out) + lgr (row 16) into LDS ----
    {
        uint4 um = *(const uint4*)((const unsigned int*)outp +
                                   (size_t)(b*64 + k)*NN + nT);
        float2 f;
        f = unph(um.x);
        sm[MIDO + (ptw+0)*36 + 2*k] = f.x; sm[MIDO + (ptw+0)*36 + 2*k+1] = f.y;
        f = unph(um.y);
        sm[MIDO + (ptw+1)*36 + 2*k] = f.x; sm[MIDO + (ptw+1)*36 + 2*k+1] = f.y;
        f = unph(um.z);
        sm[MIDO + (ptw+2)*36 + 2*k] = f.x; sm[MIDO + (ptw+2)*36 + 2*k+1] = f.y;
        f = unph(um.w);
        sm[MIDO + (ptw+3)*36 + 2*k] = f.x; sm[MIDO + (ptw+3)*36 + 2*k+1] = f.y;
        if (k == 0){
            float4 lv = *(const float4*)(outp + (size_t)(b*64 + 16)*NN + nT);
            sm[LGRO + ptw+0] = lv.x; sm[LGRO + ptw+1] = lv.y;
            sm[LGRO + ptw+2] = lv.z; sm[LGRO + ptw+3] = lv.w;
        }
    }
    wsync();

    // ---- C1: p2m (relu) -> ACT ----
    {
        const float2* wp = (const float2*)(wb + P2MWT);
        float aA[4] = {0.f,0.f,0.f,0.f}, aB[4] = {0.f,0.f,0.f,0.f};
        #pragma unroll 2
        for (int cq = 0; cq < 8; cq++){
            f32x4 mv[4];
            #pragma unroll
            for (int i = 0; i < 4; i++)
                mv[i] = *(const f32x4*)(sm + MIDO + (ptw+i)*36 + cq*4);
            #pragma unroll
            for (int cc = 0; cc < 4; cc++){
                float2 wv = wp[(cq*4+cc)*16 + k];
                #pragma unroll
                for (int i = 0; i < 4; i++){
                    aA[i] = fmaf(wv.x, mv[i][cc], aA[i]);
                    aB[i] = fmaf(wv.y, mv[i][cc], aB[i]);
                }
            }
        }
        float gA = p2mg[k], bA = p2mb[k], gB = p2mg[k+16], bB = p2mb[k+16];
        #pragma unroll
        for (int i = 0; i < 4; i++){
            sm[ACTO + (ptw+i)*36 + k]      = fmaxf(fmaf(gA, aA[i], bA), 0.f);
            sm[ACTO + (ptw+i)*36 + k + 16] = fmaxf(fmaf(gB, aB[i], bB), 0.f);
        }
    }
    wsync();

    // ---- C2: m2 + sc + m3 -> H ----
    {
        const f32x4* w2 = (const f32x4*)(wb + M2WT);
        float hAc[4][4];   // [j][i]
        #pragma unroll
        for (int j = 0; j < 4; j++)
            #pragma unroll
            for (int i = 0; i < 4; i++) hAc[j][i] = 0.f;
        #pragma unroll 2
        for (int cq = 0; cq < 8; cq++){
            f32x4 av[4];
            #pragma unroll
            for (int i = 0; i < 4; i++)
                av[i] = *(const f32x4*)(sm + ACTO + (ptw+i)*36 + cq*4);
            #pragma unroll
            for (int cc = 0; cc < 4; cc++){
                f32x4 wv = w2[(cq*4+cc)*16 + k];
                #pragma unroll
                for (int i = 0; i < 4; i++){
                    #pragma unroll
                    for (int j = 0; j < 4; j++)
                        hAc[j][i] = fmaf(wv[j], av[i][cc], hAc[j][i]);
                }
            }
        }
        const f32x4* ws = (const f32x4*)(wb + SCWT);
        float sAc[4][4];
        #pragma unroll
        for (int j = 0; j < 4; j++)
            #pragma unroll
            for (int i = 0; i < 4; i++) sAc[j][i] = 0.f;
        #pragma unroll 2
        for (int c = 0; c < 16; c++){
            f32x4 wv = ws[c*16 + k];
            f32x4 xv = *(const f32x4*)(featp + (size_t)(b*16 + c)*NN + nT);
            #pragma unroll
            for (int i = 0; i < 4; i++){
                #pragma unroll
                for (int j = 0; j < 4; j++)
                    sAc[j][i] = fmaf(wv[j], xv[i], sAc[j][i]);
            }
        }
        const f32x4* w3 = (const f32x4*)(wb + M3WT);
        float mAc[4][4];
        #pragma unroll
        for (int j = 0; j < 4; j++)
            #pragma unroll
            for (int i = 0; i < 4; i++) mAc[j][i] = 0.f;
        #pragma unroll
        for (int c = 0; c < 3; c++){
            f32x4 wv = w3[c*16 + k];
            #pragma unroll
            for (int i = 0; i < 4; i++){
                float vc = xyzp[(size_t)(p0 + ptw + i)*3 + c];
                #pragma unroll
                for (int j = 0; j < 4; j++)
                    mAc[j][i] = fmaf(wv[j], vc, mAc[j][i]);
            }
        }
        {
            f32x4 wv = w3[3*16 + k];
            #pragma unroll
            for (int i = 0; i < 4; i++){
                float vc = sm[LGRO + ptw + i];
                #pragma unroll
                for (int j = 0; j < 4; j++)
                    mAc[j][i] = fmaf(wv[j], vc, mAc[j][i]);
            }
        }
        #pragma unroll
        for (int j = 0; j < 4; j++){
            int oo = k + 16*j;
            float g2 = m2g[oo], b2 = m2b[oo];
            float gs = scg[oo], bs = scb[oo];
            float g3 = m3g[oo], b3 = m3b[oo];
            #pragma unroll
            for (int i = 0; i < 4; i++){
                float hv = fmaf(g2, hAc[j][i], b2) + fmaf(gs, sAc[j][i], bs);
                sm[HO + (ptw+i)*132 + oo]      = hv;
                sm[HO + (ptw+i)*132 + 64 + oo] = fmaf(g3, mAc[j][i], b3);
            }
        }
    }
    wsync();

    // ---- C3: m4 (relu) ----
    float acc[4][4];   // [j][i]
    #pragma unroll
    for (int j = 0; j < 4; j++)
        #pragma unroll
        for (int i = 0; i < 4; i++) acc[j][i] = 0.f;
    {
        const f32x4* w4 = (const f32x4*)(wb + M4WT);
        #pragma unroll 4
        for (int cb = 0; cb < 32; cb++){
            f32x4 wj[4];
            #pragma unroll
            for (int cc = 0; cc < 4; cc++)
                wj[cc] = w4[(cb*4+cc)*16 + k];
            f32x4 hv[4];
            #pragma unroll
            for (int i = 0; i < 4; i++)
                hv[i] = *(const f32x4*)(sm + HO + (ptw+i)*132 + cb*4);
            #pragma unroll
            for (int cc = 0; cc < 4; cc++){
                #pragma unroll
                for (int i = 0; i < 4; i++){
                    #pragma unroll
                    for (int j = 0; j < 4; j++)
                        acc[j][i] = fmaf(wj[cc][j], hv[i][cc], acc[j][i]);
                }
            }
        }
    }
    // relu + g/b, stage into wave-local slice of H (stride 20), then write.
    {
        float* stg = sm + HO + w*16*132;
        #pragma unroll
        for (int j = 0; j < 4; j++){
            int oo = k + 16*j;
            float gv = m4g[oo], bv = m4b[oo];
            #pragma unroll
            for (int i = 0; i < 4; i++)
                stg[oo*20 + g*4 + i] = fmaxf(fmaf(gv, acc[j][i], bv), 0.f);
        }
        wsync();
        const int l = tid & 63;
        float* dst = outp + (size_t)(b*64 + l)*NN + n0 + w*16;
        #pragma unroll
        for (int q = 0; q < 4; q++){
            f32x4 v = *(const f32x4*)(stg + l*20 + q*4);
            *(f32x4*)(dst + q*4) = v;
        }
    }
}

extern "C" void kernel_launch(void* const* d_in, const int* in_sizes, int n_in,
                              void* d_out, int out_size, void* d_ws, size_t ws_size,
                              hipStream_t stream) {
    float* outp = (float*)d_out;

    float fillv = 1.0f;
    bool ok = true;
    if (n_in != 32) { fillv = 5.0f; ok = false; }
    else if (in_sizes[0] != 1310720 || in_sizes[1] != 245760 ||
             in_sizes[31] != 1310720) { fillv = 7.0f; ok = false; }
    else if (out_size != 5242880) { fillv = 9.0f; ok = false; }
    else if (ws_size < ((size_t)NPTS * 16 + WTOT) * sizeof(float)) { fillv = 11.0f; ok = false; }

    k_fill4<<<1024, 256, 0, stream>>>((float4*)outp, fillv, out_size/4);
    if (!ok) return;

    const float* featp = (const float*)d_in[0];
    const float* xyzp  = (const float*)d_in[1];
    const int*   nidx  = (const int*)d_in[31];

    float* feat0 = (float*)d_out;                      // scratch in d_out
    float* feat1 = (float*)d_ws;
    float* wb    = (float*)d_ws + (size_t)NPTS * 16;

    #define W(i) ((const float*)d_in[2 + (i)])
    k_prep<<<8, 256, 0, stream>>>(W(9), W(13), W(10), W(14), W(17), W(20),
                                  W(23), W(26), wb);
    k_feat0<<<NPTS/256, 256, 0, stream>>>(featp, W(0), W(1), W(2), feat0);
    k_stage1<<<NPTS/8, 128, 0, stream>>>(xyzp, nidx, feat0,
        W(3), W(4), W(5), wb, W(11), W(12), feat1);
    k_s2ab<<<NPTS/8, 128, 0, stream>>>(xyzp, nidx, feat1,
        W(3), W(4), W(5),          // lm1
        W(6), W(7), W(8),          // lm2
        wb, outp);
    k_s2c<<<NPTS/64, 256, 0, stream>>>(featp, xyzp, wb,
        W(15), W(16),              // p2m g/b
        W(18), W(19),              // m2 g/b
        W(21), W(22),              // sc g/b
        W(24), W(25),              // m3 g/b
        W(27), W(28),              // m4 g/b
        outp);
    #undef W
}

// Round 7
// 253.713 us; speedup vs baseline: 1.4054x; 1.0480x over previous
//
#include <hip/hip_runtime.h>

#define NN 20480
#define NPTS 81920   // B(4) * N(20480)
#define MS 36        // MID row stride in s2ab/stage1 (floats)
#define RSH 40       // X row stride in shorts (80 B: c0..33 + 6 pad)
#define PTSH 640     // X shorts per point (16 rows * 40)
#define MIDOFF 2560  // MID region (X = 8*640 shorts = 2560 f)
#define LOG2E 1.4426950408889634f

// fp32 weight offsets in wb (floats):
//   P1M: [k][c] row-direct; P2M: [c][k*2+h]
//   Folded (m2/sc/m3 absorbed into m4, all act=False before m4):
//   MA = W4a*diag(m2g)*W2 [c0..31][k*4+j]; MX = W4a*diag(scg)*Ws [c0..15][r]
//   MV = W4b*diag(m3g)*W3 [c0..3][r];      C0 = W4a*(m2b+scb)+W4b*m3b [r]
#define P1MWT 0      // 512
#define P2MWT 512    // 1024
#define MAWT  1536   // 2048
#define MXWT  3584   // 1024
#define MVWT  4608   // 256
#define C0WT  4864   // 64
#define BFB   4928   // fp16 B-frags: 2 stages x 2048 shorts = 2048 floats
#define WTOT  6976   // floats total

// k_s2c LDS map (floats)
#define WL_P2M 0     // 1024
#define WL_MA  1024  // 2048
#define WL_MX  3072  // 1024
#define WL_MV  4096  // 256
#define WL_C0  4352  // 64
#define WOFF   4416  // per-wave slabs start
#define SLAB   1280  // slab: MID 16x36 | ACT at +576 16x36 | out-stage stride 20
#define LGRO   (WOFF + 4*SLAB)   // 9536, 64 floats
#define SMTOT2 9600  // 38.4 KB

typedef _Float16 half8 __attribute__((ext_vector_type(8)));
typedef float f32x4 __attribute__((ext_vector_type(4)));

__device__ __forceinline__ float redsum16(float v){
    v += __shfl_xor(v, 1); v += __shfl_xor(v, 2);
    v += __shfl_xor(v, 4); v += __shfl_xor(v, 8);
    return v;
}
__device__ __forceinline__ float redmax16(float v){
    v = fmaxf(v, __shfl_xor(v, 1)); v = fmaxf(v, __shfl_xor(v, 2));
    v = fmaxf(v, __shfl_xor(v, 4)); v = fmaxf(v, __shfl_xor(v, 8));
    return v;
}
__device__ __forceinline__ void wsync(){
    __builtin_amdgcn_wave_barrier();
    __threadfence_block();
    __builtin_amdgcn_wave_barrier();
}
__device__ __forceinline__ float frcp(float x){ return __builtin_amdgcn_rcpf(x); }

__device__ __forceinline__ unsigned int ph(float lo, float hi){
    union { _Float16 h[2]; unsigned int u; } cv;
    cv.h[0] = (_Float16)lo; cv.h[1] = (_Float16)hi;
    return cv.u;
}
__device__ __forceinline__ float2 unph(unsigned int u){
    union { unsigned int u; _Float16 h[2]; } cv; cv.u = u;
    return make_float2((float)cv.h[0], (float)cv.h[1]);
}
__device__ __forceinline__ float h2f(short s){
    union { short s; _Float16 h; } cv; cv.s = s;
    return (float)cv.h;
}

// Fast atan2 (minimax deg-9; max err ~1.4e-4 rad; atan2(0,0)=0).
__device__ __forceinline__ float fatan2(float y, float x){
    float ax = fabsf(x), ay = fabsf(y);
    float mx = fmaxf(ax, ay), mn = fminf(ax, ay);
    float z = mn * frcp(mx);
    z = (mx == 0.f) ? 0.f : z;
    float z2 = z * z;
    float a = fmaf(0.05265332f, z2, -0.11643287f);
    a = fmaf(a, z2, 0.19354346f);
    a = fmaf(a, z2, -0.33262347f);
    a = fmaf(a, z2, 0.99997726f);
    a = a * z;
    a = (ay > ax) ? (1.5707963268f - a) : a;
    a = (x < 0.f) ? (3.1415926536f - a) : a;
    return (y < 0.f) ? -a : a;
}

// Batch<->XCD affinity swizzles.
__device__ __forceinline__ int swiz(int bid){      // grid 10240
    int x = bid & 7, s = bid >> 3;
    return ((x >> 1) * 2560) + ((x & 1) * 1280) + s;
}
__device__ __forceinline__ int swizC(int bid){     // grid 1280
    int x = bid & 7, s = bid >> 3;
    return x * 160 + s;
}

__global__ void k_fill4(float4* out, float val, int n4){
    int i = blockIdx.x * blockDim.x + threadIdx.x;
    int stride = gridDim.x * blockDim.x;
    float4 v = make_float4(val, val, val, val);
    for (; i < n4; i += stride) out[i] = v;
}

// Weight prep: per-lane layouts, folded m2/sc/m3->m4 matrices, fp16 B-frags.
__global__ void k_prep(
    const float* __restrict__ p1fc, const float* __restrict__ p2fc,
    const float* __restrict__ p1mW, const float* __restrict__ p2mW,
    const float* __restrict__ m2W,  const float* __restrict__ scW,
    const float* __restrict__ m3W,  const float* __restrict__ m4W,
    const float* __restrict__ m2g,  const float* __restrict__ m2b,
    const float* __restrict__ scg,  const float* __restrict__ scb,
    const float* __restrict__ m3g,  const float* __restrict__ m3b,
    float* __restrict__ wb)
{
    int bid = blockIdx.x;
    if (bid == 0){
        for (int e = threadIdx.x; e < 512; e += 256)
            wb[P1MWT + e] = p1mW[e];
    } else if (bid == 1){
        // p2m [32o x 32c] -> [c][k*2+h], o = k + 16h
        for (int e = threadIdx.x; e < 1024; e += 256){
            int c = e >> 5, r = e & 31;
            int k = r >> 1, h = r & 1;
            wb[P2MWT + e] = p2mW[(k + 16*h)*32 + c];
        }
    } else if (bid == 2){
        // MA[c][r]: sum_h m4W[o][h] * m2g[h] * m2W[h][c]
        for (int e = threadIdx.x; e < 2048; e += 256){
            int c = e >> 6, r = e & 63;
            int o = (r >> 2) + 16*(r & 3);
            float acc = 0.f;
            for (int h = 0; h < 64; h++)
                acc = fmaf(m4W[o*128 + h] * m2g[h], m2W[h*32 + c], acc);
            wb[MAWT + e] = acc;
        }
    } else if (bid == 3){
        // MX[c][r]: sum_h m4W[o][h] * scg[h] * scW[h][c]
        for (int e = threadIdx.x; e < 1024; e += 256){
            int c = e >> 6, r = e & 63;
            int o = (r >> 2) + 16*(r & 3);
            float acc = 0.f;
            for (int h = 0; h < 64; h++)
                acc = fmaf(m4W[o*128 + h] * scg[h], scW[h*16 + c], acc);
            wb[MXWT + e] = acc;
        }
    } else if (bid == 4){
        // MV[c][r] + C0[r]
        int e = threadIdx.x;
        if (e < 256){
            int c = e >> 6, r = e & 63;
            int o = (r >> 2) + 16*(r & 3);
            float acc = 0.f;
            for (int h = 0; h < 64; h++)
                acc = fmaf(m4W[o*128 + 64 + h] * m3g[h], m3W[h*4 + c], acc);
            wb[MVWT + e] = acc;
        }
        if (e < 64){
            int o = (e >> 2) + 16*(e & 3);
            float acc = 0.f;
            for (int h = 0; h < 64; h++){
                acc = fmaf(m4W[o*128 + h], m2b[h] + scb[h], acc);
                acc = fmaf(m4W[o*128 + 64 + h], m3b[h], acc);
            }
            wb[C0WT + e] = acc;
        }
    } else if (bid == 6 || bid == 7){
        // fc B-frags: value = fc[o][c]*LOG2E as fp16 (16x16x32 B layout).
        const float* src = (bid == 6) ? p1fc : p2fc;
        short* dst = (short*)(wb + BFB) + (bid - 6) * 2048;
        for (int e = threadIdx.x; e < 2048; e += 256){
            int j = e & 7, l = (e >> 3) & 63, tq = (e >> 9) & 3;
            int q = tq & 1, t = tq >> 1;
            int kk = ((l >> 4) << 3) + j;
            int c = q*32 + kk;
            int o = (l & 15) + 16*t;
            float v = (c < 34) ? src[o*34 + c] * LOG2E : 0.f;
            union { _Float16 h; short s; } cv; cv.h = (_Float16)v;
            dst[e] = cv.s;
        }
    }
}

__global__ __launch_bounds__(256) void k_feat0(
    const float* __restrict__ featp,
    const float* __restrict__ m1W,
    const float* __restrict__ m1g,
    const float* __restrict__ m1b,
    float* __restrict__ feat0)
{
    int p = blockIdx.x * 256 + threadIdx.x;
    if (p >= NPTS) return;
    int b = p / NN;
    int n = p - b * NN;
    float x[16];
    #pragma unroll
    for (int c = 0; c < 16; c++) x[c] = featp[(b*16 + c)*NN + n];
    float o[16];
    for (int oo = 0; oo < 16; oo++){
        float acc = 0.f;
        #pragma unroll
        for (int c = 0; c < 16; c++) acc = fmaf(m1W[oo*16 + c], x[c], acc);
        o[oo] = fmaxf(fmaf(m1g[oo], acc, m1b[oo]), 0.f);
    }
    float4* dst = (float4*)(feat0 + (size_t)p * 16);
    #pragma unroll
    for (int i = 0; i < 4; i++)
        dst[i] = make_float4(o[4*i], o[4*i+1], o[4*i+2], o[4*i+3]);
}

// Pool one o-tile: softmax over k (4 in-lane + 2 butterflies, max-sub) and
// attention-weighted sum of X[c][k].
__device__ __forceinline__ float poolT(f32x4 a, const short* base, int c, int g){
    const short* xc = base + c;
    float x0 = h2f(xc[(g*4 + 0)*RSH]), x1 = h2f(xc[(g*4 + 1)*RSH]);
    float x2 = h2f(xc[(g*4 + 2)*RSH]), x3 = h2f(xc[(g*4 + 3)*RSH]);
    float m = fmaxf(fmaxf(a[0], a[1]), fmaxf(a[2], a[3]));
    m = fmaxf(m, __shfl_xor(m, 16)); m = fmaxf(m, __shfl_xor(m, 32));
    float e0 = exp2f(a[0] - m), e1 = exp2f(a[1] - m);
    float e2 = exp2f(a[2] - m), e3 = exp2f(a[3] - m);
    float s = (e0 + e1) + (e2 + e3);
    float num = fmaf(e3, x3, fmaf(e2, x2, fmaf(e1, x1, e0*x0)));
    s   += __shfl_xor(s, 16);   s   += __shfl_xor(s, 32);
    num += __shfl_xor(num, 16); num += __shfl_xor(num, 32);
    return num * frcp(s);
}

// Phase B via MFMA: per point D[k][o-tile] = X^T · W^T (K=64; c 34..63 zero).
__device__ __forceinline__ void phaseB_mfma(
    const short* xs, const short* bfS, float* smMid, int tid)
{
    const half8* bf = (const half8*)bfS;
    const int l = tid & 63, wv = tid >> 6;
    const int o = l & 15, g = l >> 4;
    half8 B00 = bf[l], B01 = bf[64 + l], B10 = bf[128 + l], B11 = bf[192 + l];
    #pragma unroll 2
    for (int pp = 0; pp < 4; pp++){
        const int pt = wv*4 + pp;
        const short* base = xs + pt*PTSH;
        const short* rowp = base + (l & 15)*RSH;
        half8 A0 = *(const half8*)(rowp + g*8);     // c = g*8+j
        unsigned int d = *(const unsigned int*)(rowp + 32);  // c32,33
        union { unsigned int u[4]; half8 v; } a1u;
        a1u.u[0] = (g == 0) ? d : 0u;
        a1u.u[1] = 0u; a1u.u[2] = 0u; a1u.u[3] = 0u;
        half8 A1 = a1u.v;                           // c = 32+g*8+j
        f32x4 z = {0.f, 0.f, 0.f, 0.f};
        f32x4 a0 = __builtin_amdgcn_mfma_f32_16x16x32_f16(A0, B00, z, 0, 0, 0);
        a0       = __builtin_amdgcn_mfma_f32_16x16x32_f16(A1, B01, a0, 0, 0, 0);
        f32x4 a1 = __builtin_amdgcn_mfma_f32_16x16x32_f16(A0, B10, z, 0, 0, 0);
        a1       = __builtin_amdgcn_mfma_f32_16x16x32_f16(A1, B11, a1, 0, 0, 0);
        float mid0 = poolT(a0, base, 2 + o,      g);
        float mid1 = poolT(a1, base, 2 + o + 16, g);
        if (g == 0){
            smMid[pt*MS + o]      = mid0;
            smMid[pt*MS + o + 16] = mid1;
        }
    }
}

// ---------------- Stage 1 ----------------
__global__ __launch_bounds__(128, 2) void k_stage1(
    const float* __restrict__ xyzp,
    const int* __restrict__ nidx,
    const float* __restrict__ feat0,
    const float* __restrict__ lm1W,
    const float* __restrict__ lm1g,
    const float* __restrict__ lm1b,
    const float* __restrict__ wb,
    const float* __restrict__ p1mg,
    const float* __restrict__ p1mb,
    float* __restrict__ feat1)
{
    __shared__ float sm[2848];
    short* xs = (short*)sm;
    const int k  = threadIdx.x & 15;
    const int pt = threadIdx.x >> 4;
    const int p  = (swiz(blockIdx.x) << 3) + pt;
    const int b  = p / NN;

    {
        const int ii = nidx[(p << 4) + k];
        const int q  = b * NN + ii;
        const float4* an = (const float4*)(feat0 + (size_t)q * 16);
        const float4* as = (const float4*)(feat0 + (size_t)p * 16);
        const float sx = xyzp[p*3 + 0];
        const float sy = xyzp[p*3 + 1];
        const float sz = xyzp[p*3 + 2];
        const float nx = xyzp[q*3 + 0];
        const float ny = xyzp[q*3 + 1];
        const float nz = xyzp[q*3 + 2];

        float4 A0 = an[0], A1 = an[1], A2 = an[2], A3 = an[3];
        float sd = 0.f;
        {
            float4 S0 = as[0], S1 = as[1], S2 = as[2], S3 = as[3];
            sd += fabsf(S0.x-A0.x) + fabsf(S0.y-A0.y) + fabsf(S0.z-A0.z) + fabsf(S0.w-A0.w);
            sd += fabsf(S1.x-A1.x) + fabsf(S1.y-A1.y) + fabsf(S1.z-A1.z) + fabsf(S1.w-A1.w);
            sd += fabsf(S2.x-A2.x) + fabsf(S2.y-A2.y) + fabsf(S2.z-A2.z) + fabsf(S2.w-A2.w);
            sd += fabsf(S3.x-A3.x) + fabsf(S3.y-A3.y) + fabsf(S3.z-A3.z) + fabsf(S3.w-A3.w);
        }
        float fdis2 = 2.f * __expf(-sd * 0.0625f);

        float rx = sx - nx, ry = sy - ny, rz = sz - nz;
        float r2 = rx*rx + ry*ry;
        float rdis = sqrtf(r2 + rz*rz);
        float ralpha = fatan2(ry, rx);
        float rbeta  = fatan2(rz, sqrtf(r2));
        float gdis = __expf(-rdis);

        float mx = redsum16(nx) * 0.0625f;
        float my = redsum16(ny) * 0.0625f;
        float mz = redsum16(nz) * 0.0625f;
        float dx = sx - mx, dy = sy - my, dz = sz - mz;
        float dalpha = fatan2(dy, dx);
        float dbeta  = fatan2(dz, sqrtf(dx*dx + dy*dy));

        float rep[9] = { ralpha - dalpha, rbeta - dbeta, rdis, sx, sy, sz, nx, ny, nz };
        float lrep[16];
        #pragma unroll
        for (int o = 0; o < 16; o++){
            float acc = 0.f;
            #pragma unroll
            for (int c = 0; c < 9; c++) acc = fmaf(lm1W[o*9 + c], rep[c], acc);
            lrep[o] = fmaxf(fmaf(lm1g[o], acc, lm1b[o]), 0.f);
        }

        uint4* rp = (uint4*)(xs + pt*PTSH + k*RSH);
        uint4 U;
        U.x = ph(gdis, fdis2); U.y = ph(A0.x, A0.y);
        U.z = ph(A0.z, A0.w);  U.w = ph(A1.x, A1.y);
        rp[0] = U;
        U.x = ph(A1.z, A1.w);  U.y = ph(A2.x, A2.y);
        U.z = ph(A2.z, A2.w);  U.w = ph(A3.x, A3.y);
        rp[1] = U;
        U.x = ph(A3.z, A3.w);      U.y = ph(lrep[0], lrep[1]);
        U.z = ph(lrep[2], lrep[3]); U.w = ph(lrep[4], lrep[5]);
        rp[2] = U;
        U.x = ph(lrep[6], lrep[7]);   U.y = ph(lrep[8], lrep[9]);
        U.z = ph(lrep[10], lrep[11]); U.w = ph(lrep[12], lrep[13]);
        rp[3] = U;
        U.x = ph(lrep[14], lrep[15]); U.y = 0u; U.z = 0u; U.w = 0u;
        rp[4] = U;
    }
    wsync();

    phaseB_mfma(xs, (const short*)(wb + BFB), sm + MIDOFF, threadIdx.x);
    wsync();

    {
        float mid[32];
        const float4* mp = (const float4*)(sm + MIDOFF + pt*MS);
        #pragma unroll
        for (int i = 0; i < 8; i++){
            float4 t = mp[i];
            mid[4*i]=t.x; mid[4*i+1]=t.y; mid[4*i+2]=t.z; mid[4*i+3]=t.w;
        }
        const float4* wp = (const float4*)(wb + P1MWT) + (k << 3);
        float acc = 0.f;
        #pragma unroll
        for (int i = 0; i < 8; i++){
            float4 wv = wp[i];
            acc = fmaf(wv.x, mid[4*i],   acc);
            acc = fmaf(wv.y, mid[4*i+1], acc);
            acc = fmaf(wv.z, mid[4*i+2], acc);
            acc = fmaf(wv.w, mid[4*i+3], acc);
        }
        feat1[(size_t)(p << 4) + k] = fmaxf(fmaf(p1mg[k], acc, p1mb[k]), 0.f);
    }
}

// ---------------- Stage 2AB: gather+geometry+MFMA-pool ----------------
// Writes MID (32 fp16, packed 2-per-dword) into out rows 0..15 of each
// point's output column; lgr (fp32) into row 16.
__global__ __launch_bounds__(128, 2) void k_s2ab(
    const float* __restrict__ xyzp,
    const int* __restrict__ nidx,
    const float* __restrict__ feat1,
    const float* __restrict__ lm1W,
    const float* __restrict__ lm1g,
    const float* __restrict__ lm1b,
    const float* __restrict__ lm2W,
    const float* __restrict__ lm2g,
    const float* __restrict__ lm2b,
    const float* __restrict__ wb,
    float* __restrict__ outp)
{
    __shared__ float sm[2848];
    short* xs = (short*)sm;
    const int k    = threadIdx.x & 15;
    const int pt   = threadIdx.x >> 4;
    const int pblk = swiz(blockIdx.x);
    const int p    = (pblk << 3) + pt;
    const int b    = p / NN;
    const int n    = p - b * NN;
    float lgrv;

    {
        const int ii = nidx[(p << 4) + k];
        const int q  = b * NN + ii;
        const float4* an = (const float4*)(feat1 + (size_t)q * 16);
        const float4* as = (const float4*)(feat1 + (size_t)p * 16);
        const float sx = xyzp[p*3 + 0];
        const float sy = xyzp[p*3 + 1];
        const float sz = xyzp[p*3 + 2];
        const float nx = xyzp[q*3 + 0];
        const float ny = xyzp[q*3 + 1];
        const float nz = xyzp[q*3 + 2];

        float4 A0 = an[0], A1 = an[1], A2 = an[2], A3 = an[3];
        float sd = 0.f;
        {
            float4 S0 = as[0], S1 = as[1], S2 = as[2], S3 = as[3];
            sd += fabsf(S0.x-A0.x) + fabsf(S0.y-A0.y) + fabsf(S0.z-A0.z) + fabsf(S0.w-A0.w);
            sd += fabsf(S1.x-A1.x) + fabsf(S1.y-A1.y) + fabsf(S1.z-A1.z) + fabsf(S1.w-A1.w);
            sd += fabsf(S2.x-A2.x) + fabsf(S2.y-A2.y) + fabsf(S2.z-A2.z) + fabsf(S2.w-A2.w);
            sd += fabsf(S3.x-A3.x) + fabsf(S3.y-A3.y) + fabsf(S3.z-A3.z) + fabsf(S3.w-A3.w);
        }
        float fdis2 = 2.f * __expf(-sd * 0.0625f);

        float rx = sx - nx, ry = sy - ny, rz = sz - nz;
        float r2 = rx*rx + ry*ry;
        float rdis = sqrtf(r2 + rz*rz);
        float ralpha = fatan2(ry, rx);
        float rbeta  = fatan2(rz, sqrtf(r2));
        float gdis = __expf(-rdis);

        float mx = redsum16(nx) * 0.0625f;
        float my = redsum16(ny) * 0.0625f;
        float mz = redsum16(nz) * 0.0625f;
        float dx = sx - mx, dy = sy - my, dz = sz - mz;
        float dalpha = fatan2(dy, dx);
        float dbeta  = fatan2(dz, sqrtf(dx*dx + dy*dy));

        float mxd = redmax16(rdis);
        float nr  = sqrtf(sx*sx + sy*sy + sz*sz);
        lgrv = (mxd*mxd*mxd) * frcp(nr*nr*nr);

        float rep[9] = { ralpha - dalpha, rbeta - dbeta, rdis, sx, sy, sz, nx, ny, nz };
        float lrep[16];
        #pragma unroll
        for (int o = 0; o < 16; o++){
            float acc = 0.f;
            #pragma unroll
            for (int c = 0; c < 9; c++) acc = fmaf(lm1W[o*9 + c], rep[c], acc);
            lrep[o] = fmaxf(fmaf(lm1g[o], acc, lm1b[o]), 0.f);
        }
        float lrep2[16];
        #pragma unroll
        for (int o = 0; o < 16; o++){
            float acc = 0.f;
            #pragma unroll
            for (int c = 0; c < 16; c++) acc = fmaf(lm2W[o*16 + c], lrep[c], acc);
            lrep2[o] = fmaxf(fmaf(lm2g[o], acc, lm2b[o]), 0.f);
        }

        uint4* rp = (uint4*)(xs + pt*PTSH + k*RSH);
        uint4 U;
        U.x = ph(gdis, fdis2); U.y = ph(A0.x, A0.y);
        U.z = ph(A0.z, A0.w);  U.w = ph(A1.x, A1.y);
        rp[0] = U;
        U.x = ph(A1.z, A1.w);  U.y = ph(A2.x, A2.y);
        U.z = ph(A2.z, A2.w);  U.w = ph(A3.x, A3.y);
        rp[1] = U;
        U.x = ph(A3.z, A3.w);        U.y = ph(lrep2[0], lrep2[1]);
        U.z = ph(lrep2[2], lrep2[3]); U.w = ph(lrep2[4], lrep2[5]);
        rp[2] = U;
        U.x = ph(lrep2[6], lrep2[7]);   U.y = ph(lrep2[8], lrep2[9]);
        U.z = ph(lrep2[10], lrep2[11]); U.w = ph(lrep2[12], lrep2[13]);
        rp[3] = U;
        U.x = ph(lrep2[14], lrep2[15]); U.y = 0u; U.z = 0u; U.w = 0u;
        rp[4] = U;
    }
    wsync();

    phaseB_mfma(xs, (const short*)(wb + BFB) + 2048, sm + MIDOFF, threadIdx.x);
    wsync();

    {
        float m0 = sm[MIDOFF + pt*MS + 2*k];
        float m1 = sm[MIDOFF + pt*MS + 2*k + 1];
        unsigned int u = ph(m0, m1);
        ((unsigned int*)outp)[(size_t)(b*64 + k)*NN + n] = u;
        if (k == 0) outp[(size_t)(b*64 + 16)*NN + n] = lgrv;
    }
}

// ---------------- Stage 2C: folded matvecs, 64 pts/block ----------------
// All weights in LDS (4416 f). o4 = relu(m4g*(MA·act + MX·x + MV·v3 + c0)+m4b)
// with act = relu(p2mg*(P2M·mid)+p2mb).  4 waves x 16 pts; thread (k,g) owns
// outputs {k+16j} x 4 points; weight LDS-reads broadcast across g.
__global__ __launch_bounds__(256, 2) void k_s2c(
    const float* __restrict__ featp,
    const float* __restrict__ xyzp,
    const float* __restrict__ wb,
    const float* __restrict__ p2mg,
    const float* __restrict__ p2mb,
    const float* __restrict__ m4g,
    const float* __restrict__ m4b,
    float* __restrict__ outp)
{
    __shared__ float sm[SMTOT2];
    const int tid = threadIdx.x;
    const int k   = tid & 15;
    const int g   = (tid >> 4) & 3;
    const int w   = tid >> 6;
    const int pblk = swizC(blockIdx.x);
    const int p0  = pblk << 6;
    const int b   = p0 / NN;
    const int n0  = p0 - b * NN;
    const int ptg = g*4;                 // wave-local first point
    const int nT  = n0 + w*16 + ptg;     // its global column
    float* slab = sm + WOFF + w*SLAB;

    // ---- Cooperative W load + MID/lgr load ----
    for (int e = tid; e < 4416; e += 256) sm[e] = wb[512 + e];
    {
        uint4 um = *(const uint4*)((const unsigned int*)outp +
                                   (size_t)(b*64 + k)*NN + nT);
        float2 f;
        f = unph(um.x);
        slab[(ptg+0)*36 + 2*k] = f.x; slab[(ptg+0)*36 + 2*k+1] = f.y;
        f = unph(um.y);
        slab[(ptg+1)*36 + 2*k] = f.x; slab[(ptg+1)*36 + 2*k+1] = f.y;
        f = unph(um.z);
        slab[(ptg+2)*36 + 2*k] = f.x; slab[(ptg+2)*36 + 2*k+1] = f.y;
        f = unph(um.w);
        slab[(ptg+3)*36 + 2*k] = f.x; slab[(ptg+3)*36 + 2*k+1] = f.y;
        if (k == 0){
            float4 lv = *(const float4*)(outp + (size_t)(b*64 + 16)*NN + nT);
            sm[LGRO + w*16 + ptg + 0] = lv.x; sm[LGRO + w*16 + ptg + 1] = lv.y;
            sm[LGRO + w*16 + ptg + 2] = lv.z; sm[LGRO + w*16 + ptg + 3] = lv.w;
        }
    }
    __syncthreads();

    // ---- C1: act = relu(p2mg*(P2M·mid)+p2mb) -> slab ACT ----
    {
        const float2* wp = (const float2*)(sm + WL_P2M);
        float aA[4] = {0.f,0.f,0.f,0.f}, aB[4] = {0.f,0.f,0.f,0.f};
        #pragma unroll 2
        for (int cq = 0; cq < 8; cq++){
            f32x4 mv[4];
            #pragma unroll
            for (int i = 0; i < 4; i++)
                mv[i] = *(const f32x4*)(slab + (ptg+i)*36 + cq*4);
            #pragma unroll
            for (int cc = 0; cc < 4; cc++){
                float2 wv = wp[(cq*4+cc)*16 + k];
                #pragma unroll
                for (int i = 0; i < 4; i++){
                    aA[i] = fmaf(wv.x, mv[i][cc], aA[i]);
                    aB[i] = fmaf(wv.y, mv[i][cc], aB[i]);
                }
            }
        }
        float gA = p2mg[k], bA = p2mb[k], gB = p2mg[k+16], bB = p2mb[k+16];
        #pragma unroll
        for (int i = 0; i < 4; i++){
            slab[576 + (ptg+i)*36 + k]      = fmaxf(fmaf(gA, aA[i], bA), 0.f);
            slab[576 + (ptg+i)*36 + k + 16] = fmaxf(fmaf(gB, aB[i], bB), 0.f);
        }
    }
    wsync();

    // ---- C2C3 fused: o = MA·act + MX·x + MV·v3 + c0; relu(m4g*o+m4b) ----
    float o4[4][4];   // [j][i]
    {
        f32x4 c0v = *(const f32x4*)(sm + WL_C0 + 4*k);
        #pragma unroll
        for (int j = 0; j < 4; j++)
            #pragma unroll
            for (int i = 0; i < 4; i++) o4[j][i] = c0v[j];

        const f32x4* wa = (const f32x4*)(sm + WL_MA);
        #pragma unroll 2
        for (int cq = 0; cq < 8; cq++){
            f32x4 av[4];
            #pragma unroll
            for (int i = 0; i < 4; i++)
                av[i] = *(const f32x4*)(slab + 576 + (ptg+i)*36 + cq*4);
            #pragma unroll
            for (int cc = 0; cc < 4; cc++){
                f32x4 wv = wa[(cq*4+cc)*16 + k];
                #pragma unroll
                for (int i = 0; i < 4; i++){
                    #pragma unroll
                    for (int j = 0; j < 4; j++)
                        o4[j][i] = fmaf(wv[j], av[i][cc], o4[j][i]);
                }
            }
        }
        const f32x4* wx = (const f32x4*)(sm + WL_MX);
        #pragma unroll 4
        for (int c = 0; c < 16; c++){
            f32x4 wv = wx[c*16 + k];
            f32x4 xv = *(const f32x4*)(featp + (size_t)(b*16 + c)*NN + nT);
            #pragma unroll
            for (int i = 0; i < 4; i++){
                #pragma unroll
                for (int j = 0; j < 4; j++)
                    o4[j][i] = fmaf(wv[j], xv[i], o4[j][i]);
            }
        }
        const f32x4* wvv = (const f32x4*)(sm + WL_MV);
        #pragma unroll
        for (int c = 0; c < 3; c++){
            f32x4 wv = wvv[c*16 + k];
            #pragma unroll
            for (int i = 0; i < 4; i++){
                float vc = xyzp[(size_t)(p0 + w*16 + ptg + i)*3 + c];
                #pragma unroll
                for (int j = 0; j < 4; j++)
                    o4[j][i] = fmaf(wv[j], vc, o4[j][i]);
            }
        }
        {
            f32x4 wv = wvv[3*16 + k];
            #pragma unroll
            for (int i = 0; i < 4; i++){
                float vc = sm[LGRO + w*16 + ptg + i];
                #pragma unroll
                for (int j = 0; j < 4; j++)
                    o4[j][i] = fmaf(wv[j], vc, o4[j][i]);
            }
        }
    }
    wsync();   // ACT reads complete before staging overwrites slab

    // ---- stage (stride 20, R6-proven pattern) + coalesced-ish write ----
    {
        float* stg = slab;
        #pragma unroll
        for (int j = 0; j < 4; j++){
            int oo = k + 16*j;
            float gv = m4g[oo], bv = m4b[oo];
            #pragma unroll
            for (int i = 0; i < 4; i++)
                stg[oo*20 + ptg + i] = fmaxf(fmaf(gv, o4[j][i], bv), 0.f);
        }
        wsync();
        const int l = tid & 63;
        float* dst = outp + (size_t)(b*64 + l)*NN + n0 + w*16;
        #pragma unroll
        for (int q = 0; q < 4; q++){
            f32x4 v = *(const f32x4*)(stg + l*20 + q*4);
            *(f32x4*)(dst + q*4) = v;
        }
    }
}

extern "C" void kernel_launch(void* const* d_in, const int* in_sizes, int n_in,
                              void* d_out, int out_size, void* d_ws, size_t ws_size,
                              hipStream_t stream) {
    float* outp = (float*)d_out;

    float fillv = 1.0f;
    bool ok = true;
    if (n_in != 32) { fillv = 5.0f; ok = false; }
    else if (in_sizes[0] != 1310720 || in_sizes[1] != 245760 ||
             in_sizes[31] != 1310720) { fillv = 7.0f; ok = false; }
    else if (out_size != 5242880) { fillv = 9.0f; ok = false; }
    else if (ws_size < ((size_t)NPTS * 16 + WTOT) * sizeof(float)) { fillv = 11.0f; ok = false; }

    if (!ok){
        k_fill4<<<1024, 256, 0, stream>>>((float4*)outp, fillv, out_size/4);
        return;
    }

    const float* featp = (const float*)d_in[0];
    const float* xyzp  = (const float*)d_in[1];
    const int*   nidx  = (const int*)d_in[31];

    float* feat0 = (float*)d_out;                      // scratch in d_out
    float* feat1 = (float*)d_ws;
    float* wb    = (float*)d_ws + (size_t)NPTS * 16;

    #define W(i) ((const float*)d_in[2 + (i)])
    k_prep<<<8, 256, 0, stream>>>(W(9), W(13), W(10), W(14), W(17), W(20),
                                  W(23), W(26),
                                  W(18), W(19), W(21), W(22), W(24), W(25),
                                  wb);
    k_feat0<<<NPTS/256, 256, 0, stream>>>(featp, W(0), W(1), W(2), feat0);
    k_stage1<<<NPTS/8, 128, 0, stream>>>(xyzp, nidx, feat0,
        W(3), W(4), W(5), wb, W(11), W(12), feat1);
    k_s2ab<<<NPTS/8, 128, 0, stream>>>(xyzp, nidx, feat1,
        W(3), W(4), W(5),          // lm1
        W(6), W(7), W(8),          // lm2
        wb, outp);
    k_s2c<<<NPTS/64, 256, 0, stream>>>(featp, xyzp, wb,
        W(15), W(16),              // p2m g/b
        W(27), W(28),              // m4 g/b
        outp);
    #undef W
}

// Round 8
// 252.595 us; speedup vs baseline: 1.4117x; 1.0044x over previous
//
#include <hip/hip_runtime.h>

#define NN 20480
#define NPTS 81920   // B(4) * N(20480)
#define MS 36        // MID row stride (floats)
#define RSH 40       // X row stride in shorts (80 B: c0..33 + 6 pad)
#define PTSH 640     // X shorts per point (16 rows * 40)
#define MIDOFF 2560  // MID region (X = 8*640 shorts = 2560 f)
#define HSOFF 2848   // hsS region (64 dwords, per-wave halves)
#define LOG2E 1.4426950408889634f

// d_out scratch rows (per batch, rows 17..63 are dead until s2c writes):
//   feat0h: flat fp16 [b*64NN + n*8 + d] (inside rows 0..16, dead after stage1)
//   HSROW..+7: Hs table (16 fp16 per point, lm1g/b folded)
//   PAROW+k: ph(d_alpha, d_beta) per pair; PBROW+k: ph(rdis, gdis)
//   LGROW: lgr fp32 per point
#define HSROW 17
#define PAROW 25
#define PBROW 41
#define LGROW 57

// fp32 weight offsets in wb (floats):
#define P1MWT 0      // 512   p1m [k][c] row-direct
#define P2MWT 512    // 1024  p2m [c][k*2+h]
#define MAWT  1536   // 2048  MA = W4a*diag(m2g)*W2   [c][k*4+j]
#define MXWT  3584   // 1024  MX = W4a*diag(scg)*Ws   [c][r]
#define MVWT  4608   // 256   MV = W4b*diag(m3g)*W3   [c][r]
#define C0WT  4864   // 64    C0 = W4a*(m2b+scb)+W4b*m3b
#define BFB   4928   // fp16 B-frags: 2 stages x 2048 shorts = 2048 floats
#define LM1AW 6976   // 48 (+pad 64): LM1A[c][o] = lm1g[o]*lm1W[o][c], c<3
#define WTOT  7040   // floats total

typedef _Float16 half8 __attribute__((ext_vector_type(8)));
typedef _Float16 h2t  __attribute__((ext_vector_type(2)));
typedef float f32x4 __attribute__((ext_vector_type(4)));
union HU { unsigned int u; h2t h; };

__device__ __forceinline__ float redsum16(float v){
    v += __shfl_xor(v, 1); v += __shfl_xor(v, 2);
    v += __shfl_xor(v, 4); v += __shfl_xor(v, 8);
    return v;
}
__device__ __forceinline__ float redmax16(float v){
    v = fmaxf(v, __shfl_xor(v, 1)); v = fmaxf(v, __shfl_xor(v, 2));
    v = fmaxf(v, __shfl_xor(v, 4)); v = fmaxf(v, __shfl_xor(v, 8));
    return v;
}
__device__ __forceinline__ void wsync(){
    __builtin_amdgcn_wave_barrier();
    __threadfence_block();
    __builtin_amdgcn_wave_barrier();
}
__device__ __forceinline__ float frcp(float x){ return __builtin_amdgcn_rcpf(x); }

__device__ __forceinline__ unsigned int ph(float lo, float hi){
    union { _Float16 h[2]; unsigned int u; } cv;
    cv.h[0] = (_Float16)lo; cv.h[1] = (_Float16)hi;
    return cv.u;
}
__device__ __forceinline__ float2 unph(unsigned int u){
    union { unsigned int u; _Float16 h[2]; } cv; cv.u = u;
    return make_float2((float)cv.h[0], (float)cv.h[1]);
}

// sum of |a-b| over 16 fp16 lanes (packed math; |x| via bitmask)
__device__ __forceinline__ float sd16(uint4 a0, uint4 a1, uint4 b0, uint4 b1){
    HU acc; acc.u = 0u;
    #define SDT(A,B) { HU x,y,d; x.u=(A); y.u=(B); d.h = x.h - y.h; \
                       d.u &= 0x7FFF7FFFu; acc.h = acc.h + d.h; }
    SDT(a0.x,b0.x) SDT(a0.y,b0.y) SDT(a0.z,b0.z) SDT(a0.w,b0.w)
    SDT(a1.x,b1.x) SDT(a1.y,b1.y) SDT(a1.z,b1.z) SDT(a1.w,b1.w)
    #undef SDT
    return (float)acc.h[0] + (float)acc.h[1];
}

// Fast atan2 (minimax deg-9; max err ~1.4e-4 rad; atan2(0,0)=0).
__device__ __forceinline__ float fatan2(float y, float x){
    float ax = fabsf(x), ay = fabsf(y);
    float mx = fmaxf(ax, ay), mn = fminf(ax, ay);
    float z = mn * frcp(mx);
    z = (mx == 0.f) ? 0.f : z;
    float z2 = z * z;
    float a = fmaf(0.05265332f, z2, -0.11643287f);
    a = fmaf(a, z2, 0.19354346f);
    a = fmaf(a, z2, -0.33262347f);
    a = fmaf(a, z2, 0.99997726f);
    a = a * z;
    a = (ay > ax) ? (1.5707963268f - a) : a;
    a = (x < 0.f) ? (3.1415926536f - a) : a;
    return (y < 0.f) ? -a : a;
}

// Batch<->XCD affinity swizzles.
__device__ __forceinline__ int swiz(int bid){      // grid 10240
    int x = bid & 7, s = bid >> 3;
    return ((x >> 1) * 2560) + ((x & 1) * 1280) + s;
}
__device__ __forceinline__ int swizC(int bid){     // grid 1280
    int x = bid & 7, s = bid >> 3;
    return x * 160 + s;
}

__global__ void k_fill4(float4* out, float val, int n4){
    int i = blockIdx.x * blockDim.x + threadIdx.x;
    int stride = gridDim.x * blockDim.x;
    float4 v = make_float4(val, val, val, val);
    for (; i < n4; i += stride) out[i] = v;
}

// Fused prep (blocks 0..7) + feat0/tables (blocks 8..327).
__global__ __launch_bounds__(256) void k_pre(
    const float* __restrict__ featp, const float* __restrict__ xyzp,
    const float* __restrict__ m1W,  const float* __restrict__ m1g,
    const float* __restrict__ m1b,
    const float* __restrict__ lm1W, const float* __restrict__ lm1g,
    const float* __restrict__ lm1b,
    const float* __restrict__ p1fc, const float* __restrict__ p2fc,
    const float* __restrict__ p1mW, const float* __restrict__ p2mW,
    const float* __restrict__ m2W,  const float* __restrict__ scW,
    const float* __restrict__ m3W,  const float* __restrict__ m4W,
    const float* __restrict__ m2g,  const float* __restrict__ m2b,
    const float* __restrict__ scg,  const float* __restrict__ scb,
    const float* __restrict__ m3g,  const float* __restrict__ m3b,
    float* __restrict__ wb, float* __restrict__ wsF,
    float* __restrict__ outp)
{
    int bid = blockIdx.x;
    if (bid < 8){
        if (bid == 0){
            for (int e = threadIdx.x; e < 512; e += 256)
                wb[P1MWT + e] = p1mW[e];
        } else if (bid == 1){
            for (int e = threadIdx.x; e < 1024; e += 256){
                int c = e >> 5, r = e & 31;
                int k = r >> 1, h = r & 1;
                wb[P2MWT + e] = p2mW[(k + 16*h)*32 + c];
            }
        } else if (bid == 2){
            for (int e = threadIdx.x; e < 2048; e += 256){
                int c = e >> 6, r = e & 63;
                int o = (r >> 2) + 16*(r & 3);
                float acc = 0.f;
                for (int h = 0; h < 64; h++)
                    acc = fmaf(m4W[o*128 + h] * m2g[h], m2W[h*32 + c], acc);
                wb[MAWT + e] = acc;
            }
        } else if (bid == 3){
            for (int e = threadIdx.x; e < 1024; e += 256){
                int c = e >> 6, r = e & 63;
                int o = (r >> 2) + 16*(r & 3);
                float acc = 0.f;
                for (int h = 0; h < 64; h++)
                    acc = fmaf(m4W[o*128 + h] * scg[h], scW[h*16 + c], acc);
                wb[MXWT + e] = acc;
            }
        } else if (bid == 4){
            int e = threadIdx.x;
            if (e < 256){
                int c = e >> 6, r = e & 63;
                int o = (r >> 2) + 16*(r & 3);
                float acc = 0.f;
                for (int h = 0; h < 64; h++)
                    acc = fmaf(m4W[o*128 + 64 + h] * m3g[h], m3W[h*4 + c], acc);
                wb[MVWT + e] = acc;
            }
            if (e < 64){
                int o = (e >> 2) + 16*(e & 3);
                float acc = 0.f;
                for (int h = 0; h < 64; h++){
                    acc = fmaf(m4W[o*128 + h], m2b[h] + scb[h], acc);
                    acc = fmaf(m4W[o*128 + 64 + h], m3b[h], acc);
                }
                wb[C0WT + e] = acc;
            }
        } else if (bid == 5){
            int e = threadIdx.x;
            if (e < 48){
                int c = e >> 4, o = e & 15;
                wb[LM1AW + e] = lm1g[o] * lm1W[o*9 + c];
            }
        } else {   // bid 6,7: fc B-frags (fc[o][c]*LOG2E fp16, 16x16x32 B layout)
            const float* src = (bid == 6) ? p1fc : p2fc;
            short* dst = (short*)(wb + BFB) + (bid - 6) * 2048;
            for (int e = threadIdx.x; e < 2048; e += 256){
                int j = e & 7, l = (e >> 3) & 63, tq = (e >> 9) & 3;
                int q = tq & 1, t = tq >> 1;
                int kk = ((l >> 4) << 3) + j;
                int c = q*32 + kk;
                int o = (l & 15) + 16*t;
                float v = (c < 34) ? src[o*34 + c] * LOG2E : 0.f;
                union { _Float16 h; short s; } cv; cv.h = (_Float16)v;
                dst[e] = cv.s;
            }
        }
        return;
    }
    // ---- feat0h + Hs/Hn tables ----
    int p = (bid - 8) * 256 + threadIdx.x;
    int b = p / NN;
    int n = p - b * NN;
    float x[16];
    #pragma unroll
    for (int c = 0; c < 16; c++) x[c] = featp[(b*16 + c)*NN + n];
    unsigned int dw[8];
    for (int oo = 0; oo < 8; oo++){
        float v0 = 0.f, v1 = 0.f;
        #pragma unroll
        for (int c = 0; c < 16; c++){
            v0 = fmaf(m1W[(2*oo)*16 + c],   x[c], v0);
            v1 = fmaf(m1W[(2*oo+1)*16 + c], x[c], v1);
        }
        v0 = fmaxf(fmaf(m1g[2*oo],   v0, m1b[2*oo]),   0.f);
        v1 = fmaxf(fmaf(m1g[2*oo+1], v1, m1b[2*oo+1]), 0.f);
        dw[oo] = ph(v0, v1);
    }
    uint4* f0 = (uint4*)(outp + (size_t)b*64*NN + (size_t)n*8);
    f0[0] = make_uint4(dw[0], dw[1], dw[2], dw[3]);
    f0[1] = make_uint4(dw[4], dw[5], dw[6], dw[7]);

    float sx = xyzp[p*3 + 0], sy = xyzp[p*3 + 1], sz = xyzp[p*3 + 2];
    unsigned int* outu = (unsigned int*)outp;
    unsigned short* hnT = (unsigned short*)wsF + (size_t)NPTS*16;
    unsigned int hw[8];
    for (int d = 0; d < 8; d++){
        float h0, h1, g0, g1;
        int o0 = 2*d, o1 = 2*d+1;
        h0 = lm1g[o0]*(lm1W[o0*9+3]*sx + lm1W[o0*9+4]*sy + lm1W[o0*9+5]*sz) + lm1b[o0];
        h1 = lm1g[o1]*(lm1W[o1*9+3]*sx + lm1W[o1*9+4]*sy + lm1W[o1*9+5]*sz) + lm1b[o1];
        g0 = lm1g[o0]*(lm1W[o0*9+6]*sx + lm1W[o0*9+7]*sy + lm1W[o0*9+8]*sz);
        g1 = lm1g[o1]*(lm1W[o1*9+6]*sx + lm1W[o1*9+7]*sy + lm1W[o1*9+8]*sz);
        outu[((size_t)b*64 + HSROW + d)*NN + n] = ph(h0, h1);   // Hs(+bias)
        hw[d] = ph(g0, g1);                                      // Hn
    }
    uint4* hq = (uint4*)(hnT + (size_t)p*16);
    hq[0] = make_uint4(hw[0], hw[1], hw[2], hw[3]);
    hq[1] = make_uint4(hw[4], hw[5], hw[6], hw[7]);
}

// Pool one o-tile: softmax over k + attention-weighted sum of X[c][k].
__device__ __forceinline__ float poolT(f32x4 a, const short* base, int c, int g){
    const short* xc = base + c;
    union { short s; _Float16 h; } c0, c1, c2, c3;
    c0.s = xc[(g*4 + 0)*RSH]; c1.s = xc[(g*4 + 1)*RSH];
    c2.s = xc[(g*4 + 2)*RSH]; c3.s = xc[(g*4 + 3)*RSH];
    float x0 = (float)c0.h, x1 = (float)c1.h, x2 = (float)c2.h, x3 = (float)c3.h;
    float m = fmaxf(fmaxf(a[0], a[1]), fmaxf(a[2], a[3]));
    m = fmaxf(m, __shfl_xor(m, 16)); m = fmaxf(m, __shfl_xor(m, 32));
    float e0 = exp2f(a[0] - m), e1 = exp2f(a[1] - m);
    float e2 = exp2f(a[2] - m), e3 = exp2f(a[3] - m);
    float s = (e0 + e1) + (e2 + e3);
    float num = fmaf(e3, x3, fmaf(e2, x2, fmaf(e1, x1, e0*x0)));
    s   += __shfl_xor(s, 16);   s   += __shfl_xor(s, 32);
    num += __shfl_xor(num, 16); num += __shfl_xor(num, 32);
    return num * frcp(s);
}

// Phase B via MFMA: per point D[k][o-tile] = X^T · W^T (K=64; c 34..63 zero).
__device__ __forceinline__ void phaseB_mfma(
    const short* xs, const short* bfS, float* smMid, int tid)
{
    const half8* bf = (const half8*)bfS;
    const int l = tid & 63, wv = tid >> 6;
    const int o = l & 15, g = l >> 4;
    half8 B00 = bf[l], B01 = bf[64 + l], B10 = bf[128 + l], B11 = bf[192 + l];
    #pragma unroll 2
    for (int pp = 0; pp < 4; pp++){
        const int pt = wv*4 + pp;
        const short* base = xs + pt*PTSH;
        const short* rowp = base + (l & 15)*RSH;
        half8 A0 = *(const half8*)(rowp + g*8);     // c = g*8+j
        unsigned int d = *(const unsigned int*)(rowp + 32);  // c32,33
        union { unsigned int u[4]; half8 v; } a1u;
        a1u.u[0] = (g == 0) ? d : 0u;
        a1u.u[1] = 0u; a1u.u[2] = 0u; a1u.u[3] = 0u;
        half8 A1 = a1u.v;                           // c = 32+g*8+j
        f32x4 z = {0.f, 0.f, 0.f, 0.f};
        f32x4 a0 = __builtin_amdgcn_mfma_f32_16x16x32_f16(A0, B00, z, 0, 0, 0);
        a0       = __builtin_amdgcn_mfma_f32_16x16x32_f16(A1, B01, a0, 0, 0, 0);
        f32x4 a1 = __builtin_amdgcn_mfma_f32_16x16x32_f16(A0, B10, z, 0, 0, 0);
        a1       = __builtin_amdgcn_mfma_f32_16x16x32_f16(A1, B11, a1, 0, 0, 0);
        float mid0 = poolT(a0, base, 2 + o,      g);
        float mid1 = poolT(a1, base, 2 + o + 16, g);
        if (g == 0){
            smMid[pt*MS + o]      = mid0;
            smMid[pt*MS + o + 16] = mid1;
        }
    }
}

// lrep[o] = relu(LM1A·(da,db,rd) + Hs'(LDS) + Hn(gathered))  -> 8 ph dwords
__device__ __forceinline__ void lrep16(
    const float* __restrict__ la, float da, float db, float rd,
    const float* hsS, uint4 H0, uint4 H1, unsigned int* lw)
{
    unsigned int hn[8] = {H0.x, H0.y, H0.z, H0.w, H1.x, H1.y, H1.z, H1.w};
    #pragma unroll
    for (int d = 0; d < 8; d++){
        HU a, b, s;
        a.u = __float_as_uint(hsS[d]);
        b.u = hn[d];
        s.h = a.h + b.h;
        int o0 = 2*d, o1 = 2*d+1;
        float v0 = fmaf(la[o0], da, fmaf(la[16+o0], db, la[32+o0]*rd));
        float v1 = fmaf(la[o1], da, fmaf(la[16+o1], db, la[32+o1]*rd));
        v0 = fmaxf(v0 + (float)s.h[0], 0.f);
        v1 = fmaxf(v1 + (float)s.h[1], 0.f);
        lw[d] = ph(v0, v1);
    }
}

// ---------------- Stage 1 ----------------
// Computes geometry fresh; uses Hs/Hn tables for lm1; saves pair scalars
// {da,db}/{rdis,gdis} + lgr to out rows; writes feat1h (fp16).
__global__ __launch_bounds__(128, 2) void k_stage1(
    const float* __restrict__ xyzp,
    const int* __restrict__ nidx,
    const float* __restrict__ wb,
    const float* __restrict__ p1mg,
    const float* __restrict__ p1mb,
    float* __restrict__ wsF,
    float* __restrict__ outp)
{
    __shared__ float sm[2912];
    short* xs = (short*)sm;
    const int k  = threadIdx.x & 15;
    const int pt = threadIdx.x >> 4;
    const int lane = threadIdx.x & 63, wv = threadIdx.x >> 6;
    const int pblk = swiz(blockIdx.x);
    const int p  = (pblk << 3) + pt;
    const int b  = p / NN;
    const int n  = p - b * NN;
    const int nb = (pblk << 3) - b * NN;   // block-base n (no batch straddle)
    unsigned short* hnT = (unsigned short*)wsF + (size_t)NPTS*16;

    // coop Hs load (wave-local: 32 lanes cover own wave's 4 points x 8 dwords)
    if (lane < 32){
        int lpt = wv*4 + (lane >> 3), d = lane & 7;
        sm[HSOFF + wv*32 + lane] =
            outp[((size_t)b*64 + HSROW + d)*NN + nb + lpt];
    }
    wsync();

    {
        const int ii = nidx[(p << 4) + k];
        const int q  = b * NN + ii;
        const uint4* aq = (const uint4*)(outp + (size_t)b*64*NN + (size_t)ii*8);
        const uint4* ap = (const uint4*)(outp + (size_t)b*64*NN + (size_t)n*8);
        uint4 A0 = aq[0], A1 = aq[1];
        uint4 S0 = ap[0], S1 = ap[1];
        const float sx = xyzp[p*3 + 0];
        const float sy = xyzp[p*3 + 1];
        const float sz = xyzp[p*3 + 2];
        const float nx = xyzp[q*3 + 0];
        const float ny = xyzp[q*3 + 1];
        const float nz = xyzp[q*3 + 2];

        float sd = sd16(A0, A1, S0, S1);
        float fdis2 = 2.f * __expf(-sd * 0.0625f);

        float rx = sx - nx, ry = sy - ny, rz = sz - nz;
        float r2 = rx*rx + ry*ry;
        float rdis = sqrtf(r2 + rz*rz);
        float ralpha = fatan2(ry, rx);
        float rbeta  = fatan2(rz, sqrtf(r2));
        float gdis = __expf(-rdis);

        float mx = redsum16(nx) * 0.0625f;
        float my = redsum16(ny) * 0.0625f;
        float mz = redsum16(nz) * 0.0625f;
        float dx = sx - mx, dy = sy - my, dz = sz - mz;
        float dalpha = fatan2(dy, dx);
        float dbeta  = fatan2(dz, sqrtf(dx*dx + dy*dy));
        float da = ralpha - dalpha, db = rbeta - dbeta;

        float mxd = redmax16(rdis);
        float nr  = sqrtf(sx*sx + sy*sy + sz*sz);

        // save pair scalars + lgr for stage 2
        unsigned int* outu = (unsigned int*)outp;
        outu[((size_t)b*64 + PAROW + k)*NN + n] = ph(da, db);
        outu[((size_t)b*64 + PBROW + k)*NN + n] = ph(rdis, gdis);
        if (k == 0)
            outp[((size_t)b*64 + LGROW)*NN + n] = (mxd*mxd*mxd) * frcp(nr*nr*nr);

        const uint4* hq = (const uint4*)(hnT + (size_t)q*16);
        uint4 H0 = hq[0], H1 = hq[1];
        unsigned int lw[8];
        lrep16(wb + LM1AW, da, db, rdis,
               sm + HSOFF + wv*32 + (pt & 3)*8, H0, H1, lw);

        uint4* rp = (uint4*)(xs + pt*PTSH + k*RSH);
        rp[0] = make_uint4(ph(gdis, fdis2), A0.x, A0.y, A0.z);
        rp[1] = make_uint4(A0.w, A1.x, A1.y, A1.z);
        rp[2] = make_uint4(A1.w, lw[0], lw[1], lw[2]);
        rp[3] = make_uint4(lw[3], lw[4], lw[5], lw[6]);
        rp[4] = make_uint4(lw[7], 0u, 0u, 0u);
    }
    wsync();

    phaseB_mfma(xs, (const short*)(wb + BFB), sm + MIDOFF, threadIdx.x);
    wsync();

    // ---- Phase C: p1m row k -> feat1h (fp16) ----
    {
        float mid[32];
        const float4* mp = (const float4*)(sm + MIDOFF + pt*MS);
        #pragma unroll
        for (int i = 0; i < 8; i++){
            float4 t = mp[i];
            mid[4*i]=t.x; mid[4*i+1]=t.y; mid[4*i+2]=t.z; mid[4*i+3]=t.w;
        }
        const float4* wp = (const float4*)(wb + P1MWT) + (k << 3);
        float acc = 0.f;
        #pragma unroll
        for (int i = 0; i < 8; i++){
            float4 wv4 = wp[i];
            acc = fmaf(wv4.x, mid[4*i],   acc);
            acc = fmaf(wv4.y, mid[4*i+1], acc);
            acc = fmaf(wv4.z, mid[4*i+2], acc);
            acc = fmaf(wv4.w, mid[4*i+3], acc);
        }
        float v = fmaxf(fmaf(p1mg[k], acc, p1mb[k]), 0.f);
        union { _Float16 h; unsigned short s; } cv; cv.h = (_Float16)v;
        ((unsigned short*)wsF)[(size_t)(p << 4) + k] = cv.s;
    }
}

// ---------------- Stage 2AB ----------------
// No geometry: loads saved pair scalars + tables; lm2 + MFMA-pool -> MID.
__global__ __launch_bounds__(128, 2) void k_s2ab(
    const int* __restrict__ nidx,
    const float* __restrict__ lm2W,
    const float* __restrict__ lm2g,
    const float* __restrict__ lm2b,
    const float* __restrict__ wb,
    const float* __restrict__ wsF,
    float* __restrict__ outp)
{
    __shared__ float sm[2912];
    short* xs = (short*)sm;
    const int k    = threadIdx.x & 15;
    const int pt   = threadIdx.x >> 4;
    const int lane = threadIdx.x & 63, wv = threadIdx.x >> 6;
    const int pblk = swiz(blockIdx.x);
    const int p    = (pblk << 3) + pt;
    const int b    = p / NN;
    const int n    = p - b * NN;
    const int nb   = (pblk << 3) - b * NN;
    const unsigned short* feat1h = (const unsigned short*)wsF;
    const unsigned short* hnT = (const unsigned short*)wsF + (size_t)NPTS*16;

    if (lane < 32){
        int lpt = wv*4 + (lane >> 3), d = lane & 7;
        sm[HSOFF + wv*32 + lane] =
            outp[((size_t)b*64 + HSROW + d)*NN + nb + lpt];
    }
    wsync();

    {
        const int ii = nidx[(p << 4) + k];
        const int q  = b * NN + ii;
        const unsigned int* outu = (const unsigned int*)outp;
        unsigned int pa = outu[((size_t)b*64 + PAROW + k)*NN + n];
        unsigned int pb = outu[((size_t)b*64 + PBROW + k)*NN + n];
        float2 dab = unph(pa);
        HU pbu; pbu.u = pb;
        float rd = (float)pbu.h[0];

        const uint4* aq = (const uint4*)(feat1h + (size_t)q*16);
        const uint4* ap = (const uint4*)(feat1h + (size_t)p*16);
        uint4 A0 = aq[0], A1 = aq[1];
        uint4 S0 = ap[0], S1 = ap[1];
        float sd = sd16(A0, A1, S0, S1);
        float fdis2 = 2.f * __expf(-sd * 0.0625f);

        const uint4* hq = (const uint4*)(hnT + (size_t)q*16);
        uint4 H0 = hq[0], H1 = hq[1];
        unsigned int lw[8];
        lrep16(wb + LM1AW, dab.x, dab.y, rd,
               sm + HSOFF + wv*32 + (pt & 3)*8, H0, H1, lw);

        // lrep (fp16 in lw) -> lrep2 = relu(lm2g*(W2*lrep)+lm2b)
        float lr[16];
        #pragma unroll
        for (int d = 0; d < 8; d++){
            float2 f = unph(lw[d]);
            lr[2*d] = f.x; lr[2*d+1] = f.y;
        }
        unsigned int l2[8];
        for (int oo = 0; oo < 8; oo++){
            float v0 = 0.f, v1 = 0.f;
            #pragma unroll
            for (int c = 0; c < 16; c++){
                v0 = fmaf(lm2W[(2*oo)*16 + c],   lr[c], v0);
                v1 = fmaf(lm2W[(2*oo+1)*16 + c], lr[c], v1);
            }
            v0 = fmaxf(fmaf(lm2g[2*oo],   v0, lm2b[2*oo]),   0.f);
            v1 = fmaxf(fmaf(lm2g[2*oo+1], v1, lm2b[2*oo+1]), 0.f);
            l2[oo] = ph(v0, v1);
        }

        HU g0; g0.h[0] = pbu.h[1]; g0.h[1] = (_Float16)fdis2;  // gdis,fdis2
        uint4* rp = (uint4*)(xs + pt*PTSH + k*RSH);
        rp[0] = make_uint4(g0.u, A0.x, A0.y, A0.z);
        rp[1] = make_uint4(A0.w, A1.x, A1.y, A1.z);
        rp[2] = make_uint4(A1.w, l2[0], l2[1], l2[2]);
        rp[3] = make_uint4(l2[3], l2[4], l2[5], l2[6]);
        rp[4] = make_uint4(l2[7], 0u, 0u, 0u);
    }
    wsync();

    phaseB_mfma(xs, (const short*)(wb + BFB) + 2048, sm + MIDOFF, threadIdx.x);
    wsync();

    {
        float m0 = sm[MIDOFF + pt*MS + 2*k];
        float m1 = sm[MIDOFF + pt*MS + 2*k + 1];
        ((unsigned int*)outp)[(size_t)(b*64 + k)*NN + n] = ph(m0, m1);
    }
}

// ---------------- Stage 2C: folded matvecs, 64 pts/block ----------------
#define WL_P2M 0     // 1024
#define WL_MA  1024  // 2048
#define WL_MX  3072  // 1024
#define WL_MV  4096  // 256
#define WL_C0  4352  // 64
#define WOFF   4416
#define SLAB   1280
#define LGRO   (WOFF + 4*SLAB)
#define SMTOT2 9600

__global__ __launch_bounds__(256, 2) void k_s2c(
    const float* __restrict__ featp,
    const float* __restrict__ xyzp,
    const float* __restrict__ wb,
    const float* __restrict__ p2mg,
    const float* __restrict__ p2mb,
    const float* __restrict__ m4g,
    const float* __restrict__ m4b,
    float* __restrict__ outp)
{
    __shared__ float sm[SMTOT2];
    const int tid = threadIdx.x;
    const int k   = tid & 15;
    const int g   = (tid >> 4) & 3;
    const int w   = tid >> 6;
    const int pblk = swizC(blockIdx.x);
    const int p0  = pblk << 6;
    const int b   = p0 / NN;
    const int n0  = p0 - b * NN;
    const int ptg = g*4;
    const int nT  = n0 + w*16 + ptg;
    float* slab = sm + WOFF + w*SLAB;

    for (int e = tid; e < 4416; e += 256) sm[e] = wb[512 + e];
    {
        uint4 um = *(const uint4*)((const unsigned int*)outp +
                                   (size_t)(b*64 + k)*NN + nT);
        float2 f;
        f = unph(um.x);
        slab[(ptg+0)*36 + 2*k] = f.x; slab[(ptg+0)*36 + 2*k+1] = f.y;
        f = unph(um.y);
        slab[(ptg+1)*36 + 2*k] = f.x; slab[(ptg+1)*36 + 2*k+1] = f.y;
        f = unph(um.z);
        slab[(ptg+2)*36 + 2*k] = f.x; slab[(ptg+2)*36 + 2*k+1] = f.y;
        f = unph(um.w);
        slab[(ptg+3)*36 + 2*k] = f.x; slab[(ptg+3)*36 + 2*k+1] = f.y;
        if (k == 0){
            float4 lv = *(const float4*)(outp + (size_t)(b*64 + LGROW)*NN + nT);
            sm[LGRO + w*16 + ptg + 0] = lv.x; sm[LGRO + w*16 + ptg + 1] = lv.y;
            sm[LGRO + w*16 + ptg + 2] = lv.z; sm[LGRO + w*16 + ptg + 3] = lv.w;
        }
    }
    __syncthreads();

    {
        const float2* wp = (const float2*)(sm + WL_P2M);
        float aA[4] = {0.f,0.f,0.f,0.f}, aB[4] = {0.f,0.f,0.f,0.f};
        #pragma unroll 2
        for (int cq = 0; cq < 8; cq++){
            f32x4 mv[4];
            #pragma unroll
            for (int i = 0; i < 4; i++)
                mv[i] = *(const f32x4*)(slab + (ptg+i)*36 + cq*4);
            #pragma unroll
            for (int cc = 0; cc < 4; cc++){
                float2 wv = wp[(cq*4+cc)*16 + k];
                #pragma unroll
                for (int i = 0; i < 4; i++){
                    aA[i] = fmaf(wv.x, mv[i][cc], aA[i]);
                    aB[i] = fmaf(wv.y, mv[i][cc], aB[i]);
                }
            }
        }
        float gA = p2mg[k], bA = p2mb[k], gB = p2mg[k+16], bB = p2mb[k+16];
        #pragma unroll
        for (int i = 0; i < 4; i++){
            slab[576 + (ptg+i)*36 + k]      = fmaxf(fmaf(gA, aA[i], bA), 0.f);
            slab[576 + (ptg+i)*36 + k + 16] = fmaxf(fmaf(gB, aB[i], bB), 0.f);
        }
    }
    wsync();

    float o4[4][4];
    {
        f32x4 c0v = *(const f32x4*)(sm + WL_C0 + 4*k);
        #pragma unroll
        for (int j = 0; j < 4; j++)
            #pragma unroll
            for (int i = 0; i < 4; i++) o4[j][i] = c0v[j];

        const f32x4* wa = (const f32x4*)(sm + WL_MA);
        #pragma unroll 2
        for (int cq = 0; cq < 8; cq++){
            f32x4 av[4];
            #pragma unroll
            for (int i = 0; i < 4; i++)
                av[i] = *(const f32x4*)(slab + 576 + (ptg+i)*36 + cq*4);
            #pragma unroll
            for (int cc = 0; cc < 4; cc++){
                f32x4 wv = wa[(cq*4+cc)*16 + k];
                #pragma unroll
                for (int i = 0; i < 4; i++){
                    #pragma unroll
                    for (int j = 0; j < 4; j++)
                        o4[j][i] = fmaf(wv[j], av[i][cc], o4[j][i]);
                }
            }
        }
        const f32x4* wx = (const f32x4*)(sm + WL_MX);
        #pragma unroll 4
        for (int c = 0; c < 16; c++){
            f32x4 wv = wx[c*16 + k];
            f32x4 xv = *(const f32x4*)(featp + (size_t)(b*16 + c)*NN + nT);
            #pragma unroll
            for (int i = 0; i < 4; i++){
                #pragma unroll
                for (int j = 0; j < 4; j++)
                    o4[j][i] = fmaf(wv[j], xv[i], o4[j][i]);
            }
        }
        const f32x4* wvv = (const f32x4*)(sm + WL_MV);
        #pragma unroll
        for (int c = 0; c < 3; c++){
            f32x4 wv = wvv[c*16 + k];
            #pragma unroll
            for (int i = 0; i < 4; i++){
                float vc = xyzp[(size_t)(p0 + w*16 + ptg + i)*3 + c];
                #pragma unroll
                for (int j = 0; j < 4; j++)
                    o4[j][i] = fmaf(wv[j], vc, o4[j][i]);
            }
        }
        {
            f32x4 wv = wvv[3*16 + k];
            #pragma unroll
            for (int i = 0; i < 4; i++){
                float vc = sm[LGRO + w*16 + ptg + i];
                #pragma unroll
                for (int j = 0; j < 4; j++)
                    o4[j][i] = fmaf(wv[j], vc, o4[j][i]);
            }
        }
    }
    wsync();

    {
        float* stg = slab;
        #pragma unroll
        for (int j = 0; j < 4; j++){
            int oo = k + 16*j;
            float gv = m4g[oo], bv = m4b[oo];
            #pragma unroll
            for (int i = 0; i < 4; i++)
                stg[oo*20 + ptg + i] = fmaxf(fmaf(gv, o4[j][i], bv), 0.f);
        }
        wsync();
        const int l = tid & 63;
        float* dst = outp + (size_t)(b*64 + l)*NN + n0 + w*16;
        #pragma unroll
        for (int q = 0; q < 4; q++){
            f32x4 v = *(const f32x4*)(stg + l*20 + q*4);
            *(f32x4*)(dst + q*4) = v;
        }
    }
}

extern "C" void kernel_launch(void* const* d_in, const int* in_sizes, int n_in,
                              void* d_out, int out_size, void* d_ws, size_t ws_size,
                              hipStream_t stream) {
    float* outp = (float*)d_out;

    float fillv = 1.0f;
    bool ok = true;
    if (n_in != 32) { fillv = 5.0f; ok = false; }
    else if (in_sizes[0] != 1310720 || in_sizes[1] != 245760 ||
             in_sizes[31] != 1310720) { fillv = 7.0f; ok = false; }
    else if (out_size != 5242880) { fillv = 9.0f; ok = false; }
    else if (ws_size < ((size_t)NPTS * 16 + WTOT) * sizeof(float)) { fillv = 11.0f; ok = false; }

    if (!ok){
        k_fill4<<<1024, 256, 0, stream>>>((float4*)outp, fillv, out_size/4);
        return;
    }

    const float* featp = (const float*)d_in[0];
    const float* xyzp  = (const float*)d_in[1];
    const int*   nidx  = (const int*)d_in[31];

    float* wsF = (float*)d_ws;
    float* wb  = (float*)d_ws + (size_t)NPTS * 16;

    #define W(i) ((const float*)d_in[2 + (i)])
    k_pre<<<8 + NPTS/256, 256, 0, stream>>>(
        featp, xyzp,
        W(0), W(1), W(2),          // m1
        W(3), W(4), W(5),          // lm1
        W(9), W(13),               // p1fc, p2fc
        W(10), W(14),              // p1mW, p2mW
        W(17), W(20), W(23), W(26),// m2W, scW, m3W, m4W
        W(18), W(19), W(21), W(22), W(24), W(25),  // m2/sc/m3 g,b
        wb, wsF, outp);
    k_stage1<<<NPTS/8, 128, 0, stream>>>(xyzp, nidx, wb,
        W(11), W(12),              // p1m g/b
        wsF, outp);
    k_s2ab<<<NPTS/8, 128, 0, stream>>>(nidx,
        W(6), W(7), W(8),          // lm2
        wb, wsF, outp);
    k_s2c<<<NPTS/64, 256, 0, stream>>>(featp, xyzp, wb,
        W(15), W(16),              // p2m g/b
        W(27), W(28),              // m4 g/b
        outp);
    #undef W
}

// Round 9
// 248.768 us; speedup vs baseline: 1.4334x; 1.0154x over previous
//
#include <hip/hip_runtime.h>

#define NN 20480
#define NPTS 81920   // B(4) * N(20480)
#define MS 36        // MID row stride (floats)
#define RSH 40       // X row stride in shorts (80 B: c0..33 + 6 pad)
#define PTSH 648     // X shorts per point (16 rows*40 + 8 pad) -> 324 dwords,
                     // %32=4: spreads the 4 wave-points across bank quads
#define MIDOFF 5184  // MID region (X = 16*648 shorts = 5184 f)
#define HSOFF  5760  // hs region (4 waves x 32 dwords)
#define SMS1   5888  // stage1/s2ab LDS floats (23.5 KB -> 6 blocks/CU)
#define LOG2E 1.4426950408889634f

// d_out scratch rows (per batch, rows 17..63 dead until s2c writes):
#define HSROW 17
#define PAROW 25
#define PBROW 41
#define LGROW 57

// fp32 weight offsets in wb (floats):
#define P1MWT 0      // 512   p1m [k][c] row-direct
#define P2MWT 512    // 1024  p2m [c][k*2+h]
#define MAWT  1536   // 2048  MA = W4a*diag(m2g)*W2   [c][k*4+j]
#define MXWT  3584   // 1024  MX = W4a*diag(scg)*Ws   [c][r]
#define MVWT  4608   // 256   MV = W4b*diag(m3g)*W3   [c][r]
#define C0WT  4864   // 64    C0 = W4a*(m2b+scb)+W4b*m3b
#define BFB   4928   // fp16 B-frags: 2 stages x 2048 shorts = 2048 floats
#define LM1AW 6976   // 48 (+pad 64): LM1A[c][o] = lm1g[o]*lm1W[o][c], c<3
#define WTOT  7040   // floats total

typedef _Float16 half8 __attribute__((ext_vector_type(8)));
typedef _Float16 h2t  __attribute__((ext_vector_type(2)));
typedef float f32x4 __attribute__((ext_vector_type(4)));
union HU { unsigned int u; h2t h; };

__device__ __forceinline__ float redsum16(float v){
    v += __shfl_xor(v, 1); v += __shfl_xor(v, 2);
    v += __shfl_xor(v, 4); v += __shfl_xor(v, 8);
    return v;
}
__device__ __forceinline__ float redmax16(float v){
    v = fmaxf(v, __shfl_xor(v, 1)); v = fmaxf(v, __shfl_xor(v, 2));
    v = fmaxf(v, __shfl_xor(v, 4)); v = fmaxf(v, __shfl_xor(v, 8));
    return v;
}
__device__ __forceinline__ void wsync(){
    __builtin_amdgcn_wave_barrier();
    __threadfence_block();
    __builtin_amdgcn_wave_barrier();
}
__device__ __forceinline__ float frcp(float x){ return __builtin_amdgcn_rcpf(x); }

__device__ __forceinline__ unsigned int ph(float lo, float hi){
    union { _Float16 h[2]; unsigned int u; } cv;
    cv.h[0] = (_Float16)lo; cv.h[1] = (_Float16)hi;
    return cv.u;
}
__device__ __forceinline__ float2 unph(unsigned int u){
    union { unsigned int u; _Float16 h[2]; } cv; cv.u = u;
    return make_float2((float)cv.h[0], (float)cv.h[1]);
}

// sum of |a-b| over 16 fp16 lanes (packed math; |x| via bitmask)
__device__ __forceinline__ float sd16(uint4 a0, uint4 a1, uint4 b0, uint4 b1){
    HU acc; acc.u = 0u;
    #define SDT(A,B) { HU x,y,d; x.u=(A); y.u=(B); d.h = x.h - y.h; \
                       d.u &= 0x7FFF7FFFu; acc.h = acc.h + d.h; }
    SDT(a0.x,b0.x) SDT(a0.y,b0.y) SDT(a0.z,b0.z) SDT(a0.w,b0.w)
    SDT(a1.x,b1.x) SDT(a1.y,b1.y) SDT(a1.z,b1.z) SDT(a1.w,b1.w)
    #undef SDT
    return (float)acc.h[0] + (float)acc.h[1];
}

// Fast atan2 (minimax deg-9; max err ~1.4e-4 rad; atan2(0,0)=0).
__device__ __forceinline__ float fatan2(float y, float x){
    float ax = fabsf(x), ay = fabsf(y);
    float mx = fmaxf(ax, ay), mn = fminf(ax, ay);
    float z = mn * frcp(mx);
    z = (mx == 0.f) ? 0.f : z;
    float z2 = z * z;
    float a = fmaf(0.05265332f, z2, -0.11643287f);
    a = fmaf(a, z2, 0.19354346f);
    a = fmaf(a, z2, -0.33262347f);
    a = fmaf(a, z2, 0.99997726f);
    a = a * z;
    a = (ay > ax) ? (1.5707963268f - a) : a;
    a = (x < 0.f) ? (3.1415926536f - a) : a;
    return (y < 0.f) ? -a : a;
}

// Batch<->XCD affinity swizzles.
__device__ __forceinline__ int swizS(int bid){     // grid 5120 (16 pts/blk)
    int x = bid & 7, s = bid >> 3;
    return x * 640 + s;
}
__device__ __forceinline__ int swizC(int bid){     // grid 1280 (64 pts/blk)
    int x = bid & 7, s = bid >> 3;
    return x * 160 + s;
}

__global__ void k_fill4(float4* out, float val, int n4){
    int i = blockIdx.x * blockDim.x + threadIdx.x;
    int stride = gridDim.x * blockDim.x;
    float4 v = make_float4(val, val, val, val);
    for (; i < n4; i += stride) out[i] = v;
}

// Fused prep (blocks 0..7) + feat0/tables (blocks 8..327).
__global__ __launch_bounds__(256) void k_pre(
    const float* __restrict__ featp, const float* __restrict__ xyzp,
    const float* __restrict__ m1W,  const float* __restrict__ m1g,
    const float* __restrict__ m1b,
    const float* __restrict__ lm1W, const float* __restrict__ lm1g,
    const float* __restrict__ lm1b,
    const float* __restrict__ p1fc, const float* __restrict__ p2fc,
    const float* __restrict__ p1mW, const float* __restrict__ p2mW,
    const float* __restrict__ m2W,  const float* __restrict__ scW,
    const float* __restrict__ m3W,  const float* __restrict__ m4W,
    const float* __restrict__ m2g,  const float* __restrict__ m2b,
    const float* __restrict__ scg,  const float* __restrict__ scb,
    const float* __restrict__ m3g,  const float* __restrict__ m3b,
    float* __restrict__ wb, float* __restrict__ wsF,
    float* __restrict__ outp)
{
    int bid = blockIdx.x;
    if (bid < 8){
        if (bid == 0){
            for (int e = threadIdx.x; e < 512; e += 256)
                wb[P1MWT + e] = p1mW[e];
        } else if (bid == 1){
            for (int e = threadIdx.x; e < 1024; e += 256){
                int c = e >> 5, r = e & 31;
                int k = r >> 1, h = r & 1;
                wb[P2MWT + e] = p2mW[(k + 16*h)*32 + c];
            }
        } else if (bid == 2){
            for (int e = threadIdx.x; e < 2048; e += 256){
                int c = e >> 6, r = e & 63;
                int o = (r >> 2) + 16*(r & 3);
                float acc = 0.f;
                for (int h = 0; h < 64; h++)
                    acc = fmaf(m4W[o*128 + h] * m2g[h], m2W[h*32 + c], acc);
                wb[MAWT + e] = acc;
            }
        } else if (bid == 3){
            for (int e = threadIdx.x; e < 1024; e += 256){
                int c = e >> 6, r = e & 63;
                int o = (r >> 2) + 16*(r & 3);
                float acc = 0.f;
                for (int h = 0; h < 64; h++)
                    acc = fmaf(m4W[o*128 + h] * scg[h], scW[h*16 + c], acc);
                wb[MXWT + e] = acc;
            }
        } else if (bid == 4){
            int e = threadIdx.x;
            if (e < 256){
                int c = e >> 6, r = e & 63;
                int o = (r >> 2) + 16*(r & 3);
                float acc = 0.f;
                for (int h = 0; h < 64; h++)
                    acc = fmaf(m4W[o*128 + 64 + h] * m3g[h], m3W[h*4 + c], acc);
                wb[MVWT + e] = acc;
            }
            if (e < 64){
                int o = (e >> 2) + 16*(e & 3);
                float acc = 0.f;
                for (int h = 0; h < 64; h++){
                    acc = fmaf(m4W[o*128 + h], m2b[h] + scb[h], acc);
                    acc = fmaf(m4W[o*128 + 64 + h], m3b[h], acc);
                }
                wb[C0WT + e] = acc;
            }
        } else if (bid == 5){
            int e = threadIdx.x;
            if (e < 48){
                int c = e >> 4, o = e & 15;
                wb[LM1AW + e] = lm1g[o] * lm1W[o*9 + c];
            }
        } else {   // bid 6,7: fc B-frags (fc[o][c]*LOG2E fp16, 16x16x32 B layout)
            const float* src = (bid == 6) ? p1fc : p2fc;
            short* dst = (short*)(wb + BFB) + (bid - 6) * 2048;
            for (int e = threadIdx.x; e < 2048; e += 256){
                int j = e & 7, l = (e >> 3) & 63, tq = (e >> 9) & 3;
                int q = tq & 1, t = tq >> 1;
                int kk = ((l >> 4) << 3) + j;
                int c = q*32 + kk;
                int o = (l & 15) + 16*t;
                float v = (c < 34) ? src[o*34 + c] * LOG2E : 0.f;
                union { _Float16 h; short s; } cv; cv.h = (_Float16)v;
                dst[e] = cv.s;
            }
        }
        return;
    }
    // ---- feat0h + Hs/Hn tables ----
    int p = (bid - 8) * 256 + threadIdx.x;
    int b = p / NN;
    int n = p - b * NN;
    float x[16];
    #pragma unroll
    for (int c = 0; c < 16; c++) x[c] = featp[(b*16 + c)*NN + n];
    unsigned int dw[8];
    for (int oo = 0; oo < 8; oo++){
        float v0 = 0.f, v1 = 0.f;
        #pragma unroll
        for (int c = 0; c < 16; c++){
            v0 = fmaf(m1W[(2*oo)*16 + c],   x[c], v0);
            v1 = fmaf(m1W[(2*oo+1)*16 + c], x[c], v1);
        }
        v0 = fmaxf(fmaf(m1g[2*oo],   v0, m1b[2*oo]),   0.f);
        v1 = fmaxf(fmaf(m1g[2*oo+1], v1, m1b[2*oo+1]), 0.f);
        dw[oo] = ph(v0, v1);
    }
    uint4* f0 = (uint4*)(outp + (size_t)b*64*NN + (size_t)n*8);
    f0[0] = make_uint4(dw[0], dw[1], dw[2], dw[3]);
    f0[1] = make_uint4(dw[4], dw[5], dw[6], dw[7]);

    float sx = xyzp[p*3 + 0], sy = xyzp[p*3 + 1], sz = xyzp[p*3 + 2];
    unsigned int* outu = (unsigned int*)outp;
    unsigned short* hnT = (unsigned short*)wsF + (size_t)NPTS*16;
    unsigned int hw[8];
    for (int d = 0; d < 8; d++){
        float h0, h1, g0, g1;
        int o0 = 2*d, o1 = 2*d+1;
        h0 = lm1g[o0]*(lm1W[o0*9+3]*sx + lm1W[o0*9+4]*sy + lm1W[o0*9+5]*sz) + lm1b[o0];
        h1 = lm1g[o1]*(lm1W[o1*9+3]*sx + lm1W[o1*9+4]*sy + lm1W[o1*9+5]*sz) + lm1b[o1];
        g0 = lm1g[o0]*(lm1W[o0*9+6]*sx + lm1W[o0*9+7]*sy + lm1W[o0*9+8]*sz);
        g1 = lm1g[o1]*(lm1W[o1*9+6]*sx + lm1W[o1*9+7]*sy + lm1W[o1*9+8]*sz);
        outu[((size_t)b*64 + HSROW + d)*NN + n] = ph(h0, h1);   // Hs(+bias)
        hw[d] = ph(g0, g1);                                      // Hn
    }
    uint4* hq = (uint4*)(hnT + (size_t)p*16);
    hq[0] = make_uint4(hw[0], hw[1], hw[2], hw[3]);
    hq[1] = make_uint4(hw[4], hw[5], hw[6], hw[7]);
}

// Pool one o-tile: softmax over k + attention-weighted sum of X[c][k].
__device__ __forceinline__ float poolT(f32x4 a, const short* base, int c, int g){
    const short* xc = base + c;
    union { short s; _Float16 h; } c0, c1, c2, c3;
    c0.s = xc[(g*4 + 0)*RSH]; c1.s = xc[(g*4 + 1)*RSH];
    c2.s = xc[(g*4 + 2)*RSH]; c3.s = xc[(g*4 + 3)*RSH];
    float x0 = (float)c0.h, x1 = (float)c1.h, x2 = (float)c2.h, x3 = (float)c3.h;
    float m = fmaxf(fmaxf(a[0], a[1]), fmaxf(a[2], a[3]));
    m = fmaxf(m, __shfl_xor(m, 16)); m = fmaxf(m, __shfl_xor(m, 32));
    float e0 = exp2f(a[0] - m), e1 = exp2f(a[1] - m);
    float e2 = exp2f(a[2] - m), e3 = exp2f(a[3] - m);
    float s = (e0 + e1) + (e2 + e3);
    float num = fmaf(e3, x3, fmaf(e2, x2, fmaf(e1, x1, e0*x0)));
    s   += __shfl_xor(s, 16);   s   += __shfl_xor(s, 32);
    num += __shfl_xor(num, 16); num += __shfl_xor(num, 32);
    return num * frcp(s);
}

// Phase B via MFMA: per point D[k][o-tile] = X^T · W^T (K=64; c 34..63 zero).
__device__ __forceinline__ void phaseB_mfma(
    const short* xs, const short* bfS, float* smMid, int tid)
{
    const half8* bf = (const half8*)bfS;
    const int l = tid & 63, wv = tid >> 6;
    const int o = l & 15, g = l >> 4;
    half8 B00 = bf[l], B01 = bf[64 + l], B10 = bf[128 + l], B11 = bf[192 + l];
    #pragma unroll 2
    for (int pp = 0; pp < 4; pp++){
        const int pt = wv*4 + pp;
        const short* base = xs + pt*PTSH;
        const short* rowp = base + (l & 15)*RSH;
        half8 A0 = *(const half8*)(rowp + g*8);     // c = g*8+j
        unsigned int d = *(const unsigned int*)(rowp + 32);  // c32,33
        union { unsigned int u[4]; half8 v; } a1u;
        a1u.u[0] = (g == 0) ? d : 0u;
        a1u.u[1] = 0u; a1u.u[2] = 0u; a1u.u[3] = 0u;
        half8 A1 = a1u.v;                           // c = 32+g*8+j
        f32x4 z = {0.f, 0.f, 0.f, 0.f};
        f32x4 a0 = __builtin_amdgcn_mfma_f32_16x16x32_f16(A0, B00, z, 0, 0, 0);
        a0       = __builtin_amdgcn_mfma_f32_16x16x32_f16(A1, B01, a0, 0, 0, 0);
        f32x4 a1 = __builtin_amdgcn_mfma_f32_16x16x32_f16(A0, B10, z, 0, 0, 0);
        a1       = __builtin_amdgcn_mfma_f32_16x16x32_f16(A1, B11, a1, 0, 0, 0);
        float mid0 = poolT(a0, base, 2 + o,      g);
        float mid1 = poolT(a1, base, 2 + o + 16, g);
        if (g == 0){
            smMid[pt*MS + o]      = mid0;
            smMid[pt*MS + o + 16] = mid1;
        }
    }
}

// lrep[o] = relu(LM1A·(da,db,rd) + Hs'(LDS) + Hn(gathered))  -> 8 ph dwords
__device__ __forceinline__ void lrep16(
    const float* __restrict__ la, float da, float db, float rd,
    const float* hsS, uint4 H0, uint4 H1, unsigned int* lw)
{
    unsigned int hn[8] = {H0.x, H0.y, H0.z, H0.w, H1.x, H1.y, H1.z, H1.w};
    #pragma unroll
    for (int d = 0; d < 8; d++){
        HU a, b, s;
        a.u = __float_as_uint(hsS[d]);
        b.u = hn[d];
        s.h = a.h + b.h;
        int o0 = 2*d, o1 = 2*d+1;
        float v0 = fmaf(la[o0], da, fmaf(la[16+o0], db, la[32+o0]*rd));
        float v1 = fmaf(la[o1], da, fmaf(la[16+o1], db, la[32+o1]*rd));
        v0 = fmaxf(v0 + (float)s.h[0], 0.f);
        v1 = fmaxf(v1 + (float)s.h[1], 0.f);
        lw[d] = ph(v0, v1);
    }
}

// ---------------- Stage 1: 256 thr, 16 pts, 4 independent waves ----------------
__global__ __launch_bounds__(256, 4) void k_stage1(
    const float* __restrict__ xyzp,
    const int* __restrict__ nidx,
    const float* __restrict__ wb,
    const float* __restrict__ p1mg,
    const float* __restrict__ p1mb,
    float* __restrict__ wsF,
    float* __restrict__ outp)
{
    __shared__ float sm[SMS1];
    short* xs = (short*)sm;
    const int k  = threadIdx.x & 15;
    const int pt = threadIdx.x >> 4;
    const int lane = threadIdx.x & 63, wv = threadIdx.x >> 6;
    const int pblk = swizS(blockIdx.x);
    const int p  = (pblk << 4) + pt;
    const int b  = p / NN;
    const int n  = p - b * NN;
    const int nb = (pblk << 4) - b * NN;   // block-base n (16|NN, no straddle)
    unsigned short* hnT = (unsigned short*)wsF + (size_t)NPTS*16;

    // coop Hs load: 32 lanes/wave cover own wave's 4 pts x 8 dwords
    if (lane < 32){
        int lpt = wv*4 + (lane >> 3), d = lane & 7;
        sm[HSOFF + wv*32 + lane] =
            outp[((size_t)b*64 + HSROW + d)*NN + nb + lpt];
    }
    wsync();

    {
        const int ii = nidx[(p << 4) + k];
        const int q  = b * NN + ii;
        const uint4* aq = (const uint4*)(outp + (size_t)b*64*NN + (size_t)ii*8);
        const uint4* ap = (const uint4*)(outp + (size_t)b*64*NN + (size_t)n*8);
        uint4 A0 = aq[0], A1 = aq[1];
        uint4 S0 = ap[0], S1 = ap[1];
        const float sx = xyzp[p*3 + 0];
        const float sy = xyzp[p*3 + 1];
        const float sz = xyzp[p*3 + 2];
        const float nx = xyzp[q*3 + 0];
        const float ny = xyzp[q*3 + 1];
        const float nz = xyzp[q*3 + 2];

        float sd = sd16(A0, A1, S0, S1);
        float fdis2 = 2.f * __expf(-sd * 0.0625f);

        float rx = sx - nx, ry = sy - ny, rz = sz - nz;
        float r2 = rx*rx + ry*ry;
        float rdis = sqrtf(r2 + rz*rz);
        float ralpha = fatan2(ry, rx);
        float rbeta  = fatan2(rz, sqrtf(r2));
        float gdis = __expf(-rdis);

        float mx = redsum16(nx) * 0.0625f;
        float my = redsum16(ny) * 0.0625f;
        float mz = redsum16(nz) * 0.0625f;
        float dx = sx - mx, dy = sy - my, dz = sz - mz;
        float dalpha = fatan2(dy, dx);
        float dbeta  = fatan2(dz, sqrtf(dx*dx + dy*dy));
        float da = ralpha - dalpha, db = rbeta - dbeta;

        float mxd = redmax16(rdis);
        float nr  = sqrtf(sx*sx + sy*sy + sz*sz);

        unsigned int* outu = (unsigned int*)outp;
        outu[((size_t)b*64 + PAROW + k)*NN + n] = ph(da, db);
        outu[((size_t)b*64 + PBROW + k)*NN + n] = ph(rdis, gdis);
        if (k == 0)
            outp[((size_t)b*64 + LGROW)*NN + n] = (mxd*mxd*mxd) * frcp(nr*nr*nr);

        const uint4* hq = (const uint4*)(hnT + (size_t)q*16);
        uint4 H0 = hq[0], H1 = hq[1];
        unsigned int lw[8];
        lrep16(wb + LM1AW, da, db, rdis,
               sm + HSOFF + wv*32 + (pt & 3)*8, H0, H1, lw);

        uint4* rp = (uint4*)(xs + pt*PTSH + k*RSH);
        rp[0] = make_uint4(ph(gdis, fdis2), A0.x, A0.y, A0.z);
        rp[1] = make_uint4(A0.w, A1.x, A1.y, A1.z);
        rp[2] = make_uint4(A1.w, lw[0], lw[1], lw[2]);
        rp[3] = make_uint4(lw[3], lw[4], lw[5], lw[6]);
        rp[4] = make_uint4(lw[7], 0u, 0u, 0u);
    }
    wsync();

    phaseB_mfma(xs, (const short*)(wb + BFB), sm + MIDOFF, threadIdx.x);
    wsync();

    // ---- Phase C: p1m row k -> feat1h (fp16) ----
    {
        float mid[32];
        const float4* mp = (const float4*)(sm + MIDOFF + pt*MS);
        #pragma unroll
        for (int i = 0; i < 8; i++){
            float4 t = mp[i];
            mid[4*i]=t.x; mid[4*i+1]=t.y; mid[4*i+2]=t.z; mid[4*i+3]=t.w;
        }
        const float4* wp = (const float4*)(wb + P1MWT) + (k << 3);
        float acc = 0.f;
        #pragma unroll
        for (int i = 0; i < 8; i++){
            float4 wv4 = wp[i];
            acc = fmaf(wv4.x, mid[4*i],   acc);
            acc = fmaf(wv4.y, mid[4*i+1], acc);
            acc = fmaf(wv4.z, mid[4*i+2], acc);
            acc = fmaf(wv4.w, mid[4*i+3], acc);
        }
        float v = fmaxf(fmaf(p1mg[k], acc, p1mb[k]), 0.f);
        union { _Float16 h; unsigned short s; } cv; cv.h = (_Float16)v;
        ((unsigned short*)wsF)[(size_t)(p << 4) + k] = cv.s;
    }
}

// ---------------- Stage 2AB: 256 thr, 16 pts ----------------
__global__ __launch_bounds__(256, 4) void k_s2ab(
    const int* __restrict__ nidx,
    const float* __restrict__ lm2W,
    const float* __restrict__ lm2g,
    const float* __restrict__ lm2b,
    const float* __restrict__ wb,
    const float* __restrict__ wsF,
    float* __restrict__ outp)
{
    __shared__ float sm[SMS1];
    short* xs = (short*)sm;
    const int k    = threadIdx.x & 15;
    const int pt   = threadIdx.x >> 4;
    const int lane = threadIdx.x & 63, wv = threadIdx.x >> 6;
    const int pblk = swizS(blockIdx.x);
    const int p    = (pblk << 4) + pt;
    const int b    = p / NN;
    const int n    = p - b * NN;
    const int nb   = (pblk << 4) - b * NN;
    const unsigned short* feat1h = (const unsigned short*)wsF;
    const unsigned short* hnT = (const unsigned short*)wsF + (size_t)NPTS*16;

    if (lane < 32){
        int lpt = wv*4 + (lane >> 3), d = lane & 7;
        sm[HSOFF + wv*32 + lane] =
            outp[((size_t)b*64 + HSROW + d)*NN + nb + lpt];
    }
    wsync();

    {
        const int ii = nidx[(p << 4) + k];
        const int q  = b * NN + ii;
        const unsigned int* outu = (const unsigned int*)outp;
        unsigned int pa = outu[((size_t)b*64 + PAROW + k)*NN + n];
        unsigned int pb = outu[((size_t)b*64 + PBROW + k)*NN + n];
        float2 dab = unph(pa);
        HU pbu; pbu.u = pb;
        float rd = (float)pbu.h[0];

        const uint4* aq = (const uint4*)(feat1h + (size_t)q*16);
        const uint4* ap = (const uint4*)(feat1h + (size_t)p*16);
        uint4 A0 = aq[0], A1 = aq[1];
        uint4 S0 = ap[0], S1 = ap[1];
        float sd = sd16(A0, A1, S0, S1);
        float fdis2 = 2.f * __expf(-sd * 0.0625f);

        const uint4* hq = (const uint4*)(hnT + (size_t)q*16);
        uint4 H0 = hq[0], H1 = hq[1];
        unsigned int lw[8];
        lrep16(wb + LM1AW, dab.x, dab.y, rd,
               sm + HSOFF + wv*32 + (pt & 3)*8, H0, H1, lw);

        float lr[16];
        #pragma unroll
        for (int d = 0; d < 8; d++){
            float2 f = unph(lw[d]);
            lr[2*d] = f.x; lr[2*d+1] = f.y;
        }
        unsigned int l2[8];
        for (int oo = 0; oo < 8; oo++){
            float v0 = 0.f, v1 = 0.f;
            #pragma unroll
            for (int c = 0; c < 16; c++){
                v0 = fmaf(lm2W[(2*oo)*16 + c],   lr[c], v0);
                v1 = fmaf(lm2W[(2*oo+1)*16 + c], lr[c], v1);
            }
            v0 = fmaxf(fmaf(lm2g[2*oo],   v0, lm2b[2*oo]),   0.f);
            v1 = fmaxf(fmaf(lm2g[2*oo+1], v1, lm2b[2*oo+1]), 0.f);
            l2[oo] = ph(v0, v1);
        }

        HU g0; g0.h[0] = pbu.h[1]; g0.h[1] = (_Float16)fdis2;  // gdis,fdis2
        uint4* rp = (uint4*)(xs + pt*PTSH + k*RSH);
        rp[0] = make_uint4(g0.u, A0.x, A0.y, A0.z);
        rp[1] = make_uint4(A0.w, A1.x, A1.y, A1.z);
        rp[2] = make_uint4(A1.w, l2[0], l2[1], l2[2]);
        rp[3] = make_uint4(l2[3], l2[4], l2[5], l2[6]);
        rp[4] = make_uint4(l2[7], 0u, 0u, 0u);
    }
    wsync();

    phaseB_mfma(xs, (const short*)(wb + BFB) + 2048, sm + MIDOFF, threadIdx.x);
    wsync();

    {
        float m0 = sm[MIDOFF + pt*MS + 2*k];
        float m1 = sm[MIDOFF + pt*MS + 2*k + 1];
        ((unsigned int*)outp)[(size_t)(b*64 + k)*NN + n] = ph(m0, m1);
    }
}

// ---------------- Stage 2C: folded matvecs, 64 pts/block ----------------
#define WL_P2M 0     // 1024
#define WL_MA  1024  // 2048
#define WL_MX  3072  // 1024
#define WL_MV  4096  // 256
#define WL_C0  4352  // 64
#define WOFF   4416
#define SLAB   1280
#define LGRO   (WOFF + 4*SLAB)
#define SMTOT2 9600

__global__ __launch_bounds__(256, 2) void k_s2c(
    const float* __restrict__ featp,
    const float* __restrict__ xyzp,
    const float* __restrict__ wb,
    const float* __restrict__ p2mg,
    const float* __restrict__ p2mb,
    const float* __restrict__ m4g,
    const float* __restrict__ m4b,
    float* __restrict__ outp)
{
    __shared__ float sm[SMTOT2];
    const int tid = threadIdx.x;
    const int k   = tid & 15;
    const int g   = (tid >> 4) & 3;
    const int w   = tid >> 6;
    const int pblk = swizC(blockIdx.x);
    const int p0  = pblk << 6;
    const int b   = p0 / NN;
    const int n0  = p0 - b * NN;
    const int ptg = g*4;
    const int nT  = n0 + w*16 + ptg;
    float* slab = sm + WOFF + w*SLAB;

    for (int e = tid; e < 4416; e += 256) sm[e] = wb[512 + e];
    {
        uint4 um = *(const uint4*)((const unsigned int*)outp +
                                   (size_t)(b*64 + k)*NN + nT);
        float2 f;
        f = unph(um.x);
        slab[(ptg+0)*36 + 2*k] = f.x; slab[(ptg+0)*36 + 2*k+1] = f.y;
        f = unph(um.y);
        slab[(ptg+1)*36 + 2*k] = f.x; slab[(ptg+1)*36 + 2*k+1] = f.y;
        f = unph(um.z);
        slab[(ptg+2)*36 + 2*k] = f.x; slab[(ptg+2)*36 + 2*k+1] = f.y;
        f = unph(um.w);
        slab[(ptg+3)*36 + 2*k] = f.x; slab[(ptg+3)*36 + 2*k+1] = f.y;
        if (k == 0){
            float4 lv = *(const float4*)(outp + (size_t)(b*64 + LGROW)*NN + nT);
            sm[LGRO + w*16 + ptg + 0] = lv.x; sm[LGRO + w*16 + ptg + 1] = lv.y;
            sm[LGRO + w*16 + ptg + 2] = lv.z; sm[LGRO + w*16 + ptg + 3] = lv.w;
        }
    }
    __syncthreads();

    {
        const float2* wp = (const float2*)(sm + WL_P2M);
        float aA[4] = {0.f,0.f,0.f,0.f}, aB[4] = {0.f,0.f,0.f,0.f};
        #pragma unroll 2
        for (int cq = 0; cq < 8; cq++){
            f32x4 mv[4];
            #pragma unroll
            for (int i = 0; i < 4; i++)
                mv[i] = *(const f32x4*)(slab + (ptg+i)*36 + cq*4);
            #pragma unroll
            for (int cc = 0; cc < 4; cc++){
                float2 wv = wp[(cq*4+cc)*16 + k];
                #pragma unroll
                for (int i = 0; i < 4; i++){
                    aA[i] = fmaf(wv.x, mv[i][cc], aA[i]);
                    aB[i] = fmaf(wv.y, mv[i][cc], aB[i]);
                }
            }
        }
        float gA = p2mg[k], bA = p2mb[k], gB = p2mg[k+16], bB = p2mb[k+16];
        #pragma unroll
        for (int i = 0; i < 4; i++){
            slab[576 + (ptg+i)*36 + k]      = fmaxf(fmaf(gA, aA[i], bA), 0.f);
            slab[576 + (ptg+i)*36 + k + 16] = fmaxf(fmaf(gB, aB[i], bB), 0.f);
        }
    }
    wsync();

    float o4[4][4];
    {
        f32x4 c0v = *(const f32x4*)(sm + WL_C0 + 4*k);
        #pragma unroll
        for (int j = 0; j < 4; j++)
            #pragma unroll
            for (int i = 0; i < 4; i++) o4[j][i] = c0v[j];

        const f32x4* wa = (const f32x4*)(sm + WL_MA);
        #pragma unroll 2
        for (int cq = 0; cq < 8; cq++){
            f32x4 av[4];
            #pragma unroll
            for (int i = 0; i < 4; i++)
                av[i] = *(const f32x4*)(slab + 576 + (ptg+i)*36 + cq*4);
            #pragma unroll
            for (int cc = 0; cc < 4; cc++){
                f32x4 wv = wa[(cq*4+cc)*16 + k];
                #pragma unroll
                for (int i = 0; i < 4; i++){
                    #pragma unroll
                    for (int j = 0; j < 4; j++)
                        o4[j][i] = fmaf(wv[j], av[i][cc], o4[j][i]);
                }
            }
        }
        const f32x4* wx = (const f32x4*)(sm + WL_MX);
        #pragma unroll 4
        for (int c = 0; c < 16; c++){
            f32x4 wv = wx[c*16 + k];
            f32x4 xv = *(const f32x4*)(featp + (size_t)(b*16 + c)*NN + nT);
            #pragma unroll
            for (int i = 0; i < 4; i++){
                #pragma unroll
                for (int j = 0; j < 4; j++)
                    o4[j][i] = fmaf(wv[j], xv[i], o4[j][i]);
            }
        }
        const f32x4* wvv = (const f32x4*)(sm + WL_MV);
        #pragma unroll
        for (int c = 0; c < 3; c++){
            f32x4 wv = wvv[c*16 + k];
            #pragma unroll
            for (int i = 0; i < 4; i++){
                float vc = xyzp[(size_t)(p0 + w*16 + ptg + i)*3 + c];
                #pragma unroll
                for (int j = 0; j < 4; j++)
                    o4[j][i] = fmaf(wv[j], vc, o4[j][i]);
            }
        }
        {
            f32x4 wv = wvv[3*16 + k];
            #pragma unroll
            for (int i = 0; i < 4; i++){
                float vc = sm[LGRO + w*16 + ptg + i];
                #pragma unroll
                for (int j = 0; j < 4; j++)
                    o4[j][i] = fmaf(wv[j], vc, o4[j][i]);
            }
        }
    }
    wsync();

    {
        float* stg = slab;
        #pragma unroll
        for (int j = 0; j < 4; j++){
            int oo = k + 16*j;
            float gv = m4g[oo], bv = m4b[oo];
            #pragma unroll
            for (int i = 0; i < 4; i++)
                stg[oo*20 + ptg + i] = fmaxf(fmaf(gv, o4[j][i], bv), 0.f);
        }
        wsync();
        const int l = tid & 63;
        float* dst = outp + (size_t)(b*64 + l)*NN + n0 + w*16;
        #pragma unroll
        for (int q = 0; q < 4; q++){
            f32x4 v = *(const f32x4*)(stg + l*20 + q*4);
            *(f32x4*)(dst + q*4) = v;
        }
    }
}

extern "C" void kernel_launch(void* const* d_in, const int* in_sizes, int n_in,
                              void* d_out, int out_size, void* d_ws, size_t ws_size,
                              hipStream_t stream) {
    float* outp = (float*)d_out;

    float fillv = 1.0f;
    bool ok = true;
    if (n_in != 32) { fillv = 5.0f; ok = false; }
    else if (in_sizes[0] != 1310720 || in_sizes[1] != 245760 ||
             in_sizes[31] != 1310720) { fillv = 7.0f; ok = false; }
    else if (out_size != 5242880) { fillv = 9.0f; ok = false; }
    else if (ws_size < ((size_t)NPTS * 16 + WTOT) * sizeof(float)) { fillv = 11.0f; ok = false; }

    if (!ok){
        k_fill4<<<1024, 256, 0, stream>>>((float4*)outp, fillv, out_size/4);
        return;
    }

    const float* featp = (const float*)d_in[0];
    const float* xyzp  = (const float*)d_in[1];
    const int*   nidx  = (const int*)d_in[31];

    float* wsF = (float*)d_ws;
    float* wb  = (float*)d_ws + (size_t)NPTS * 16;

    #define W(i) ((const float*)d_in[2 + (i)])
    k_pre<<<8 + NPTS/256, 256, 0, stream>>>(
        featp, xyzp,
        W(0), W(1), W(2),          // m1
        W(3), W(4), W(5),          // lm1
        W(9), W(13),               // p1fc, p2fc
        W(10), W(14),              // p1mW, p2mW
        W(17), W(20), W(23), W(26),// m2W, scW, m3W, m4W
        W(18), W(19), W(21), W(22), W(24), W(25),  // m2/sc/m3 g,b
        wb, wsF, outp);
    k_stage1<<<NPTS/16, 256, 0, stream>>>(xyzp, nidx, wb,
        W(11), W(12),              // p1m g/b
        wsF, outp);
    k_s2ab<<<NPTS/16, 256, 0, stream>>>(nidx,
        W(6), W(7), W(8),          // lm2
        wb, wsF, outp);
    k_s2c<<<NPTS/64, 256, 0, stream>>>(featp, xyzp, wb,
        W(15), W(16),              // p2m g/b
        W(27), W(28),              // m4 g/b
        outp);
    #undef W
}

// Round 10
// 244.498 us; speedup vs baseline: 1.4584x; 1.0175x over previous
//
#include <hip/hip_runtime.h>

#define NN 20480
#define NPTS 81920   // B(4) * N(20480)
#define MS 36        // MID row stride (floats)
#define RSH 36       // X row stride in shorts (72 B: 18 dwords, gcd(18,32)=2
                     // -> b128 row reads spread over 16 bank-groups, not 8)
#define PTSH 584     // X shorts per point (16*36=576 +8 pad) -> 292 dwords,
                     // %32=4: wave's 4 points start at bank quads 0/4/8/12
#define MIDOFF 4672  // MID region (X = 16*584 shorts = 4672 f)
#define HSOFF  5248  // hs region (4 waves x 32 dwords)
#define SMS1   5376  // stage1/s2ab LDS floats (21.5 KB)
#define LOG2E 1.4426950408889634f

// d_out scratch rows (per batch, rows 17..63 dead until s2c writes):
#define HSROW 17
#define PAROW 25
#define PBROW 41
#define LGROW 57

// fp32 weight offsets in wb (floats):
#define P1MWT 0      // 512   p1m [k][c] row-direct
#define P2MWT 512    // 1024  p2m [c][k*2+h]
#define MAWT  1536   // 2048  MA = W4a*diag(m2g)*W2   [c][k*4+j]
#define MXWT  3584   // 1024  MX = W4a*diag(scg)*Ws   [c][r]
#define MVWT  4608   // 256   MV = W4b*diag(m3g)*W3   [c][r]
#define C0WT  4864   // 64    C0 = W4a*(m2b+scb)+W4b*m3b
#define BFB   4928   // fp16 B-frags: 2 stages x 2048 shorts = 2048 floats
#define LM1AW 6976   // 24 dwords: packed fp16 pairs LM1A[c][d]=(o=2d,2d+1)
#define LM2HW 7008   // 128 dwords: packed fp16 lm2g-folded [o][cc]=(c=2cc,2cc+1)
#define WTOT  7136   // floats total

typedef _Float16 half8 __attribute__((ext_vector_type(8)));
typedef _Float16 h2t  __attribute__((ext_vector_type(2)));
typedef float f32x4 __attribute__((ext_vector_type(4)));
union HU { unsigned int u; h2t h; };

__device__ __forceinline__ float redsum16(float v){
    v += __shfl_xor(v, 1); v += __shfl_xor(v, 2);
    v += __shfl_xor(v, 4); v += __shfl_xor(v, 8);
    return v;
}
__device__ __forceinline__ float redmax16(float v){
    v = fmaxf(v, __shfl_xor(v, 1)); v = fmaxf(v, __shfl_xor(v, 2));
    v = fmaxf(v, __shfl_xor(v, 4)); v = fmaxf(v, __shfl_xor(v, 8));
    return v;
}
__device__ __forceinline__ void wsync(){
    __builtin_amdgcn_wave_barrier();
    __threadfence_block();
    __builtin_amdgcn_wave_barrier();
}
__device__ __forceinline__ float frcp(float x){ return __builtin_amdgcn_rcpf(x); }

__device__ __forceinline__ unsigned int ph(float lo, float hi){
    union { _Float16 h[2]; unsigned int u; } cv;
    cv.h[0] = (_Float16)lo; cv.h[1] = (_Float16)hi;
    return cv.u;
}
__device__ __forceinline__ float2 unph(unsigned int u){
    union { unsigned int u; _Float16 h[2]; } cv; cv.u = u;
    return make_float2((float)cv.h[0], (float)cv.h[1]);
}

// sum of |a-b| over 16 fp16 lanes (packed math; |x| via bitmask)
__device__ __forceinline__ float sd16(uint4 a0, uint4 a1, uint4 b0, uint4 b1){
    HU acc; acc.u = 0u;
    #define SDT(A,B) { HU x,y,d; x.u=(A); y.u=(B); d.h = x.h - y.h; \
                       d.u &= 0x7FFF7FFFu; acc.h = acc.h + d.h; }
    SDT(a0.x,b0.x) SDT(a0.y,b0.y) SDT(a0.z,b0.z) SDT(a0.w,b0.w)
    SDT(a1.x,b1.x) SDT(a1.y,b1.y) SDT(a1.z,b1.z) SDT(a1.w,b1.w)
    #undef SDT
    return (float)acc.h[0] + (float)acc.h[1];
}

// Fast atan2 (minimax deg-9; max err ~1.4e-4 rad; atan2(0,0)=0).
__device__ __forceinline__ float fatan2(float y, float x){
    float ax = fabsf(x), ay = fabsf(y);
    float mx = fmaxf(ax, ay), mn = fminf(ax, ay);
    float z = mn * frcp(mx);
    z = (mx == 0.f) ? 0.f : z;
    float z2 = z * z;
    float a = fmaf(0.05265332f, z2, -0.11643287f);
    a = fmaf(a, z2, 0.19354346f);
    a = fmaf(a, z2, -0.33262347f);
    a = fmaf(a, z2, 0.99997726f);
    a = a * z;
    a = (ay > ax) ? (1.5707963268f - a) : a;
    a = (x < 0.f) ? (3.1415926536f - a) : a;
    return (y < 0.f) ? -a : a;
}

// Batch<->XCD affinity swizzles.
__device__ __forceinline__ int swizS(int bid){     // grid 5120 (16 pts/blk)
    int x = bid & 7, s = bid >> 3;
    return x * 640 + s;
}
__device__ __forceinline__ int swizC(int bid){     // grid 1280 (64 pts/blk)
    int x = bid & 7, s = bid >> 3;
    return x * 160 + s;
}

__global__ void k_fill4(float4* out, float val, int n4){
    int i = blockIdx.x * blockDim.x + threadIdx.x;
    int stride = gridDim.x * blockDim.x;
    float4 v = make_float4(val, val, val, val);
    for (; i < n4; i += stride) out[i] = v;
}

// Fused prep (blocks 0..7) + feat0/tables (blocks 8..327).
__global__ __launch_bounds__(256) void k_pre(
    const float* __restrict__ featp, const float* __restrict__ xyzp,
    const float* __restrict__ m1W,  const float* __restrict__ m1g,
    const float* __restrict__ m1b,
    const float* __restrict__ lm1W, const float* __restrict__ lm1g,
    const float* __restrict__ lm1b,
    const float* __restrict__ lm2W, const float* __restrict__ lm2g,
    const float* __restrict__ p1fc, const float* __restrict__ p2fc,
    const float* __restrict__ p1mW, const float* __restrict__ p2mW,
    const float* __restrict__ m2W,  const float* __restrict__ scW,
    const float* __restrict__ m3W,  const float* __restrict__ m4W,
    const float* __restrict__ m2g,  const float* __restrict__ m2b,
    const float* __restrict__ scg,  const float* __restrict__ scb,
    const float* __restrict__ m3g,  const float* __restrict__ m3b,
    float* __restrict__ wb, float* __restrict__ wsF,
    float* __restrict__ outp)
{
    int bid = blockIdx.x;
    if (bid < 8){
        if (bid == 0){
            for (int e = threadIdx.x; e < 512; e += 256)
                wb[P1MWT + e] = p1mW[e];
        } else if (bid == 1){
            for (int e = threadIdx.x; e < 1024; e += 256){
                int c = e >> 5, r = e & 31;
                int k = r >> 1, h = r & 1;
                wb[P2MWT + e] = p2mW[(k + 16*h)*32 + c];
            }
        } else if (bid == 2){
            for (int e = threadIdx.x; e < 2048; e += 256){
                int c = e >> 6, r = e & 63;
                int o = (r >> 2) + 16*(r & 3);
                float acc = 0.f;
                for (int h = 0; h < 64; h++)
                    acc = fmaf(m4W[o*128 + h] * m2g[h], m2W[h*32 + c], acc);
                wb[MAWT + e] = acc;
            }
        } else if (bid == 3){
            for (int e = threadIdx.x; e < 1024; e += 256){
                int c = e >> 6, r = e & 63;
                int o = (r >> 2) + 16*(r & 3);
                float acc = 0.f;
                for (int h = 0; h < 64; h++)
                    acc = fmaf(m4W[o*128 + h] * scg[h], scW[h*16 + c], acc);
                wb[MXWT + e] = acc;
            }
        } else if (bid == 4){
            int e = threadIdx.x;
            if (e < 256){
                int c = e >> 6, r = e & 63;
                int o = (r >> 2) + 16*(r & 3);
                float acc = 0.f;
                for (int h = 0; h < 64; h++)
                    acc = fmaf(m4W[o*128 + 64 + h] * m3g[h], m3W[h*4 + c], acc);
                wb[MVWT + e] = acc;
            }
            if (e < 64){
                int o = (e >> 2) + 16*(e & 3);
                float acc = 0.f;
                for (int h = 0; h < 64; h++){
                    acc = fmaf(m4W[o*128 + h], m2b[h] + scb[h], acc);
                    acc = fmaf(m4W[o*128 + 64 + h], m3b[h], acc);
                }
                wb[C0WT + e] = acc;
            }
        } else if (bid == 5){
            int e = threadIdx.x;
            if (e < 24){   // LM1A packed pairs [c][d]: outputs (2d, 2d+1)
                int c = e >> 3, d = e & 7;
                ((unsigned int*)(wb + LM1AW))[e] =
                    ph(lm1g[2*d]   * lm1W[(2*d)*9   + c],
                       lm1g[2*d+1] * lm1W[(2*d+1)*9 + c]);
            }
            if (e >= 32 && e < 160){  // LM2H [o][cc]: lm2g-folded pairs
                int o = (e - 32) >> 3, cc = (e - 32) & 7;
                ((unsigned int*)(wb + LM2HW))[e - 32] =
                    ph(lm2g[o] * lm2W[o*16 + 2*cc],
                       lm2g[o] * lm2W[o*16 + 2*cc + 1]);
            }
        } else {   // bid 6,7: fc B-frags (fc[o][c]*LOG2E fp16, 16x16x32 B layout)
            const float* src = (bid == 6) ? p1fc : p2fc;
            short* dst = (short*)(wb + BFB) + (bid - 6) * 2048;
            for (int e = threadIdx.x; e < 2048; e += 256){
                int j = e & 7, l = (e >> 3) & 63, tq = (e >> 9) & 3;
                int q = tq & 1, t = tq >> 1;
                int kk = ((l >> 4) << 3) + j;
                int c = q*32 + kk;
                int o = (l & 15) + 16*t;
                float v = (c < 34) ? src[o*34 + c] * LOG2E : 0.f;
                union { _Float16 h; short s; } cv; cv.h = (_Float16)v;
                dst[e] = cv.s;
            }
        }
        return;
    }
    // ---- feat0h + Hs/Hn tables ----
    int p = (bid - 8) * 256 + threadIdx.x;
    int b = p / NN;
    int n = p - b * NN;
    float x[16];
    #pragma unroll
    for (int c = 0; c < 16; c++) x[c] = featp[(b*16 + c)*NN + n];
    unsigned int dw[8];
    for (int oo = 0; oo < 8; oo++){
        float v0 = 0.f, v1 = 0.f;
        #pragma unroll
        for (int c = 0; c < 16; c++){
            v0 = fmaf(m1W[(2*oo)*16 + c],   x[c], v0);
            v1 = fmaf(m1W[(2*oo+1)*16 + c], x[c], v1);
        }
        v0 = fmaxf(fmaf(m1g[2*oo],   v0, m1b[2*oo]),   0.f);
        v1 = fmaxf(fmaf(m1g[2*oo+1], v1, m1b[2*oo+1]), 0.f);
        dw[oo] = ph(v0, v1);
    }
    uint4* f0 = (uint4*)(outp + (size_t)b*64*NN + (size_t)n*8);
    f0[0] = make_uint4(dw[0], dw[1], dw[2], dw[3]);
    f0[1] = make_uint4(dw[4], dw[5], dw[6], dw[7]);

    float sx = xyzp[p*3 + 0], sy = xyzp[p*3 + 1], sz = xyzp[p*3 + 2];
    unsigned int* outu = (unsigned int*)outp;
    unsigned short* hnT = (unsigned short*)wsF + (size_t)NPTS*16;
    unsigned int hw[8];
    for (int d = 0; d < 8; d++){
        float h0, h1, g0, g1;
        int o0 = 2*d, o1 = 2*d+1;
        h0 = lm1g[o0]*(lm1W[o0*9+3]*sx + lm1W[o0*9+4]*sy + lm1W[o0*9+5]*sz) + lm1b[o0];
        h1 = lm1g[o1]*(lm1W[o1*9+3]*sx + lm1W[o1*9+4]*sy + lm1W[o1*9+5]*sz) + lm1b[o1];
        g0 = lm1g[o0]*(lm1W[o0*9+6]*sx + lm1W[o0*9+7]*sy + lm1W[o0*9+8]*sz);
        g1 = lm1g[o1]*(lm1W[o1*9+6]*sx + lm1W[o1*9+7]*sy + lm1W[o1*9+8]*sz);
        outu[((size_t)b*64 + HSROW + d)*NN + n] = ph(h0, h1);   // Hs(+bias)
        hw[d] = ph(g0, g1);                                      // Hn
    }
    uint4* hq = (uint4*)(hnT + (size_t)p*16);
    hq[0] = make_uint4(hw[0], hw[1], hw[2], hw[3]);
    hq[1] = make_uint4(hw[4], hw[5], hw[6], hw[7]);
}

// Pool one o-tile: softmax over k + attention-weighted sum of X[c][k].
__device__ __forceinline__ float poolT(f32x4 a, const short* base, int c, int g){
    const short* xc = base + c;
    union { short s; _Float16 h; } c0, c1, c2, c3;
    c0.s = xc[(g*4 + 0)*RSH]; c1.s = xc[(g*4 + 1)*RSH];
    c2.s = xc[(g*4 + 2)*RSH]; c3.s = xc[(g*4 + 3)*RSH];
    float x0 = (float)c0.h, x1 = (float)c1.h, x2 = (float)c2.h, x3 = (float)c3.h;
    float m = fmaxf(fmaxf(a[0], a[1]), fmaxf(a[2], a[3]));
    m = fmaxf(m, __shfl_xor(m, 16)); m = fmaxf(m, __shfl_xor(m, 32));
    float e0 = exp2f(a[0] - m), e1 = exp2f(a[1] - m);
    float e2 = exp2f(a[2] - m), e3 = exp2f(a[3] - m);
    float s = (e0 + e1) + (e2 + e3);
    float num = fmaf(e3, x3, fmaf(e2, x2, fmaf(e1, x1, e0*x0)));
    s   += __shfl_xor(s, 16);   s   += __shfl_xor(s, 32);
    num += __shfl_xor(num, 16); num += __shfl_xor(num, 32);
    return num * frcp(s);
}

// Phase B via MFMA: per point D[k][o-tile] = X^T · W^T (K=64; c 34..63 zero).
__device__ __forceinline__ void phaseB_mfma(
    const short* xs, const short* bfS, float* smMid, int tid)
{
    const half8* bf = (const half8*)bfS;
    const int l = tid & 63, wv = tid >> 6;
    const int o = l & 15, g = l >> 4;
    half8 B00 = bf[l], B01 = bf[64 + l], B10 = bf[128 + l], B11 = bf[192 + l];
    #pragma unroll 2
    for (int pp = 0; pp < 4; pp++){
        const int pt = wv*4 + pp;
        const short* base = xs + pt*PTSH;
        const short* rowp = base + (l & 15)*RSH;
        half8 A0 = *(const half8*)(rowp + g*8);     // c = g*8+j
        unsigned int d = *(const unsigned int*)(rowp + 32);  // c32,33
        union { unsigned int u[4]; half8 v; } a1u;
        a1u.u[0] = (g == 0) ? d : 0u;
        a1u.u[1] = 0u; a1u.u[2] = 0u; a1u.u[3] = 0u;
        half8 A1 = a1u.v;                           // c = 32+g*8+j
        f32x4 z = {0.f, 0.f, 0.f, 0.f};
        f32x4 a0 = __builtin_amdgcn_mfma_f32_16x16x32_f16(A0, B00, z, 0, 0, 0);
        a0       = __builtin_amdgcn_mfma_f32_16x16x32_f16(A1, B01, a0, 0, 0, 0);
        f32x4 a1 = __builtin_amdgcn_mfma_f32_16x16x32_f16(A0, B10, z, 0, 0, 0);
        a1       = __builtin_amdgcn_mfma_f32_16x16x32_f16(A1, B11, a1, 0, 0, 0);
        float mid0 = poolT(a0, base, 2 + o,      g);
        float mid1 = poolT(a1, base, 2 + o + 16, g);
        if (g == 0){
            smMid[pt*MS + o]      = mid0;
            smMid[pt*MS + o + 16] = mid1;
        }
    }
}

// Packed-fp16 lrep: lw[d] = relu_pk(LM1A·(da,db,rd) + Hs + Hn)
// relu via (x+|x|)*0.5 (exact for fp16 normals; 0 for negatives).
__device__ __forceinline__ void lrep16p(
    const unsigned int* __restrict__ laU, float da, float db, float rd,
    const float* hsS, uint4 H0, uint4 H1, unsigned int* lw)
{
    h2t vda, vdb, vrd, vhalf;
    vda[0] = (_Float16)da; vda[1] = vda[0];
    vdb[0] = (_Float16)db; vdb[1] = vdb[0];
    vrd[0] = (_Float16)rd; vrd[1] = vrd[0];
    vhalf[0] = (_Float16)0.5f; vhalf[1] = vhalf[0];
    unsigned int hn[8] = {H0.x, H0.y, H0.z, H0.w, H1.x, H1.y, H1.z, H1.w};
    #pragma unroll
    for (int d = 0; d < 8; d++){
        HU a, b, w0, w1, w2, acc, ab;
        a.u = __float_as_uint(hsS[d]);
        b.u = hn[d];
        w0.u = laU[d]; w1.u = laU[8 + d]; w2.u = laU[16 + d];
        acc.h = a.h + b.h;
        acc.h = acc.h + w0.h * vda;
        acc.h = acc.h + w1.h * vdb;
        acc.h = acc.h + w2.h * vrd;
        ab.u = acc.u & 0x7FFF7FFFu;
        acc.h = (acc.h + ab.h) * vhalf;
        lw[d] = acc.u;
    }
}

// ---------------- Stage 1: 256 thr, 16 pts, 4 independent waves ----------------
__global__ __launch_bounds__(256, 4) void k_stage1(
    const float* __restrict__ xyzp,
    const int* __restrict__ nidx,
    const float* __restrict__ wb,
    const float* __restrict__ p1mg,
    const float* __restrict__ p1mb,
    float* __restrict__ wsF,
    float* __restrict__ outp)
{
    __shared__ float sm[SMS1];
    short* xs = (short*)sm;
    const int k  = threadIdx.x & 15;
    const int pt = threadIdx.x >> 4;
    const int lane = threadIdx.x & 63, wv = threadIdx.x >> 6;
    const int pblk = swizS(blockIdx.x);
    const int p  = (pblk << 4) + pt;
    const int b  = p / NN;
    const int n  = p - b * NN;
    const int nb = (pblk << 4) - b * NN;   // block-base n (16|NN, no straddle)
    unsigned short* hnT = (unsigned short*)wsF + (size_t)NPTS*16;

    if (lane < 32){
        int lpt = wv*4 + (lane >> 3), d = lane & 7;
        sm[HSOFF + wv*32 + lane] =
            outp[((size_t)b*64 + HSROW + d)*NN + nb + lpt];
    }
    wsync();

    {
        const int ii = nidx[(p << 4) + k];
        const int q  = b * NN + ii;
        const uint4* aq = (const uint4*)(outp + (size_t)b*64*NN + (size_t)ii*8);
        const uint4* ap = (const uint4*)(outp + (size_t)b*64*NN + (size_t)n*8);
        uint4 A0 = aq[0], A1 = aq[1];
        uint4 S0 = ap[0], S1 = ap[1];
        const float sx = xyzp[p*3 + 0];
        const float sy = xyzp[p*3 + 1];
        const float sz = xyzp[p*3 + 2];
        const float nx = xyzp[q*3 + 0];
        const float ny = xyzp[q*3 + 1];
        const float nz = xyzp[q*3 + 2];

        float sd = sd16(A0, A1, S0, S1);
        float fdis2 = 2.f * __expf(-sd * 0.0625f);

        float rx = sx - nx, ry = sy - ny, rz = sz - nz;
        float r2 = rx*rx + ry*ry;
        float rdis = sqrtf(r2 + rz*rz);
        float ralpha = fatan2(ry, rx);
        float rbeta  = fatan2(rz, sqrtf(r2));
        float gdis = __expf(-rdis);

        float mx = redsum16(nx) * 0.0625f;
        float my = redsum16(ny) * 0.0625f;
        float mz = redsum16(nz) * 0.0625f;
        float dx = sx - mx, dy = sy - my, dz = sz - mz;
        float dalpha = fatan2(dy, dx);
        float dbeta  = fatan2(dz, sqrtf(dx*dx + dy*dy));
        float da = ralpha - dalpha, db = rbeta - dbeta;

        float mxd = redmax16(rdis);
        float nr  = sqrtf(sx*sx + sy*sy + sz*sz);

        unsigned int* outu = (unsigned int*)outp;
        outu[((size_t)b*64 + PAROW + k)*NN + n] = ph(da, db);
        outu[((size_t)b*64 + PBROW + k)*NN + n] = ph(rdis, gdis);
        if (k == 0)
            outp[((size_t)b*64 + LGROW)*NN + n] = (mxd*mxd*mxd) * frcp(nr*nr*nr);

        const uint4* hq = (const uint4*)(hnT + (size_t)q*16);
        uint4 H0 = hq[0], H1 = hq[1];
        unsigned int lw[8];
        lrep16p((const unsigned int*)(wb + LM1AW), da, db, rdis,
                sm + HSOFF + wv*32 + (pt & 3)*8, H0, H1, lw);

        uint4* rp = (uint4*)(xs + pt*PTSH + k*RSH);
        rp[0] = make_uint4(ph(gdis, fdis2), A0.x, A0.y, A0.z);
        rp[1] = make_uint4(A0.w, A1.x, A1.y, A1.z);
        rp[2] = make_uint4(A1.w, lw[0], lw[1], lw[2]);
        rp[3] = make_uint4(lw[3], lw[4], lw[5], lw[6]);
        ((unsigned int*)rp)[16] = lw[7];   // shorts 32..33
    }
    wsync();

    phaseB_mfma(xs, (const short*)(wb + BFB), sm + MIDOFF, threadIdx.x);
    wsync();

    // ---- Phase C: p1m row k -> feat1h (fp16) ----
    {
        float mid[32];
        const float4* mp = (const float4*)(sm + MIDOFF + pt*MS);
        #pragma unroll
        for (int i = 0; i < 8; i++){
            float4 t = mp[i];
            mid[4*i]=t.x; mid[4*i+1]=t.y; mid[4*i+2]=t.z; mid[4*i+3]=t.w;
        }
        const float4* wp = (const float4*)(wb + P1MWT) + (k << 3);
        float acc = 0.f;
        #pragma unroll
        for (int i = 0; i < 8; i++){
            float4 wv4 = wp[i];
            acc = fmaf(wv4.x, mid[4*i],   acc);
            acc = fmaf(wv4.y, mid[4*i+1], acc);
            acc = fmaf(wv4.z, mid[4*i+2], acc);
            acc = fmaf(wv4.w, mid[4*i+3], acc);
        }
        float v = fmaxf(fmaf(p1mg[k], acc, p1mb[k]), 0.f);
        union { _Float16 h; unsigned short s; } cv; cv.h = (_Float16)v;
        ((unsigned short*)wsF)[(size_t)(p << 4) + k] = cv.s;
    }
}

// ---------------- Stage 2AB: 256 thr, 16 pts ----------------
__global__ __launch_bounds__(256, 4) void k_s2ab(
    const int* __restrict__ nidx,
    const float* __restrict__ lm2b,
    const float* __restrict__ wb,
    const float* __restrict__ wsF,
    float* __restrict__ outp)
{
    __shared__ float sm[SMS1];
    short* xs = (short*)sm;
    const int k    = threadIdx.x & 15;
    const int pt   = threadIdx.x >> 4;
    const int lane = threadIdx.x & 63, wv = threadIdx.x >> 6;
    const int pblk = swizS(blockIdx.x);
    const int p    = (pblk << 4) + pt;
    const int b    = p / NN;
    const int n    = p - b * NN;
    const int nb   = (pblk << 4) - b * NN;
    const unsigned short* feat1h = (const unsigned short*)wsF;
    const unsigned short* hnT = (const unsigned short*)wsF + (size_t)NPTS*16;

    if (lane < 32){
        int lpt = wv*4 + (lane >> 3), d = lane & 7;
        sm[HSOFF + wv*32 + lane] =
            outp[((size_t)b*64 + HSROW + d)*NN + nb + lpt];
    }
    wsync();

    {
        const int ii = nidx[(p << 4) + k];
        const int q  = b * NN + ii;
        const unsigned int* outu = (const unsigned int*)outp;
        unsigned int pa = outu[((size_t)b*64 + PAROW + k)*NN + n];
        unsigned int pb = outu[((size_t)b*64 + PBROW + k)*NN + n];
        float2 dab = unph(pa);
        HU pbu; pbu.u = pb;
        float rd = (float)pbu.h[0];

        const uint4* aq = (const uint4*)(feat1h + (size_t)q*16);
        const uint4* ap = (const uint4*)(feat1h + (size_t)p*16);
        uint4 A0 = aq[0], A1 = aq[1];
        uint4 S0 = ap[0], S1 = ap[1];
        float sd = sd16(A0, A1, S0, S1);
        float fdis2 = 2.f * __expf(-sd * 0.0625f);

        const uint4* hq = (const uint4*)(hnT + (size_t)q*16);
        uint4 H0 = hq[0], H1 = hq[1];
        unsigned int lw[8];
        lrep16p((const unsigned int*)(wb + LM1AW), dab.x, dab.y, rd,
                sm + HSOFF + wv*32 + (pt & 3)*8, H0, H1, lw);

        // lrep2 = relu(lm2g-folded-W2(h2) · lrep + lm2b), packed dot
        HU lrp[8];
        #pragma unroll
        for (int d = 0; d < 8; d++) lrp[d].u = lw[d];
        const unsigned int* l2h = (const unsigned int*)(wb + LM2HW);
        unsigned int l2[8];
        #pragma unroll
        for (int d = 0; d < 8; d++){
            HU a0, a1;
            a0.u = 0u; a1.u = 0u;
            #pragma unroll
            for (int cc = 0; cc < 8; cc++){
                HU w0, w1;
                w0.u = l2h[(2*d)*8 + cc];
                w1.u = l2h[(2*d+1)*8 + cc];
                a0.h = a0.h + w0.h * lrp[cc].h;
                a1.h = a1.h + w1.h * lrp[cc].h;
            }
            float v0 = (float)a0.h[0] + (float)a0.h[1] + lm2b[2*d];
            float v1 = (float)a1.h[0] + (float)a1.h[1] + lm2b[2*d+1];
            l2[d] = ph(fmaxf(v0, 0.f), fmaxf(v1, 0.f));
        }

        HU g0; g0.h[0] = pbu.h[1]; g0.h[1] = (_Float16)fdis2;  // gdis,fdis2
        uint4* rp = (uint4*)(xs + pt*PTSH + k*RSH);
        rp[0] = make_uint4(g0.u, A0.x, A0.y, A0.z);
        rp[1] = make_uint4(A0.w, A1.x, A1.y, A1.z);
        rp[2] = make_uint4(A1.w, l2[0], l2[1], l2[2]);
        rp[3] = make_uint4(l2[3], l2[4], l2[5], l2[6]);
        ((unsigned int*)rp)[16] = l2[7];
    }
    wsync();

    phaseB_mfma(xs, (const short*)(wb + BFB) + 2048, sm + MIDOFF, threadIdx.x);
    wsync();

    {
        float m0 = sm[MIDOFF + pt*MS + 2*k];
        float m1 = sm[MIDOFF + pt*MS + 2*k + 1];
        ((unsigned int*)outp)[(size_t)(b*64 + k)*NN + n] = ph(m0, m1);
    }
}

// ---------------- Stage 2C: folded matvecs, 64 pts/block ----------------
#define WL_P2M 0     // 1024
#define WL_MA  1024  // 2048
#define WL_MX  3072  // 1024
#define WL_MV  4096  // 256
#define WL_C0  4352  // 64
#define WOFF   4416
#define SLAB   1280
#define LGRO   (WOFF + 4*SLAB)
#define SMTOT2 9600

__global__ __launch_bounds__(256, 2) void k_s2c(
    const float* __restrict__ featp,
    const float* __restrict__ xyzp,
    const float* __restrict__ wb,
    const float* __restrict__ p2mg,
    const float* __restrict__ p2mb,
    const float* __restrict__ m4g,
    const float* __restrict__ m4b,
    float* __restrict__ outp)
{
    __shared__ float sm[SMTOT2];
    const int tid = threadIdx.x;
    const int k   = tid & 15;
    const int g   = (tid >> 4) & 3;
    const int w   = tid >> 6;
    const int pblk = swizC(blockIdx.x);
    const int p0  = pblk << 6;
    const int b   = p0 / NN;
    const int n0  = p0 - b * NN;
    const int ptg = g*4;
    const int nT  = n0 + w*16 + ptg;
    float* slab = sm + WOFF + w*SLAB;

    for (int e = tid; e < 4416; e += 256) sm[e] = wb[512 + e];
    {
        uint4 um = *(const uint4*)((const unsigned int*)outp +
                                   (size_t)(b*64 + k)*NN + nT);
        float2 f;
        f = unph(um.x);
        slab[(ptg+0)*36 + 2*k] = f.x; slab[(ptg+0)*36 + 2*k+1] = f.y;
        f = unph(um.y);
        slab[(ptg+1)*36 + 2*k] = f.x; slab[(ptg+1)*36 + 2*k+1] = f.y;
        f = unph(um.z);
        slab[(ptg+2)*36 + 2*k] = f.x; slab[(ptg+2)*36 + 2*k+1] = f.y;
        f = unph(um.w);
        slab[(ptg+3)*36 + 2*k] = f.x; slab[(ptg+3)*36 + 2*k+1] = f.y;
        if (k == 0){
            float4 lv = *(const float4*)(outp + (size_t)(b*64 + LGROW)*NN + nT);
            sm[LGRO + w*16 + ptg + 0] = lv.x; sm[LGRO + w*16 + ptg + 1] = lv.y;
            sm[LGRO + w*16 + ptg + 2] = lv.z; sm[LGRO + w*16 + ptg + 3] = lv.w;
        }
    }
    __syncthreads();

    {
        const float2* wp = (const float2*)(sm + WL_P2M);
        float aA[4] = {0.f,0.f,0.f,0.f}, aB[4] = {0.f,0.f,0.f,0.f};
        #pragma unroll 2
        for (int cq = 0; cq < 8; cq++){
            f32x4 mv[4];
            #pragma unroll
            for (int i = 0; i < 4; i++)
                mv[i] = *(const f32x4*)(slab + (ptg+i)*36 + cq*4);
            #pragma unroll
            for (int cc = 0; cc < 4; cc++){
                float2 wv = wp[(cq*4+cc)*16 + k];
                #pragma unroll
                for (int i = 0; i < 4; i++){
                    aA[i] = fmaf(wv.x, mv[i][cc], aA[i]);
                    aB[i] = fmaf(wv.y, mv[i][cc], aB[i]);
                }
            }
        }
        float gA = p2mg[k], bA = p2mb[k], gB = p2mg[k+16], bB = p2mb[k+16];
        #pragma unroll
        for (int i = 0; i < 4; i++){
            slab[576 + (ptg+i)*36 + k]      = fmaxf(fmaf(gA, aA[i], bA), 0.f);
            slab[576 + (ptg+i)*36 + k + 16] = fmaxf(fmaf(gB, aB[i], bB), 0.f);
        }
    }
    wsync();

    float o4[4][4];
    {
        f32x4 c0v = *(const f32x4*)(sm + WL_C0 + 4*k);
        #pragma unroll
        for (int j = 0; j < 4; j++)
            #pragma unroll
            for (int i = 0; i < 4; i++) o4[j][i] = c0v[j];

        const f32x4* wa = (const f32x4*)(sm + WL_MA);
        #pragma unroll 2
        for (int cq = 0; cq < 8; cq++){
            f32x4 av[4];
            #pragma unroll
            for (int i = 0; i < 4; i++)
                av[i] = *(const f32x4*)(slab + 576 + (ptg+i)*36 + cq*4);
            #pragma unroll
            for (int cc = 0; cc < 4; cc++){
                f32x4 wv = wa[(cq*4+cc)*16 + k];
                #pragma unroll
                for (int i = 0; i < 4; i++){
                    #pragma unroll
                    for (int j = 0; j < 4; j++)
                        o4[j][i] = fmaf(wv[j], av[i][cc], o4[j][i]);
                }
            }
        }
        const f32x4* wx = (const f32x4*)(sm + WL_MX);
        #pragma unroll 4
        for (int c = 0; c < 16; c++){
            f32x4 wv = wx[c*16 + k];
            f32x4 xv = *(const f32x4*)(featp + (size_t)(b*16 + c)*NN + nT);
            #pragma unroll
            for (int i = 0; i < 4; i++){
                #pragma unroll
                for (int j = 0; j < 4; j++)
                    o4[j][i] = fmaf(wv[j], xv[i], o4[j][i]);
            }
        }
        const f32x4* wvv = (const f32x4*)(sm + WL_MV);
        #pragma unroll
        for (int c = 0; c < 3; c++){
            f32x4 wv = wvv[c*16 + k];
            #pragma unroll
            for (int i = 0; i < 4; i++){
                float vc = xyzp[(size_t)(p0 + w*16 + ptg + i)*3 + c];
                #pragma unroll
                for (int j = 0; j < 4; j++)
                    o4[j][i] = fmaf(wv[j], vc, o4[j][i]);
            }
        }
        {
            f32x4 wv = wvv[3*16 + k];
            #pragma unroll
            for (int i = 0; i < 4; i++){
                float vc = sm[LGRO + w*16 + ptg + i];
                #pragma unroll
                for (int j = 0; j < 4; j++)
                    o4[j][i] = fmaf(wv[j], vc, o4[j][i]);
            }
        }
    }
    wsync();

    {
        float* stg = slab;
        #pragma unroll
        for (int j = 0; j < 4; j++){
            int oo = k + 16*j;
            float gv = m4g[oo], bv = m4b[oo];
            #pragma unroll
            for (int i = 0; i < 4; i++)
                stg[oo*20 + ptg + i] = fmaxf(fmaf(gv, o4[j][i], bv), 0.f);
        }
        wsync();
        const int l = tid & 63;
        float* dst = outp + (size_t)(b*64 + l)*NN + n0 + w*16;
        #pragma unroll
        for (int q = 0; q < 4; q++){
            f32x4 v = *(const f32x4*)(stg + l*20 + q*4);
            *(f32x4*)(dst + q*4) = v;
        }
    }
}

extern "C" void kernel_launch(void* const* d_in, const int* in_sizes, int n_in,
                              void* d_out, int out_size, void* d_ws, size_t ws_size,
                              hipStream_t stream) {
    float* outp = (float*)d_out;

    float fillv = 1.0f;
    bool ok = true;
    if (n_in != 32) { fillv = 5.0f; ok = false; }
    else if (in_sizes[0] != 1310720 || in_sizes[1] != 245760 ||
             in_sizes[31] != 1310720) { fillv = 7.0f; ok = false; }
    else if (out_size != 5242880) { fillv = 9.0f; ok = false; }
    else if (ws_size < ((size_t)NPTS * 16 + WTOT) * sizeof(float)) { fillv = 11.0f; ok = false; }

    if (!ok){
        k_fill4<<<1024, 256, 0, stream>>>((float4*)outp, fillv, out_size/4);
        return;
    }

    const float* featp = (const float*)d_in[0];
    const float* xyzp  = (const float*)d_in[1];
    const int*   nidx  = (const int*)d_in[31];

    float* wsF = (float*)d_ws;
    float* wb  = (float*)d_ws + (size_t)NPTS * 16;

    #define W(i) ((const float*)d_in[2 + (i)])
    k_pre<<<8 + NPTS/256, 256, 0, stream>>>(
        featp, xyzp,
        W(0), W(1), W(2),          // m1
        W(3), W(4), W(5),          // lm1
        W(6), W(7),                // lm2W, lm2g
        W(9), W(13),               // p1fc, p2fc
        W(10), W(14),              // p1mW, p2mW
        W(17), W(20), W(23), W(26),// m2W, scW, m3W, m4W
        W(18), W(19), W(21), W(22), W(24), W(25),  // m2/sc/m3 g,b
        wb, wsF, outp);
    k_stage1<<<NPTS/16, 256, 0, stream>>>(xyzp, nidx, wb,
        W(11), W(12),              // p1m g/b
        wsF, outp);
    k_s2ab<<<NPTS/16, 256, 0, stream>>>(nidx,
        W(8),                      // lm2b
        wb, wsF, outp);
    k_s2c<<<NPTS/64, 256, 0, stream>>>(featp, xyzp, wb,
        W(15), W(16),              // p2m g/b
        W(27), W(28),              // m4 g/b
        outp);
    #undef W
}

// Round 12
// 237.141 us; speedup vs baseline: 1.5036x; 1.0310x over previous
//
#include <hip/hip_runtime.h>

#define NN 20480
#define NPTS 81920   // B(4) * N(20480)
#define MS 36        // MID row stride (floats)
#define RSH 36       // X row stride in shorts (72 B: 18 dwords, gcd(18,32)=2)
#define PTSH 584     // X shorts per point (16*36=576 +8 pad) -> 292 dwords %32=4
#define MIDOFF 4672  // MID region (X = 16*584 shorts = 4672 f)
#define HSOFF  5248  // hs region (4 waves x 32 dwords)
#define SMS1   5376  // stage1/s2ab LDS floats (21.5 KB)
#define LOG2E 1.4426950408889634f

// d_out scratch rows (per batch, rows 17..63 dead until s2c writes):
#define HSROW 17
#define PAROW 25
#define PBROW 41
#define LGROW 57

// fp32 weight offsets in wb (floats):
#define P1MWT 0      // 512   p1m [k][c] row-direct
#define P2MWT 512    // 1024  p2m [c][k*2+h]
#define MAWT  1536   // 2048  MA = W4a*diag(m2g)*W2   [c][k*4+j]
#define MXWT  3584   // 1024  MX = W4a*diag(scg)*Ws   [c][r]
#define MVWT  4608   // 256   MV = W4b*diag(m3g)*W3   [c][r]
#define C0WT  4864   // 64    C0 = W4a*(m2b+scb)+W4b*m3b
#define BFB   4928   // fp16 B-frags: 2 stages x 2048 shorts = 2048 floats
#define LM1AW 6976   // 24 dwords: packed fp16 pairs LM1A[c][d]=(o=2d,2d+1)
#define LM2HW 7008   // 128 dwords: packed fp16 lm2g-folded [o][cc]=(c=2cc,2cc+1)
#define WTOT  7136   // floats total

typedef _Float16 half8 __attribute__((ext_vector_type(8)));
typedef _Float16 h2t  __attribute__((ext_vector_type(2)));
typedef float f32x4 __attribute__((ext_vector_type(4)));
union HU { unsigned int u; h2t h; };

__device__ __forceinline__ float redsum16(float v){
    v += __shfl_xor(v, 1); v += __shfl_xor(v, 2);
    v += __shfl_xor(v, 4); v += __shfl_xor(v, 8);
    return v;
}
__device__ __forceinline__ float redmax16(float v){
    v = fmaxf(v, __shfl_xor(v, 1)); v = fmaxf(v, __shfl_xor(v, 2));
    v = fmaxf(v, __shfl_xor(v, 4)); v = fmaxf(v, __shfl_xor(v, 8));
    return v;
}
__device__ __forceinline__ void wsync(){
    __builtin_amdgcn_wave_barrier();
    __threadfence_block();
    __builtin_amdgcn_wave_barrier();
}
__device__ __forceinline__ float frcp(float x){ return __builtin_amdgcn_rcpf(x); }

__device__ __forceinline__ unsigned int ph(float lo, float hi){
    union { _Float16 h[2]; unsigned int u; } cv;
    cv.h[0] = (_Float16)lo; cv.h[1] = (_Float16)hi;
    return cv.u;
}
__device__ __forceinline__ float2 unph(unsigned int u){
    union { unsigned int u; _Float16 h[2]; } cv; cv.u = u;
    return make_float2((float)cv.h[0], (float)cv.h[1]);
}

// sum of |a-b| over 16 fp16 lanes (packed math; |x| via bitmask)
__device__ __forceinline__ float sd16(uint4 a0, uint4 a1, uint4 b0, uint4 b1){
    HU acc; acc.u = 0u;
    #define SDT(A,B) { HU x,y,d; x.u=(A); y.u=(B); d.h = x.h - y.h; \
                       d.u &= 0x7FFF7FFFu; acc.h = acc.h + d.h; }
    SDT(a0.x,b0.x) SDT(a0.y,b0.y) SDT(a0.z,b0.z) SDT(a0.w,b0.w)
    SDT(a1.x,b1.x) SDT(a1.y,b1.y) SDT(a1.z,b1.z) SDT(a1.w,b1.w)
    #undef SDT
    return (float)acc.h[0] + (float)acc.h[1];
}

// Fast atan2 (minimax deg-9; max err ~1.4e-4 rad; atan2(0,0)=0).
__device__ __forceinline__ float fatan2(float y, float x){
    float ax = fabsf(x), ay = fabsf(y);
    float mx = fmaxf(ax, ay), mn = fminf(ax, ay);
    float z = mn * frcp(mx);
    z = (mx == 0.f) ? 0.f : z;
    float z2 = z * z;
    float a = fmaf(0.05265332f, z2, -0.11643287f);
    a = fmaf(a, z2, 0.19354346f);
    a = fmaf(a, z2, -0.33262347f);
    a = fmaf(a, z2, 0.99997726f);
    a = a * z;
    a = (ay > ax) ? (1.5707963268f - a) : a;
    a = (x < 0.f) ? (3.1415926536f - a) : a;
    return (y < 0.f) ? -a : a;
}

// Batch<->XCD affinity swizzles.
__device__ __forceinline__ int swizS(int bid){     // grid 5120 (16 pts/blk)
    int x = bid & 7, s = bid >> 3;
    return x * 640 + s;
}
__device__ __forceinline__ int swizC(int bid){     // grid 1280 (64 pts/blk)
    int x = bid & 7, s = bid >> 3;
    return x * 160 + s;
}

__global__ void k_fill4(float4* out, float val, int n4){
    int i = blockIdx.x * blockDim.x + threadIdx.x;
    int stride = gridDim.x * blockDim.x;
    float4 v = make_float4(val, val, val, val);
    for (; i < n4; i += stride) out[i] = v;
}

// Fused prep (blocks 0..7) + feat0/tables (blocks 8..; 128 pts/block,
// 2 threads per point: half A = m1 matvec, half B = Hs/Hn tables —
// doubles resident waves for this latency-bound kernel).
__global__ __launch_bounds__(256) void k_pre(
    const float* __restrict__ featp, const float* __restrict__ xyzp,
    const float* __restrict__ m1W,  const float* __restrict__ m1g,
    const float* __restrict__ m1b,
    const float* __restrict__ lm1W, const float* __restrict__ lm1g,
    const float* __restrict__ lm1b,
    const float* __restrict__ lm2W, const float* __restrict__ lm2g,
    const float* __restrict__ p1fc, const float* __restrict__ p2fc,
    const float* __restrict__ p1mW, const float* __restrict__ p2mW,
    const float* __restrict__ m2W,  const float* __restrict__ scW,
    const float* __restrict__ m3W,  const float* __restrict__ m4W,
    const float* __restrict__ m2g,  const float* __restrict__ m2b,
    const float* __restrict__ scg,  const float* __restrict__ scb,
    const float* __restrict__ m3g,  const float* __restrict__ m3b,
    float* __restrict__ wb, float* __restrict__ wsF,
    float* __restrict__ outp)
{
    int bid = blockIdx.x;
    if (bid < 8){
        if (bid == 0){
            for (int e = threadIdx.x; e < 512; e += 256)
                wb[P1MWT + e] = p1mW[e];
        } else if (bid == 1){
            for (int e = threadIdx.x; e < 1024; e += 256){
                int c = e >> 5, r = e & 31;
                int k = r >> 1, h = r & 1;
                wb[P2MWT + e] = p2mW[(k + 16*h)*32 + c];
            }
        } else if (bid == 2){
            for (int e = threadIdx.x; e < 2048; e += 256){
                int c = e >> 6, r = e & 63;
                int o = (r >> 2) + 16*(r & 3);
                float acc = 0.f;
                for (int h = 0; h < 64; h++)
                    acc = fmaf(m4W[o*128 + h] * m2g[h], m2W[h*32 + c], acc);
                wb[MAWT + e] = acc;
            }
        } else if (bid == 3){
            for (int e = threadIdx.x; e < 1024; e += 256){
                int c = e >> 6, r = e & 63;
                int o = (r >> 2) + 16*(r & 3);
                float acc = 0.f;
                for (int h = 0; h < 64; h++)
                    acc = fmaf(m4W[o*128 + h] * scg[h], scW[h*16 + c], acc);
                wb[MXWT + e] = acc;
            }
        } else if (bid == 4){
            int e = threadIdx.x;
            if (e < 256){
                int c = e >> 6, r = e & 63;
                int o = (r >> 2) + 16*(r & 3);
                float acc = 0.f;
                for (int h = 0; h < 64; h++)
                    acc = fmaf(m4W[o*128 + 64 + h] * m3g[h], m3W[h*4 + c], acc);
                wb[MVWT + e] = acc;
            }
            if (e < 64){
                int o = (e >> 2) + 16*(e & 3);
                float acc = 0.f;
                for (int h = 0; h < 64; h++){
                    acc = fmaf(m4W[o*128 + h], m2b[h] + scb[h], acc);
                    acc = fmaf(m4W[o*128 + 64 + h], m3b[h], acc);
                }
                wb[C0WT + e] = acc;
            }
        } else if (bid == 5){
            int e = threadIdx.x;
            if (e < 24){   // LM1A packed pairs [c][d]: outputs (2d, 2d+1)
                int c = e >> 3, d = e & 7;
                ((unsigned int*)(wb + LM1AW))[e] =
                    ph(lm1g[2*d]   * lm1W[(2*d)*9   + c],
                       lm1g[2*d+1] * lm1W[(2*d+1)*9 + c]);
            }
            if (e >= 32 && e < 160){  // LM2H [o][cc]: lm2g-folded pairs
                int o = (e - 32) >> 3, cc = (e - 32) & 7;
                ((unsigned int*)(wb + LM2HW))[e - 32] =
                    ph(lm2g[o] * lm2W[o*16 + 2*cc],
                       lm2g[o] * lm2W[o*16 + 2*cc + 1]);
            }
        } else {   // bid 6,7: fc B-frags (fc[o][c]*LOG2E fp16, 16x16x32 B layout)
            const float* src = (bid == 6) ? p1fc : p2fc;
            short* dst = (short*)(wb + BFB) + (bid - 6) * 2048;
            for (int e = threadIdx.x; e < 2048; e += 256){
                int j = e & 7, l = (e >> 3) & 63, tq = (e >> 9) & 3;
                int q = tq & 1, t = tq >> 1;
                int kk = ((l >> 4) << 3) + j;
                int c = q*32 + kk;
                int o = (l & 15) + 16*t;
                float v = (c < 34) ? src[o*34 + c] * LOG2E : 0.f;
                union { _Float16 h; short s; } cv; cv.h = (_Float16)v;
                dst[e] = cv.s;
            }
        }
        return;
    }
    // ---- feat0h (half A) + Hs/Hn tables (half B), 128 points/block ----
    int t = threadIdx.x;
    int idx = t & 127;
    int p = (bid - 8) * 128 + idx;
    int b = p / NN;
    int n = p - b * NN;
    if (t < 128){
        // half A: m1 matvec -> feat0h
        float x[16];
        #pragma unroll
        for (int c = 0; c < 16; c++) x[c] = featp[(b*16 + c)*NN + n];
        unsigned int dw[8];
        for (int oo = 0; oo < 8; oo++){
            float v0 = 0.f, v1 = 0.f;
            #pragma unroll
            for (int c = 0; c < 16; c++){
                v0 = fmaf(m1W[(2*oo)*16 + c],   x[c], v0);
                v1 = fmaf(m1W[(2*oo+1)*16 + c], x[c], v1);
            }
            v0 = fmaxf(fmaf(m1g[2*oo],   v0, m1b[2*oo]),   0.f);
            v1 = fmaxf(fmaf(m1g[2*oo+1], v1, m1b[2*oo+1]), 0.f);
            dw[oo] = ph(v0, v1);
        }
        uint4* f0 = (uint4*)(outp + (size_t)b*64*NN + (size_t)n*8);
        f0[0] = make_uint4(dw[0], dw[1], dw[2], dw[3]);
        f0[1] = make_uint4(dw[4], dw[5], dw[6], dw[7]);
    } else {
        // half B: Hs/Hn tables from xyz
        float sx = xyzp[p*3 + 0], sy = xyzp[p*3 + 1], sz = xyzp[p*3 + 2];
        unsigned int* outu = (unsigned int*)outp;
        unsigned short* hnT = (unsigned short*)wsF + (size_t)NPTS*16;
        unsigned int hw[8];
        for (int d = 0; d < 8; d++){
            float h0, h1, g0, g1;
            int o0 = 2*d, o1 = 2*d+1;
            h0 = lm1g[o0]*(lm1W[o0*9+3]*sx + lm1W[o0*9+4]*sy + lm1W[o0*9+5]*sz) + lm1b[o0];
            h1 = lm1g[o1]*(lm1W[o1*9+3]*sx + lm1W[o1*9+4]*sy + lm1W[o1*9+5]*sz) + lm1b[o1];
            g0 = lm1g[o0]*(lm1W[o0*9+6]*sx + lm1W[o0*9+7]*sy + lm1W[o0*9+8]*sz);
            g1 = lm1g[o1]*(lm1W[o1*9+6]*sx + lm1W[o1*9+7]*sy + lm1W[o1*9+8]*sz);
            outu[((size_t)b*64 + HSROW + d)*NN + n] = ph(h0, h1);   // Hs(+bias)
            hw[d] = ph(g0, g1);                                      // Hn
        }
        uint4* hq = (uint4*)(hnT + (size_t)p*16);
        hq[0] = make_uint4(hw[0], hw[1], hw[2], hw[3]);
        hq[1] = make_uint4(hw[4], hw[5], hw[6], hw[7]);
    }
}

// Pool one o-tile: softmax over k WITHOUT max-sub (|logit| <~ 2 in
// exp2-domain; fp32 exact enough — R2-validated) + weighted sum of X[c][k].
__device__ __forceinline__ float poolT(f32x4 a, const short* base, int c, int g){
    const short* xc = base + c;
    union { short s; _Float16 h; } c0, c1, c2, c3;
    c0.s = xc[(g*4 + 0)*RSH]; c1.s = xc[(g*4 + 1)*RSH];
    c2.s = xc[(g*4 + 2)*RSH]; c3.s = xc[(g*4 + 3)*RSH];
    float x0 = (float)c0.h, x1 = (float)c1.h, x2 = (float)c2.h, x3 = (float)c3.h;
    float e0 = exp2f(a[0]), e1 = exp2f(a[1]);
    float e2 = exp2f(a[2]), e3 = exp2f(a[3]);
    float s = (e0 + e1) + (e2 + e3);
    float num = fmaf(e3, x3, fmaf(e2, x2, fmaf(e1, x1, e0*x0)));
    s   += __shfl_xor(s, 16);   s   += __shfl_xor(s, 32);
    num += __shfl_xor(num, 16); num += __shfl_xor(num, 32);
    return num * frcp(s);
}

// Phase B via MFMA: per point D[k][o-tile] = X^T · W^T (K=64; c 34..63 zero).
__device__ __forceinline__ void phaseB_mfma(
    const short* xs, const short* bfS, float* smMid, int tid)
{
    const half8* bf = (const half8*)bfS;
    const int l = tid & 63, wv = tid >> 6;
    const int o = l & 15, g = l >> 4;
    half8 B00 = bf[l], B01 = bf[64 + l], B10 = bf[128 + l], B11 = bf[192 + l];
    #pragma unroll 2
    for (int pp = 0; pp < 4; pp++){
        const int pt = wv*4 + pp;
        const short* base = xs + pt*PTSH;
        const short* rowp = base + (l & 15)*RSH;
        half8 A0 = *(const half8*)(rowp + g*8);     // c = g*8+j
        unsigned int d = *(const unsigned int*)(rowp + 32);  // c32,33
        union { unsigned int u[4]; half8 v; } a1u;
        a1u.u[0] = (g == 0) ? d : 0u;
        a1u.u[1] = 0u; a1u.u[2] = 0u; a1u.u[3] = 0u;
        half8 A1 = a1u.v;                           // c = 32+g*8+j
        f32x4 z = {0.f, 0.f, 0.f, 0.f};
        f32x4 a0 = __builtin_amdgcn_mfma_f32_16x16x32_f16(A0, B00, z, 0, 0, 0);
        a0       = __builtin_amdgcn_mfma_f32_16x16x32_f16(A1, B01, a0, 0, 0, 0);
        f32x4 a1 = __builtin_amdgcn_mfma_f32_16x16x32_f16(A0, B10, z, 0, 0, 0);
        a1       = __builtin_amdgcn_mfma_f32_16x16x32_f16(A1, B11, a1, 0, 0, 0);
        float mid0 = poolT(a0, base, 2 + o,      g);
        float mid1 = poolT(a1, base, 2 + o + 16, g);
        if (g == 0){
            smMid[pt*MS + o]      = mid0;
            smMid[pt*MS + o + 16] = mid1;
        }
    }
}

// Packed-fp16 lrep: lw[d] = relu_pk(LM1A·(da,db,rd) + Hs + Hn)
__device__ __forceinline__ void lrep16p(
    const unsigned int* __restrict__ laU, float da, float db, float rd,
    const float* hsS, uint4 H0, uint4 H1, unsigned int* lw)
{
    h2t vda, vdb, vrd, vhalf;
    vda[0] = (_Float16)da; vda[1] = vda[0];
    vdb[0] = (_Float16)db; vdb[1] = vdb[0];
    vrd[0] = (_Float16)rd; vrd[1] = vrd[0];
    vhalf[0] = (_Float16)0.5f; vhalf[1] = vhalf[0];
    unsigned int hn[8] = {H0.x, H0.y, H0.z, H0.w, H1.x, H1.y, H1.z, H1.w};
    #pragma unroll
    for (int d = 0; d < 8; d++){
        HU a, b, w0, w1, w2, acc, ab;
        a.u = __float_as_uint(hsS[d]);
        b.u = hn[d];
        w0.u = laU[d]; w1.u = laU[8 + d]; w2.u = laU[16 + d];
        acc.h = a.h + b.h;
        acc.h = acc.h + w0.h * vda;
        acc.h = acc.h + w1.h * vdb;
        acc.h = acc.h + w2.h * vrd;
        ab.u = acc.u & 0x7FFF7FFFu;
        acc.h = (acc.h + ab.h) * vhalf;
        lw[d] = acc.u;
    }
}

// ---------------- Stage 1: 256 thr, 16 pts, 4 independent waves ----------------
__global__ __launch_bounds__(256, 4) void k_stage1(
    const float* __restrict__ xyzp,
    const int* __restrict__ nidx,
    const float* __restrict__ wb,
    const float* __restrict__ p1mg,
    const float* __restrict__ p1mb,
    float* __restrict__ wsF,
    float* __restrict__ outp)
{
    __shared__ float sm[SMS1];
    short* xs = (short*)sm;
    const int k  = threadIdx.x & 15;
    const int pt = threadIdx.x >> 4;
    const int lane = threadIdx.x & 63, wv = threadIdx.x >> 6;
    const int pblk = swizS(blockIdx.x);
    const int p  = (pblk << 4) + pt;
    const int b  = p / NN;
    const int n  = p - b * NN;
    const int nb = (pblk << 4) - b * NN;   // block-base n (16|NN, no straddle)
    unsigned short* hnT = (unsigned short*)wsF + (size_t)NPTS*16;

    if (lane < 32){
        int lpt = wv*4 + (lane >> 3), d = lane & 7;
        sm[HSOFF + wv*32 + lane] =
            outp[((size_t)b*64 + HSROW + d)*NN + nb + lpt];
    }
    wsync();

    {
        const int ii = nidx[(p << 4) + k];
        const int q  = b * NN + ii;
        const uint4* aq = (const uint4*)(outp + (size_t)b*64*NN + (size_t)ii*8);
        const uint4* ap = (const uint4*)(outp + (size_t)b*64*NN + (size_t)n*8);
        uint4 A0 = aq[0], A1 = aq[1];
        uint4 S0 = ap[0], S1 = ap[1];
        const float sx = xyzp[p*3 + 0];
        const float sy = xyzp[p*3 + 1];
        const float sz = xyzp[p*3 + 2];
        const float nx = xyzp[q*3 + 0];
        const float ny = xyzp[q*3 + 1];
        const float nz = xyzp[q*3 + 2];

        float sd = sd16(A0, A1, S0, S1);
        float fdis2 = 2.f * __expf(-sd * 0.0625f);

        float rx = sx - nx, ry = sy - ny, rz = sz - nz;
        float r2 = rx*rx + ry*ry;
        float rdis = sqrtf(r2 + rz*rz);
        float ralpha = fatan2(ry, rx);
        float rbeta  = fatan2(rz, sqrtf(r2));
        float gdis = __expf(-rdis);

        float mx = redsum16(nx) * 0.0625f;
        float my = redsum16(ny) * 0.0625f;
        float mz = redsum16(nz) * 0.0625f;
        float dx = sx - mx, dy = sy - my, dz = sz - mz;
        float dalpha = fatan2(dy, dx);
        float dbeta  = fatan2(dz, sqrtf(dx*dx + dy*dy));
        float da = ralpha - dalpha, db = rbeta - dbeta;

        float mxd = redmax16(rdis);
        float nr  = sqrtf(sx*sx + sy*sy + sz*sz);

        unsigned int* outu = (unsigned int*)outp;
        outu[((size_t)b*64 + PAROW + k)*NN + n] = ph(da, db);
        outu[((size_t)b*64 + PBROW + k)*NN + n] = ph(rdis, gdis);
        if (k == 0)
            outp[((size_t)b*64 + LGROW)*NN + n] = (mxd*mxd*mxd) * frcp(nr*nr*nr);

        const uint4* hq = (const uint4*)(hnT + (size_t)q*16);
        uint4 H0 = hq[0], H1 = hq[1];
        unsigned int lw[8];
        lrep16p((const unsigned int*)(wb + LM1AW), da, db, rdis,
                sm + HSOFF + wv*32 + (pt & 3)*8, H0, H1, lw);

        uint4* rp = (uint4*)(xs + pt*PTSH + k*RSH);
        rp[0] = make_uint4(ph(gdis, fdis2), A0.x, A0.y, A0.z);
        rp[1] = make_uint4(A0.w, A1.x, A1.y, A1.z);
        rp[2] = make_uint4(A1.w, lw[0], lw[1], lw[2]);
        rp[3] = make_uint4(lw[3], lw[4], lw[5], lw[6]);
        ((unsigned int*)rp)[16] = lw[7];   // shorts 32..33
    }
    wsync();

    phaseB_mfma(xs, (const short*)(wb + BFB), sm + MIDOFF, threadIdx.x);
    wsync();

    // ---- Phase C: p1m row k -> feat1h (fp16) ----
    {
        float mid[32];
        const float4* mp = (const float4*)(sm + MIDOFF + pt*MS);
        #pragma unroll
        for (int i = 0; i < 8; i++){
            float4 t = mp[i];
            mid[4*i]=t.x; mid[4*i+1]=t.y; mid[4*i+2]=t.z; mid[4*i+3]=t.w;
        }
        const float4* wp = (const float4*)(wb + P1MWT) + (k << 3);
        float acc = 0.f;
        #pragma unroll
        for (int i = 0; i < 8; i++){
            float4 wv4 = wp[i];
            acc = fmaf(wv4.x, mid[4*i],   acc);
            acc = fmaf(wv4.y, mid[4*i+1], acc);
            acc = fmaf(wv4.z, mid[4*i+2], acc);
            acc = fmaf(wv4.w, mid[4*i+3], acc);
        }
        float v = fmaxf(fmaf(p1mg[k], acc, p1mb[k]), 0.f);
        union { _Float16 h; unsigned short s; } cv; cv.h = (_Float16)v;
        ((unsigned short*)wsF)[(size_t)(p << 4) + k] = cv.s;
    }
}

// ---------------- Stage 2AB: 256 thr, 16 pts ----------------
__global__ __launch_bounds__(256, 4) void k_s2ab(
    const int* __restrict__ nidx,
    const float* __restrict__ lm2b,
    const float* __restrict__ wb,
    const float* __restrict__ wsF,
    float* __restrict__ outp)
{
    __shared__ float sm[SMS1];
    short* xs = (short*)sm;
    const int k    = threadIdx.x & 15;
    const int pt   = threadIdx.x >> 4;
    const int lane = threadIdx.x & 63, wv = threadIdx.x >> 6;
    const int pblk = swizS(blockIdx.x);
    const int p    = (pblk << 4) + pt;
    const int b    = p / NN;
    const int n    = p - b * NN;
    const int nb   = (pblk << 4) - b * NN;
    const unsigned short* feat1h = (const unsigned short*)wsF;
    const unsigned short* hnT = (const unsigned short*)wsF + (size_t)NPTS*16;

    if (lane < 32){
        int lpt = wv*4 + (lane >> 3), d = lane & 7;
        sm[HSOFF + wv*32 + lane] =
            outp[((size_t)b*64 + HSROW + d)*NN + nb + lpt];
    }
    wsync();

    {
        const int ii = nidx[(p << 4) + k];
        const int q  = b * NN + ii;
        const unsigned int* outu = (const unsigned int*)outp;
        unsigned int pa = outu[((size_t)b*64 + PAROW + k)*NN + n];
        unsigned int pb = outu[((size_t)b*64 + PBROW + k)*NN + n];
        float2 dab = unph(pa);
        HU pbu; pbu.u = pb;
        float rd = (float)pbu.h[0];

        const uint4* aq = (const uint4*)(feat1h + (size_t)q*16);
        const uint4* ap = (const uint4*)(feat1h + (size_t)p*16);
        uint4 A0 = aq[0], A1 = aq[1];
        uint4 S0 = ap[0], S1 = ap[1];
        float sd = sd16(A0, A1, S0, S1);
        float fdis2 = 2.f * __expf(-sd * 0.0625f);

        const uint4* hq = (const uint4*)(hnT + (size_t)q*16);
        uint4 H0 = hq[0], H1 = hq[1];
        unsigned int lw[8];
        lrep16p((const unsigned int*)(wb + LM1AW), dab.x, dab.y, rd,
                sm + HSOFF + wv*32 + (pt & 3)*8, H0, H1, lw);

        // lrep2 = relu(lm2g-folded-W2(h2) · lrep + lm2b), packed dot
        HU lrp[8];
        #pragma unroll
        for (int d = 0; d < 8; d++) lrp[d].u = lw[d];
        const unsigned int* l2h = (const unsigned int*)(wb + LM2HW);
        unsigned int l2[8];
        #pragma unroll
        for (int d = 0; d < 8; d++){
            HU a0, a1;
            a0.u = 0u; a1.u = 0u;
            #pragma unroll
            for (int cc = 0; cc < 8; cc++){
                HU w0, w1;
                w0.u = l2h[(2*d)*8 + cc];
                w1.u = l2h[(2*d+1)*8 + cc];
                a0.h = a0.h + w0.h * lrp[cc].h;
                a1.h = a1.h + w1.h * lrp[cc].h;
            }
            float v0 = (float)a0.h[0] + (float)a0.h[1] + lm2b[2*d];
            float v1 = (float)a1.h[0] + (float)a1.h[1] + lm2b[2*d+1];
            l2[d] = ph(fmaxf(v0, 0.f), fmaxf(v1, 0.f));
        }

        HU g0; g0.h[0] = pbu.h[1]; g0.h[1] = (_Float16)fdis2;  // gdis,fdis2
        uint4* rp = (uint4*)(xs + pt*PTSH + k*RSH);
        rp[0] = make_uint4(g0.u, A0.x, A0.y, A0.z);
        rp[1] = make_uint4(A0.w, A1.x, A1.y, A1.z);
        rp[2] = make_uint4(A1.w, l2[0], l2[1], l2[2]);
        rp[3] = make_uint4(l2[3], l2[4], l2[5], l2[6]);
        ((unsigned int*)rp)[16] = l2[7];
    }
    wsync();

    phaseB_mfma(xs, (const short*)(wb + BFB) + 2048, sm + MIDOFF, threadIdx.x);
    wsync();

    {
        float m0 = sm[MIDOFF + pt*MS + 2*k];
        float m1 = sm[MIDOFF + pt*MS + 2*k + 1];
        ((unsigned int*)outp)[(size_t)(b*64 + k)*NN + n] = ph(m0, m1);
    }
}

// ---------------- Stage 2C: folded matvecs, 64 pts/block ----------------
#define WL_P2M 0     // 1024
#define WL_MA  1024  // 2048
#define WL_MX  3072  // 1024
#define WL_MV  4096  // 256
#define WL_C0  4352  // 64
#define WOFF   4416
#define SLAB   1280
#define LGRO   (WOFF + 4*SLAB)
#define SMTOT2 9600

__global__ __launch_bounds__(256, 2) void k_s2c(
    const float* __restrict__ featp,
    const float* __restrict__ xyzp,
    const float* __restrict__ wb,
    const float* __restrict__ p2mg,
    const float* __restrict__ p2mb,
    const float* __restrict__ m4g,
    const float* __restrict__ m4b,
    float* __restrict__ outp)
{
    __shared__ float sm[SMTOT2];
    const int tid = threadIdx.x;
    const int k   = tid & 15;
    const int g   = (tid >> 4) & 3;
    const int w   = tid >> 6;
    const int pblk = swizC(blockIdx.x);
    const int p0  = pblk << 6;
    const int b   = p0 / NN;
    const int n0  = p0 - b * NN;
    const int ptg = g*4;
    const int nT  = n0 + w*16 + ptg;
    float* slab = sm + WOFF + w*SLAB;

    for (int e = tid; e < 4416; e += 256) sm[e] = wb[512 + e];
    {
        uint4 um = *(const uint4*)((const unsigned int*)outp +
                                   (size_t)(b*64 + k)*NN + nT);
        float2 f;
        f = unph(um.x);
        slab[(ptg+0)*36 + 2*k] = f.x; slab[(ptg+0)*36 + 2*k+1] = f.y;
        f = unph(um.y);
        slab[(ptg+1)*36 + 2*k] = f.x; slab[(ptg+1)*36 + 2*k+1] = f.y;
        f = unph(um.z);
        slab[(ptg+2)*36 + 2*k] = f.x; slab[(ptg+2)*36 + 2*k+1] = f.y;
        f = unph(um.w);
        slab[(ptg+3)*36 + 2*k] = f.x; slab[(ptg+3)*36 + 2*k+1] = f.y;
        if (k == 0){
            float4 lv = *(const float4*)(outp + (size_t)(b*64 + LGROW)*NN + nT);
            sm[LGRO + w*16 + ptg + 0] = lv.x; sm[LGRO + w*16 + ptg + 1] = lv.y;
            sm[LGRO + w*16 + ptg + 2] = lv.z; sm[LGRO + w*16 + ptg + 3] = lv.w;
        }
    }
    __syncthreads();

    {
        const float2* wp = (const float2*)(sm + WL_P2M);
        float aA[4] = {0.f,0.f,0.f,0.f}, aB[4] = {0.f,0.f,0.f,0.f};
        #pragma unroll 2
        for (int cq = 0; cq < 8; cq++){
            f32x4 mv[4];
            #pragma unroll
            for (int i = 0; i < 4; i++)
                mv[i] = *(const f32x4*)(slab + (ptg+i)*36 + cq*4);
            #pragma unroll
            for (int cc = 0; cc < 4; cc++){
                float2 wv = wp[(cq*4+cc)*16 + k];
                #pragma unroll
                for (int i = 0; i < 4; i++){
                    aA[i] = fmaf(wv.x, mv[i][cc], aA[i]);
                    aB[i] = fmaf(wv.y, mv[i][cc], aB[i]);
                }
            }
        }
        float gA = p2mg[k], bA = p2mb[k], gB = p2mg[k+16], bB = p2mb[k+16];
        #pragma unroll
        for (int i = 0; i < 4; i++){
            slab[576 + (ptg+i)*36 + k]      = fmaxf(fmaf(gA, aA[i], bA), 0.f);
            slab[576 + (ptg+i)*36 + k + 16] = fmaxf(fmaf(gB, aB[i], bB), 0.f);
        }
    }
    wsync();

    float o4[4][4];
    {
        f32x4 c0v = *(const f32x4*)(sm + WL_C0 + 4*k);
        #pragma unroll
        for (int j = 0; j < 4; j++)
            #pragma unroll
            for (int i = 0; i < 4; i++) o4[j][i] = c0v[j];

        const f32x4* wa = (const f32x4*)(sm + WL_MA);
        #pragma unroll 2
        for (int cq = 0; cq < 8; cq++){
            f32x4 av[4];
            #pragma unroll
            for (int i = 0; i < 4; i++)
                av[i] = *(const f32x4*)(slab + 576 + (ptg+i)*36 + cq*4);
            #pragma unroll
            for (int cc = 0; cc < 4; cc++){
                f32x4 wv = wa[(cq*4+cc)*16 + k];
                #pragma unroll
                for (int i = 0; i < 4; i++){
                    #pragma unroll
                    for (int j = 0; j < 4; j++)
                        o4[j][i] = fmaf(wv[j], av[i][cc], o4[j][i]);
                }
            }
        }
        const f32x4* wx = (const f32x4*)(sm + WL_MX);
        #pragma unroll 4
        for (int c = 0; c < 16; c++){
            f32x4 wv = wx[c*16 + k];
            f32x4 xv = *(const f32x4*)(featp + (size_t)(b*16 + c)*NN + nT);
            #pragma unroll
            for (int i = 0; i < 4; i++){
                #pragma unroll
                for (int j = 0; j < 4; j++)
                    o4[j][i] = fmaf(wv[j], xv[i], o4[j][i]);
            }
        }
        const f32x4* wvv = (const f32x4*)(sm + WL_MV);
        #pragma unroll
        for (int c = 0; c < 3; c++){
            f32x4 wv = wvv[c*16 + k];
            #pragma unroll
            for (int i = 0; i < 4; i++){
                float vc = xyzp[(size_t)(p0 + w*16 + ptg + i)*3 + c];
                #pragma unroll
                for (int j = 0; j < 4; j++)
                    o4[j][i] = fmaf(wv[j], vc, o4[j][i]);
            }
        }
        {
            f32x4 wv = wvv[3*16 + k];
            #pragma unroll
            for (int i = 0; i < 4; i++){
                float vc = sm[LGRO + w*16 + ptg + i];
                #pragma unroll
                for (int j = 0; j < 4; j++)
                    o4[j][i] = fmaf(wv[j], vc, o4[j][i]);
            }
        }
    }
    wsync();

    {
        float* stg = slab;
        #pragma unroll
        for (int j = 0; j < 4; j++){
            int oo = k + 16*j;
            float gv = m4g[oo], bv = m4b[oo];
            #pragma unroll
            for (int i = 0; i < 4; i++)
                stg[oo*20 + ptg + i] = fmaxf(fmaf(gv, o4[j][i], bv), 0.f);
        }
        wsync();
        const int l = tid & 63;
        float* dst = outp + (size_t)(b*64 + l)*NN + n0 + w*16;
        #pragma unroll
        for (int q = 0; q < 4; q++){
            f32x4 v = *(const f32x4*)(stg + l*20 + q*4);
            *(f32x4*)(dst + q*4) = v;
        }
    }
}

extern "C" void kernel_launch(void* const* d_in, const int* in_sizes, int n_in,
                              void* d_out, int out_size, void* d_ws, size_t ws_size,
                              hipStream_t stream) {
    float* outp = (float*)d_out;

    float fillv = 1.0f;
    bool ok = true;
    if (n_in != 32) { fillv = 5.0f; ok = false; }
    else if (in_sizes[0] != 1310720 || in_sizes[1] != 245760 ||
             in_sizes[31] != 1310720) { fillv = 7.0f; ok = false; }
    else if (out_size != 5242880) { fillv = 9.0f; ok = false; }
    else if (ws_size < ((size_t)NPTS * 16 + WTOT) * sizeof(float)) { fillv = 11.0f; ok = false; }

    if (!ok){
        k_fill4<<<1024, 256, 0, stream>>>((float4*)outp, fillv, out_size/4);
        return;
    }

    const float* featp = (const float*)d_in[0];
    const float* xyzp  = (const float*)d_in[1];
    const int*   nidx  = (const int*)d_in[31];

    float* wsF = (float*)d_ws;
    float* wb  = (float*)d_ws + (size_t)NPTS * 16;

    #define W(i) ((const float*)d_in[2 + (i)])
    k_pre<<<8 + NPTS/128, 256, 0, stream>>>(
        featp, xyzp,
        W(0), W(1), W(2),          // m1
        W(3), W(4), W(5),          // lm1
        W(6), W(7),                // lm2W, lm2g
        W(9), W(13),               // p1fc, p2fc
        W(10), W(14),              // p1mW, p2mW
        W(17), W(20), W(23), W(26),// m2W, scW, m3W, m4W
        W(18), W(19), W(21), W(22), W(24), W(25),  // m2/sc/m3 g,b
        wb, wsF, outp);
    k_stage1<<<NPTS/16, 256, 0, stream>>>(xyzp, nidx, wb,
        W(11), W(12),              // p1m g/b
        wsF, outp);
    k_s2ab<<<NPTS/16, 256, 0, stream>>>(nidx,
        W(8),                      // lm2b
        wb, wsF, outp);
    k_s2c<<<NPTS/64, 256, 0, stream>>>(featp, xyzp, wb,
        W(15), W(16),              // p2m g/b
        W(27), W(28),              // m4 g/b
        outp);
    #undef W
}